// Round 10
// baseline (258.507 us; speedup 1.0000x reference)
//
#include <hip/hip_runtime.h>
#include <stdint.h>
#include <math.h>

#define NS_ITERS 26
#define PIT 72   // LDS row pitch in shorts (144B: 16B-aligned, bank-spread)
#define P2  72   // pitch for kns3 matrices

typedef unsigned short u16;
typedef __attribute__((ext_vector_type(8))) short short8;
typedef __attribute__((ext_vector_type(4))) float f32x4;

__device__ __forceinline__ u16 f2b(float f){
  unsigned u = __float_as_uint(f);
  unsigned r = (u + 0x7FFFu + ((u>>16)&1u)) >> 16;
  return (u16)r;
}
__device__ __forceinline__ float b2f(u16 h){ return __uint_as_float(((unsigned)h)<<16); }
__device__ __forceinline__ unsigned pk2(float lo, float hi){
  return (unsigned)f2b(lo) | ((unsigned)f2b(hi) << 16);
}

// ---------------- threefry2x32 (JAX-compatible) ----------------
__host__ __device__ constexpr uint32_t rotl32(uint32_t v, int n){ return (v<<n)|(v>>(32-n)); }
struct TFOut { uint32_t a, b; };
__host__ __device__ constexpr TFOut tf2x32(uint32_t k0, uint32_t k1, uint32_t x0, uint32_t x1){
  uint32_t ks2 = k0 ^ k1 ^ 0x1BD11BDAu;
  x0 += k0; x1 += k1;
#define TFR(R) x0 += x1; x1 = rotl32(x1,(R)) ^ x0;
  TFR(13) TFR(15) TFR(26) TFR(6)
  x0 += k1; x1 += ks2 + 1u;
  TFR(17) TFR(29) TFR(16) TFR(24)
  x0 += ks2; x1 += k0 + 2u;
  TFR(13) TFR(15) TFR(26) TFR(6)
  x0 += k0; x1 += k1 + 3u;
  TFR(17) TFR(29) TFR(16) TFR(24)
  x0 += k1; x1 += ks2 + 4u;
  TFR(13) TFR(15) TFR(26) TFR(6)
  x0 += ks2; x1 += k0 + 5u;
#undef TFR
  return TFOut{x0, x1};
}

__device__ __forceinline__ float erfinv_f32(float x){
  float w = -log1pf(-x*x);
  float p;
  if (w < 5.0f) {
    w -= 2.5f;
    p = 2.81022636e-08f;
    p = fmaf(p, w, 3.43273939e-07f);
    p = fmaf(p, w, -3.5233877e-06f);
    p = fmaf(p, w, -4.39150654e-06f);
    p = fmaf(p, w, 0.00021858087f);
    p = fmaf(p, w, -0.00125372503f);
    p = fmaf(p, w, -0.00417768164f);
    p = fmaf(p, w, 0.246640727f);
    p = fmaf(p, w, 1.50140941f);
  } else {
    w = sqrtf(w) - 3.0f;
    p = -0.000200214257f;
    p = fmaf(p, w, 0.000100950558f);
    p = fmaf(p, w, 0.00134934322f);
    p = fmaf(p, w, -0.00367342844f);
    p = fmaf(p, w, 0.00573950773f);
    p = fmaf(p, w, -0.0076224613f);
    p = fmaf(p, w, 0.00943887047f);
    p = fmaf(p, w, 1.00167406f);
    p = fmaf(p, w, 2.83297682f);
  }
  return p * x;
}

// ---------------- K1: fused prep ----------------
// blk 0..63     : primes -> PT bf16 [64][1024], unit-norm, rows>=50 zero
// blk 64..1087  : W1 [1024][4096] -> W1T bf16 [4096][1024] (64x64 tiles)
// blk 1088..2111: W2 [4096][1024] -> W2T bf16 [1024][4096]
__global__ __launch_bounds__(256) void kprepAll(const float* __restrict__ prime, u16* __restrict__ PT,
                                                const float* __restrict__ W1, u16* __restrict__ W1T,
                                                const float* __restrict__ W2, u16* __restrict__ W2T){
  int blk = blockIdx.x;
  int tid = threadIdx.x;
  if (blk < 64){
    int m = blk;
    u16* dst = PT + m*1024;
    if (m >= 50){ for (int k = tid; k < 1024; k += 256) dst[k] = 0; return; }
    __shared__ float red[256];
    const float* pr = prime + m*1024;
    float ss = 0.f;
    for (int k = tid; k < 1024; k += 256){ float v = pr[k]; ss = fmaf(v,v,ss); }
    red[tid] = ss; __syncthreads();
    for (int s = 128; s > 0; s >>= 1){ if (tid < s) red[tid] += red[tid+s]; __syncthreads(); }
    float sc = 1.0f / fmaxf(sqrtf(red[0]), 1e-12f);
    for (int k = tid; k < 1024; k += 256) dst[k] = f2b(pr[k]*sc);
    return;
  }
  const float* src; u16* dst; int srcStride, dstStride;
  if (blk < 1088){
    int t = blk - 64;
    int kt2 = t >> 6, nt2 = t & 63;
    src = W1 + (size_t)(kt2*64)*4096 + nt2*64; srcStride = 4096;
    dst = W1T + (size_t)(nt2*64)*1024 + kt2*64; dstStride = 1024;
  } else {
    int t = blk - 1088;
    int kt2 = t >> 4, dt2 = t & 15;
    src = W2 + (size_t)(kt2*64)*1024 + dt2*64; srcStride = 1024;
    dst = W2T + (size_t)(dt2*64)*4096 + kt2*64; dstStride = 4096;
  }
  __shared__ __align__(16) u16 ts[64*PIT];   // [src_row(k)][src_col(n)]
  int r = tid>>2, sseg = tid&3;
  {
    const float* s0 = src + (size_t)r*srcStride + sseg*16;
    unsigned p[8];
#pragma unroll
    for (int i = 0; i < 4; i++){
      float4 v = *reinterpret_cast<const float4*>(s0 + i*4);
      p[2*i]   = pk2(v.x, v.y);
      p[2*i+1] = pk2(v.z, v.w);
    }
    uint4 w0; w0.x=p[0]; w0.y=p[1]; w0.z=p[2]; w0.w=p[3];
    uint4 w1; w1.x=p[4]; w1.y=p[5]; w1.z=p[6]; w1.w=p[7];
    *reinterpret_cast<uint4*>(&ts[r*PIT + sseg*16])     = w0;
    *reinterpret_cast<uint4*>(&ts[r*PIT + sseg*16 + 8]) = w1;
  }
  __syncthreads();
  {
    int n2 = tid>>2, kseg = tid&3;
    unsigned q[8];
#pragma unroll
    for (int j = 0; j < 8; j++){
      u16 lo = ts[(kseg*16 + 2*j)*PIT + n2];
      u16 hi = ts[(kseg*16 + 2*j+1)*PIT + n2];
      q[j] = (unsigned)lo | ((unsigned)hi<<16);
    }
    u16* d2 = dst + (size_t)n2*dstStride + kseg*16;
    uint4 w0; w0.x=q[0]; w0.y=q[1]; w0.z=q[2]; w0.w=q[3];
    uint4 w1; w1.x=q[4]; w1.y=q[5]; w1.z=q[6]; w1.w=q[7];
    *reinterpret_cast<uint4*>(d2)   = w0;
    *reinterpret_cast<uint4*>(d2+8) = w1;
  }
}

// ---------------- K2: MFMA logits + softmax (zero-LDS main loop) ----------------
// A-fragments loaded directly from global x (f32->bf16 in regs); B-fragments
// directly from L2-resident PT. No barriers until the C/CT write epilogue.
__global__ __launch_bounds__(256) void kC(const float* __restrict__ x, const u16* __restrict__ PT,
                                          u16* __restrict__ C, u16* __restrict__ CT){
  int blk = blockIdx.x; int b = blk>>6, n0 = (blk&63)<<6;
  int tid = threadIdx.x, lane = tid&63, w = tid>>6;
  __shared__ __align__(16) u16 cl[64*PIT];     // epilogue bounce only
  f32x4 acc[4] = {{0,0,0,0},{0,0,0,0},{0,0,0,0},{0,0,0,0}};
  float sqa = 0.f;
  int tokA = 16*w + (lane&15);                 // A-fragment row this lane serves
  int kgrp = lane>>4;                          // 0..3 -> k-subslice
  const float* xrow = x + ((size_t)(b*4096 + n0 + tokA))*1024;
  const u16* pbase = PT + (size_t)(lane&15)*1024;
  for (int kc = 0; kc < 16; kc++){
    int k0 = kc*64;
#pragma unroll
    for (int s = 0; s < 2; s++){
      int kk = k0 + s*32 + kgrp*8;
      float4 v0 = *reinterpret_cast<const float4*>(xrow + kk);
      float4 v1 = *reinterpret_cast<const float4*>(xrow + kk + 4);
      sqa = fmaf(v0.x,v0.x,sqa); sqa = fmaf(v0.y,v0.y,sqa);
      sqa = fmaf(v0.z,v0.z,sqa); sqa = fmaf(v0.w,v0.w,sqa);
      sqa = fmaf(v1.x,v1.x,sqa); sqa = fmaf(v1.y,v1.y,sqa);
      sqa = fmaf(v1.z,v1.z,sqa); sqa = fmaf(v1.w,v1.w,sqa);
      union { unsigned u[4]; short8 s8; } cv;
      cv.u[0] = pk2(v0.x, v0.y); cv.u[1] = pk2(v0.z, v0.w);
      cv.u[2] = pk2(v1.x, v1.y); cv.u[3] = pk2(v1.z, v1.w);
      short8 a = cv.s8;
#pragma unroll
      for (int t = 0; t < 4; t++){
        short8 bb = *reinterpret_cast<const short8*>(pbase + (size_t)t*16*1024 + kk);
        acc[t] = __builtin_amdgcn_mfma_f32_16x16x32_bf16(a, bb, acc[t], 0, 0, 0);
      }
    }
  }
  // sumsq reduce across the 4 k-groups (lanes sharing lane&15)
  sqa += __shfl_xor(sqa, 16, 64);
  sqa += __shfl_xor(sqa, 32, 64);
  float inorm = 10.0f / fmaxf(sqrtf(sqa), 1e-12f);   // keyed by lane&15 (token 16w+(lane&15))
  // softmax per token (rows spread over lane>>4 groups; primes = lane&15 + 16*t)
#pragma unroll
  for (int r = 0; r < 4; r++){
    int tl = (lane>>4)*4 + r;                  // local token index 0..15
    int gt = 16*w + tl;
    float scale = __shfl(inorm, tl, 64);
    float v[4];
#pragma unroll
    for (int t = 0; t < 4; t++) v[t] = acc[t][r] * scale;
    if ((lane&15) >= 2) v[3] = -1e30f;
    float mx = fmaxf(fmaxf(v[0],v[1]), fmaxf(v[2],v[3]));
#pragma unroll
    for (int off = 1; off < 16; off <<= 1) mx = fmaxf(mx, __shfl_xor(mx, off, 64));
    float e[4], sum = 0.f;
#pragma unroll
    for (int t = 0; t < 4; t++){ e[t] = __expf(v[t]-mx); sum += e[t]; }
#pragma unroll
    for (int off = 1; off < 16; off <<= 1) sum += __shfl_xor(sum, off, 64);
    float inv = 1.0f / sum;
#pragma unroll
    for (int t = 0; t < 4; t++) cl[gt*PIT + t*16 + (lane&15)] = f2b(e[t]*inv);
  }
  __syncthreads();
  int stok = tid>>2, sseg = tid&3;
  { // C write (row-major) b128
    u16* dst = C + ((size_t)(b*4096 + n0 + stok))*64 + sseg*16;
    *reinterpret_cast<uint4*>(dst)   = *reinterpret_cast<const uint4*>(&cl[stok*PIT + sseg*16]);
    *reinterpret_cast<uint4*>(dst+8) = *reinterpret_cast<const uint4*>(&cl[stok*PIT + sseg*16+8]);
  }
  { // CT write (transposed)
    int m = tid>>2, nseg = tid&3;
    unsigned vs[8];
#pragma unroll
    for (int j = 0; j < 8; j++){
      u16 lo = cl[(nseg*16 + 2*j)*PIT + m];
      u16 hi = cl[(nseg*16 + 2*j+1)*PIT + m];
      vs[j] = (unsigned)lo | ((unsigned)hi<<16);
    }
    u16* dst = CT + ((size_t)(b*64 + m))*4096 + n0 + nseg*16;
    uint4 w0; w0.x=vs[0]; w0.y=vs[1]; w0.z=vs[2]; w0.w=vs[3];
    uint4 w1; w1.x=vs[4]; w1.y=vs[5]; w1.z=vs[6]; w1.w=vs[7];
    *reinterpret_cast<uint4*>(dst)   = w0;
    *reinterpret_cast<uint4*>(dst+8) = w1;
  }
}

// ---------------- K3: H_prime partials = CT @ x over n-quarter (MFMA, K-split x4) ----
__global__ __launch_bounds__(256) void kHp2(const float* __restrict__ x, const u16* __restrict__ CT,
                                            float* __restrict__ Hpart){
  int blk = blockIdx.x;            // 512 = b(8) * dt(16) * kt(4)
  int kt = blk & 3, dt = (blk >> 2) & 15, b = blk >> 6;
  int d0 = dt*64;
  int tid = threadIdx.x, lane = tid&63, w = tid>>6;
  __shared__ __align__(16) u16 cs[64*PIT];    // [m][n]
  __shared__ __align__(16) u16 xt[64*PIT];    // [d][n]
  f32x4 acc[4] = {{0,0,0,0},{0,0,0,0},{0,0,0,0},{0,0,0,0}};
  int nn = tid>>2, seg = tid&3;
  int np = tid & 31, dsg = tid >> 5;          // n-pair staging map
  for (int nc = 0; nc < 16; nc++){
    int n0 = kt*1024 + nc*64;
    __syncthreads();
    { // stage CT rows [m][n-chunk]
      const u16* src = CT + ((size_t)(b*64 + nn))*4096 + n0 + seg*16;  // nn = m here
      *reinterpret_cast<uint4*>(&cs[nn*PIT + seg*16])   = *reinterpret_cast<const uint4*>(src);
      *reinterpret_cast<uint4*>(&cs[nn*PIT + seg*16+8]) = *reinterpret_cast<const uint4*>(src+8);
    }
    { // stage x transposed: n-paired packed u32 writes (conflict-free)
      const float* s0 = x + ((size_t)(b*4096 + n0 + 2*np))*1024 + d0 + dsg*8;
      const float* s1 = s0 + 1024;
      float4 a0 = *reinterpret_cast<const float4*>(s0);
      float4 a1 = *reinterpret_cast<const float4*>(s0+4);
      float4 c0v = *reinterpret_cast<const float4*>(s1);
      float4 c1v = *reinterpret_cast<const float4*>(s1+4);
      float av[8] = {a0.x,a0.y,a0.z,a0.w,a1.x,a1.y,a1.z,a1.w};
      float cv[8] = {c0v.x,c0v.y,c0v.z,c0v.w,c1v.x,c1v.y,c1v.z,c1v.w};
#pragma unroll
      for (int j2 = 0; j2 < 8; j2++){
        int dd = dsg*8 + j2;
        *reinterpret_cast<unsigned*>(&xt[dd*PIT + 2*np]) = pk2(av[j2], cv[j2]);
      }
    }
    __syncthreads();
#pragma unroll
    for (int s = 0; s < 2; s++){
      short8 a = *reinterpret_cast<const short8*>(&cs[(16*w + (lane&15))*PIT + s*32 + (lane>>4)*8]);
#pragma unroll
      for (int t = 0; t < 4; t++){
        short8 bb = *reinterpret_cast<const short8*>(&xt[(t*16 + (lane&15))*PIT + s*32 + (lane>>4)*8]);
        acc[t] = __builtin_amdgcn_mfma_f32_16x16x32_bf16(a, bb, acc[t], 0, 0, 0);
      }
    }
  }
#pragma unroll
  for (int t = 0; t < 4; t++)
#pragma unroll
    for (int r = 0; r < 4; r++){
      int m = 16*w + (lane>>4)*4 + r;
      int d = d0 + t*16 + (lane&15);
      if (m < 50) Hpart[(((size_t)(b*4) + kt)*50 + m)*1024 + d] = acc[t][r];
    }
}

// ---------------- K3b: reduce partials -> H f32 + Hb bf16, pad rows zeroed (grid 2048) ----
__global__ void kredH(const float* __restrict__ Hpart, float* __restrict__ H, u16* __restrict__ Hb){
  int e = blockIdx.x*256 + threadIdx.x;    // grid 2048 -> 524288 over [b][m(64)][d]
  int b = e >> 16, rem = e & 65535;
  int m = rem >> 10, d = rem & 1023;
  size_t o = ((size_t)(b*64 + m))*1024 + d;
  if (m < 50){
    const float* p = Hpart + (size_t)b*204800 + m*1024 + d;
    float s = p[0] + p[51200] + p[102400] + p[153600];
    H[o] = s;
    Hb[o] = f2b(s);
  } else {
    Hb[o] = 0;
  }
}

// ---------------- K4a: Gram via MFMA: G = Hb Hb^T ----------------
__global__ __launch_bounds__(256) void kgram(const u16* __restrict__ Hb, float* __restrict__ G){
  int b = blockIdx.x;
  int tid = threadIdx.x, lane = tid&63, w = tid>>6;
  __shared__ __align__(16) u16 hs[64*PIT];
  f32x4 acc[4] = {{0,0,0,0},{0,0,0,0},{0,0,0,0},{0,0,0,0}};
  int m = tid>>2, seg = tid&3;
  for (int kc = 0; kc < 16; kc++){
    int k0 = kc*64;
    __syncthreads();
    const u16* src = Hb + ((size_t)(b*64 + m))*1024 + k0 + seg*16;
    *reinterpret_cast<uint4*>(&hs[m*PIT + seg*16])   = *reinterpret_cast<const uint4*>(src);
    *reinterpret_cast<uint4*>(&hs[m*PIT + seg*16+8]) = *reinterpret_cast<const uint4*>(src+8);
    __syncthreads();
#pragma unroll
    for (int s = 0; s < 2; s++){
      short8 a = *reinterpret_cast<const short8*>(&hs[(16*w + (lane&15))*PIT + s*32 + (lane>>4)*8]);
#pragma unroll
      for (int t = 0; t < 4; t++){
        short8 bb = *reinterpret_cast<const short8*>(&hs[(t*16 + (lane&15))*PIT + s*32 + (lane>>4)*8]);
        acc[t] = __builtin_amdgcn_mfma_f32_16x16x32_bf16(a, bb, acc[t], 0, 0, 0);
      }
    }
  }
#pragma unroll
  for (int t = 0; t < 4; t++)
#pragma unroll
    for (int r = 0; r < 4; r++){
      int i = 16*w + (lane>>4)*4 + r;
      int j = t*16 + (lane&15);
      if (i < 50 && j < 50) G[(size_t)b*2500 + i*50 + j] = acc[t][r];
    }
}

// ---------------- K4b: Newton-Schulz invsqrt via MFMA (bf16 fragments, 64x64 padded) ----
__global__ __launch_bounds__(256) void kns3(const float* __restrict__ G, float* __restrict__ Wm){
  int b = blockIdx.x;
  __shared__ __align__(16) u16 Yr[2][64*P2], Yc[2][64*P2], Zr[2][64*P2], Zc[2][64*P2];
  __shared__ __align__(16) u16 Tr[64*P2], Tc[64*P2];
  __shared__ float sv[2];
  int tid = threadIdx.x, lane = tid&63, w = tid>>6;
  int lr = lane>>4, lc = lane&15;
  int row0 = 16*w;
  const float* Gb = G + (size_t)b*2500;
  if (tid < 64){
    float v = (tid < 50) ? Gb[tid*50+tid] : 0.f;
    for (int off = 1; off < 64; off <<= 1) v += __shfl_xor(v, off, 64);
    if (tid == 0){ sv[0] = 1.0f / v; sv[1] = rsqrtf(v); }
  }
  __syncthreads();
  float rs = sv[0];
  for (int idx = tid; idx < 4096; idx += 256){
    int r = idx>>6, c = idx&63;
    float yv = (r<50 && c<50) ? Gb[r*50+c]*rs : ((r==c) ? 1.f : 0.f);
    float zv = (r==c) ? 1.f : 0.f;
    u16 yb = f2b(yv), zb = f2b(zv);
    Yr[0][r*P2+c] = yb; Yc[0][c*P2+r] = yb;
    Zr[0][r*P2+c] = zb; Zc[0][c*P2+r] = zb;
  }
  __syncthreads();
  for (int it = 0; it < NS_ITERS; it++){
    int cur = it & 1, nxt = cur ^ 1;
    { // phase 1: T = 1.5I - 0.5 * Z@Y
      short8 a0 = *reinterpret_cast<const short8*>(&Zr[cur][(row0+lc)*P2 + lr*8]);
      short8 a1 = *reinterpret_cast<const short8*>(&Zr[cur][(row0+lc)*P2 + 32 + lr*8]);
      f32x4 acc[4] = {{0,0,0,0},{0,0,0,0},{0,0,0,0},{0,0,0,0}};
#pragma unroll
      for (int t = 0; t < 4; t++){
        short8 b0 = *reinterpret_cast<const short8*>(&Yc[cur][(t*16+lc)*P2 + lr*8]);
        short8 b1 = *reinterpret_cast<const short8*>(&Yc[cur][(t*16+lc)*P2 + 32 + lr*8]);
        acc[t] = __builtin_amdgcn_mfma_f32_16x16x32_bf16(a0, b0, acc[t], 0, 0, 0);
        acc[t] = __builtin_amdgcn_mfma_f32_16x16x32_bf16(a1, b1, acc[t], 0, 0, 0);
      }
#pragma unroll
      for (int t = 0; t < 4; t++)
#pragma unroll
        for (int r = 0; r < 4; r++){
          int row = row0 + lr*4 + r, col = t*16 + lc;
          float v = ((row==col) ? 1.5f : 0.f) - 0.5f*acc[t][r];
          u16 h = f2b(v);
          Tr[row*P2+col] = h; Tc[col*P2+row] = h;
        }
    }
    __syncthreads();
    { // phase 2: Y' = Y@T ; Z' = T@Z
      short8 ya0 = *reinterpret_cast<const short8*>(&Yr[cur][(row0+lc)*P2 + lr*8]);
      short8 ya1 = *reinterpret_cast<const short8*>(&Yr[cur][(row0+lc)*P2 + 32 + lr*8]);
      short8 ta0 = *reinterpret_cast<const short8*>(&Tr[(row0+lc)*P2 + lr*8]);
      short8 ta1 = *reinterpret_cast<const short8*>(&Tr[(row0+lc)*P2 + 32 + lr*8]);
      f32x4 accY[4] = {{0,0,0,0},{0,0,0,0},{0,0,0,0},{0,0,0,0}};
      f32x4 accZ[4] = {{0,0,0,0},{0,0,0,0},{0,0,0,0},{0,0,0,0}};
#pragma unroll
      for (int t = 0; t < 4; t++){
        short8 tb0 = *reinterpret_cast<const short8*>(&Tc[(t*16+lc)*P2 + lr*8]);
        short8 tb1 = *reinterpret_cast<const short8*>(&Tc[(t*16+lc)*P2 + 32 + lr*8]);
        accY[t] = __builtin_amdgcn_mfma_f32_16x16x32_bf16(ya0, tb0, accY[t], 0, 0, 0);
        accY[t] = __builtin_amdgcn_mfma_f32_16x16x32_bf16(ya1, tb1, accY[t], 0, 0, 0);
        short8 zb0 = *reinterpret_cast<const short8*>(&Zc[cur][(t*16+lc)*P2 + lr*8]);
        short8 zb1 = *reinterpret_cast<const short8*>(&Zc[cur][(t*16+lc)*P2 + 32 + lr*8]);
        accZ[t] = __builtin_amdgcn_mfma_f32_16x16x32_bf16(ta0, zb0, accZ[t], 0, 0, 0);
        accZ[t] = __builtin_amdgcn_mfma_f32_16x16x32_bf16(ta1, zb1, accZ[t], 0, 0, 0);
      }
#pragma unroll
      for (int t = 0; t < 4; t++)
#pragma unroll
        for (int r = 0; r < 4; r++){
          int row = row0 + lr*4 + r, col = t*16 + lc;
          u16 hy = f2b(accY[t][r]);
          u16 hz = f2b(accZ[t][r]);
          Yr[nxt][row*P2+col] = hy; Yc[nxt][col*P2+row] = hy;
          Zr[nxt][row*P2+col] = hz; Zc[nxt][col*P2+row] = hz;
        }
    }
    __syncthreads();
  }
  float rss = sv[1];
  int fin = NS_ITERS & 1;
  for (int idx = tid; idx < 2500; idx += 256){
    int r = idx/50, c = idx - r*50;
    Wm[(size_t)b*2500 + idx] = b2f(Zr[fin][r*P2+c]) * rss;
  }
}

// ---------------- K4c: H_logic = Wm @ H + threefry noise -> ZbB bf16 (fused) ----------------
__global__ __launch_bounds__(256) void kapply2(const float* __restrict__ H, const float* __restrict__ Wm,
                                               u16* __restrict__ zb){
  TFOut K1 = tf2x32(0u, 42u, 0u, 0u);
  TFOut K2 = tf2x32(0u, 42u, 0u, 1u);
  int blk = blockIdx.x;          // 128 = b(8) * dt(16)
  int dt = blk & 15, b = blk >> 4;
  int d0 = dt*64;
  int tid = threadIdx.x;
  int d = tid & 63, mg = tid >> 6;
  __shared__ __align__(16) float WsT[50*64];
  __shared__ float Hs[50*65];
  for (int idx = tid; idx < 3200; idx += 256){
    int j = idx >> 6, c = idx & 63;
    WsT[idx] = (c < 50) ? Wm[(size_t)b*2500 + c*50 + j] : 0.f;
  }
  for (int idx = tid; idx < 3200; idx += 256){
    int j = idx >> 6, c = idx & 63;
    Hs[j*65 + c] = H[((size_t)(b*64) + j)*1024 + d0 + c];
  }
  __syncthreads();
  float acc[16];
#pragma unroll
  for (int i = 0; i < 16; i++) acc[i] = 0.f;
  for (int j = 0; j < 50; j++){
    float hv = Hs[j*65 + d];
    const float* wb = WsT + j*64 + (mg << 4);
#pragma unroll
    for (int q = 0; q < 4; q++){
      float4 wv = *reinterpret_cast<const float4*>(wb + q*4);
      acc[q*4+0] = fmaf(wv.x, hv, acc[q*4+0]);
      acc[q*4+1] = fmaf(wv.y, hv, acc[q*4+1]);
      acc[q*4+2] = fmaf(wv.z, hv, acc[q*4+2]);
      acc[q*4+3] = fmaf(wv.w, hv, acc[q*4+3]);
    }
  }
#pragma unroll
  for (int i = 0; i < 16; i++){
    int m = (mg << 4) + i;
    size_t zo = ((size_t)(b*64 + m))*1024 + d0 + d;
    u16 ov = 0;
    if (m < 50){
      float val = acc[i];
      uint32_t j = (uint32_t)(((b*50 + m) << 10) + d0 + d);
      TFOut r1 = tf2x32(K1.a, K1.b, 0u, j);
      uint32_t bits = r1.a ^ r1.b;
      float u = __uint_as_float(0x3F800000u | (bits >> 9)) - 1.0f;
      if (u < 0.0464f){
        TFOut r2 = tf2x32(K2.a, K2.b, 0u, j);
        uint32_t nb = r2.a ^ r2.b;
        float ww = __uint_as_float(0x3F800000u | (nb >> 9)) - 1.0f;
        const float lo = -0.99999994f;
        float un = fmaxf(lo, fmaf(ww, 2.0f, lo));
        val += 0.1f * (1.4142135f * erfinv_f32(un));
      }
      ov = f2b(val);
    }
    zb[zo] = ov;
  }
}

// ---------------- K5: Hh = gelu(ZbB @ W1T + b1) (MFMA; bf16 W1T direct staging) ----------------
__global__ __launch_bounds__(256) void kmlp1(const u16* __restrict__ ZbB, const u16* __restrict__ W1T,
                                             const float* __restrict__ b1, u16* __restrict__ Hh){
  int blk = blockIdx.x; int b = blk>>6, c0 = (blk&63)<<6;
  int tid = threadIdx.x, lane = tid&63, w = tid>>6;
  __shared__ __align__(16) u16 az[64*PIT];   // [m][k]
  __shared__ __align__(16) u16 wt[64*PIT];   // [n][k]
  f32x4 acc[4] = {{0,0,0,0},{0,0,0,0},{0,0,0,0},{0,0,0,0}};
  int rr = tid>>2, seg = tid&3;
  for (int kc = 0; kc < 16; kc++){
    int k0 = kc*64;
    __syncthreads();
    { // stage A (ZbB rows)
      const u16* src = ZbB + ((size_t)(b*64 + rr))*1024 + k0 + seg*16;
      *reinterpret_cast<uint4*>(&az[rr*PIT + seg*16])   = *reinterpret_cast<const uint4*>(src);
      *reinterpret_cast<uint4*>(&az[rr*PIT + seg*16+8]) = *reinterpret_cast<const uint4*>(src+8);
    }
    { // stage B (W1T rows, direct bf16 copy)
      const u16* src = W1T + ((size_t)(c0 + rr))*1024 + k0 + seg*16;
      *reinterpret_cast<uint4*>(&wt[rr*PIT + seg*16])   = *reinterpret_cast<const uint4*>(src);
      *reinterpret_cast<uint4*>(&wt[rr*PIT + seg*16+8]) = *reinterpret_cast<const uint4*>(src+8);
    }
    __syncthreads();
#pragma unroll
    for (int s = 0; s < 2; s++){
      short8 a = *reinterpret_cast<const short8*>(&az[(16*w + (lane&15))*PIT + s*32 + (lane>>4)*8]);
#pragma unroll
      for (int t = 0; t < 4; t++){
        short8 bb = *reinterpret_cast<const short8*>(&wt[(t*16 + (lane&15))*PIT + s*32 + (lane>>4)*8]);
        acc[t] = __builtin_amdgcn_mfma_f32_16x16x32_bf16(a, bb, acc[t], 0, 0, 0);
      }
    }
  }
#pragma unroll
  for (int t = 0; t < 4; t++)
#pragma unroll
    for (int r = 0; r < 4; r++){
      int m = 16*w + (lane>>4)*4 + r;
      int n = c0 + t*16 + (lane&15);
      float val = acc[t][r] + b1[n];
      float g = 0.5f * val * (1.0f + erff(val * 0.70710678f));
      Hh[((size_t)(b*64 + m))*4096 + n] = (m < 50) ? f2b(g) : (u16)0;
    }
}

// ---------------- K6: partials of Hh @ W2T (MFMA, K-split x4, bf16 direct staging) ----------------
__global__ __launch_bounds__(256) void kmlp2p(const u16* __restrict__ Hh, const u16* __restrict__ W2T,
                                              float* __restrict__ Mpart){
  int blk = blockIdx.x;            // 512 = b(8) * dt(16) * kt(4)
  int kt = blk & 3, dt = (blk >> 2) & 15, b = blk >> 6;
  int d0 = dt*64;
  int tid = threadIdx.x, lane = tid&63, w = tid>>6;
  __shared__ __align__(16) u16 az[64*PIT];
  __shared__ __align__(16) u16 wt[64*PIT];
  f32x4 acc[4] = {{0,0,0,0},{0,0,0,0},{0,0,0,0},{0,0,0,0}};
  int rr = tid>>2, seg = tid&3;
  for (int kc = 0; kc < 16; kc++){
    int k0 = kt*1024 + kc*64;
    __syncthreads();
    {
      const u16* src = Hh + ((size_t)(b*64 + rr))*4096 + k0 + seg*16;
      *reinterpret_cast<uint4*>(&az[rr*PIT + seg*16])   = *reinterpret_cast<const uint4*>(src);
      *reinterpret_cast<uint4*>(&az[rr*PIT + seg*16+8]) = *reinterpret_cast<const uint4*>(src+8);
    }
    { // stage B (W2T rows, direct bf16 copy)
      const u16* src = W2T + ((size_t)(d0 + rr))*4096 + k0 + seg*16;
      *reinterpret_cast<uint4*>(&wt[rr*PIT + seg*16])   = *reinterpret_cast<const uint4*>(src);
      *reinterpret_cast<uint4*>(&wt[rr*PIT + seg*16+8]) = *reinterpret_cast<const uint4*>(src+8);
    }
    __syncthreads();
#pragma unroll
    for (int s = 0; s < 2; s++){
      short8 a = *reinterpret_cast<const short8*>(&az[(16*w + (lane&15))*PIT + s*32 + (lane>>4)*8]);
#pragma unroll
      for (int t = 0; t < 4; t++){
        short8 bb = *reinterpret_cast<const short8*>(&wt[(t*16 + (lane&15))*PIT + s*32 + (lane>>4)*8]);
        acc[t] = __builtin_amdgcn_mfma_f32_16x16x32_bf16(a, bb, acc[t], 0, 0, 0);
      }
    }
  }
#pragma unroll
  for (int t = 0; t < 4; t++)
#pragma unroll
    for (int r = 0; r < 4; r++){
      int m = 16*w + (lane>>4)*4 + r;
      int d = d0 + t*16 + (lane&15);
      if (m < 50) Mpart[(((size_t)(b*4) + kt)*50 + m)*1024 + d] = acc[t][r];
    }
}

// ---------------- K6b: HfT = tanh(sum partials + b2)^T, bf16, m>=50 zero ----------------
__global__ void kredT(const float* __restrict__ Mpart, const float* __restrict__ b2, u16* __restrict__ HfT){
  int e = blockIdx.x*256 + threadIdx.x;    // grid 2048 -> 524288 over [b][m(64)][d]
  int b = e >> 16, rem = e & 65535;
  int m = rem >> 10, d = rem & 1023;
  u16 outv = 0;
  if (m < 50){
    const float* p = Mpart + (size_t)b*204800 + m*1024 + d;
    float s = p[0] + p[51200] + p[102400] + p[153600] + b2[d];
    outv = f2b(tanhf(s));
  }
  HfT[((size_t)(b*1024) + d)*64 + m] = outv;
}

// ---------------- K7: out = x + C @ Hf (MFMA + LDS-bounced coalesced epilogue) ----------
__global__ __launch_bounds__(256) void kdec2(const float* __restrict__ x, const u16* __restrict__ C,
                                             const u16* __restrict__ HfT, float* __restrict__ out){
  int blk = blockIdx.x;              // 2048 = b(8) * nt(64) * dq(4)
  int dq = blk & 3, nt = (blk >> 2) & 63, b = blk >> 8;
  int n0 = nt << 6;
  int tid = threadIdx.x, lane = tid&63, w = tid>>6;
  __shared__ __align__(16) u16 ctile[64*PIT];   // [tok][m]
  __shared__ __align__(16) u16 htile[64*PIT];   // [d][m]
  __shared__ __align__(16) float obuf[64*68];   // [n][d] f32, pitch 68
  int rr = tid>>2, seg = tid&3;
  {
    const u16* src = C + ((size_t)(b*4096 + n0 + rr))*64 + seg*16;
    *reinterpret_cast<uint4*>(&ctile[rr*PIT + seg*16])   = *reinterpret_cast<const uint4*>(src);
    *reinterpret_cast<uint4*>(&ctile[rr*PIT + seg*16+8]) = *reinterpret_cast<const uint4*>(src+8);
  }
  __syncthreads();
  short8 afrag[2];
#pragma unroll
  for (int s = 0; s < 2; s++)
    afrag[s] = *reinterpret_cast<const short8*>(&ctile[(16*w + (lane&15))*PIT + s*32 + (lane>>4)*8]);
  for (int dt2 = 0; dt2 < 4; dt2++){
    int d0 = (dq*4 + dt2) * 64;
    __syncthreads();
    {
      const u16* src = HfT + ((size_t)(b*1024 + d0 + rr))*64 + seg*16;
      *reinterpret_cast<uint4*>(&htile[rr*PIT + seg*16])   = *reinterpret_cast<const uint4*>(src);
      *reinterpret_cast<uint4*>(&htile[rr*PIT + seg*16+8]) = *reinterpret_cast<const uint4*>(src+8);
    }
    __syncthreads();
    f32x4 acc[4] = {{0,0,0,0},{0,0,0,0},{0,0,0,0},{0,0,0,0}};
#pragma unroll
    for (int s = 0; s < 2; s++){
#pragma unroll
      for (int t = 0; t < 4; t++){
        short8 bb = *reinterpret_cast<const short8*>(&htile[(t*16 + (lane&15))*PIT + s*32 + (lane>>4)*8]);
        acc[t] = __builtin_amdgcn_mfma_f32_16x16x32_bf16(afrag[s], bb, acc[t], 0, 0, 0);
      }
    }
    // scatter acc into LDS [n][d] f32
#pragma unroll
    for (int t = 0; t < 4; t++)
#pragma unroll
      for (int r = 0; r < 4; r++){
        int nl = 16*w + (lane>>4)*4 + r;
        int dl = t*16 + (lane&15);
        obuf[nl*68 + dl] = acc[t][r];
      }
    __syncthreads();
    // coalesced epilogue: 1024 float4-slots (64 rows x 16 slots), 4 per thread
#pragma unroll
    for (int pass = 0; pass < 4; pass++){
      int s2 = tid + pass*256;
      int nl = s2 >> 4, sg = s2 & 15;
      size_t o = ((size_t)(b*4096 + n0 + nl))*1024 + d0 + sg*4;
      float4 xv = *reinterpret_cast<const float4*>(x + o);
      const float* ob = &obuf[nl*68 + sg*4];
      float4 ov;
      ov.x = xv.x + ob[0];
      ov.y = xv.y + ob[1];
      ov.z = xv.z + ob[2];
      ov.w = xv.w + ob[3];
      *reinterpret_cast<float4*>(out + o) = ov;
    }
  }
}

// ---------------- launch ----------------
extern "C" void kernel_launch(void* const* d_in, const int* in_sizes, int n_in,
                              void* d_out, int out_size, void* d_ws, size_t ws_size,
                              hipStream_t stream) {
  (void)in_sizes; (void)n_in; (void)out_size;
  if (ws_size < (size_t)19755264) return;
  const float* x  = (const float*)d_in[0];
  const float* pn = (const float*)d_in[1];
  const float* W1 = (const float*)d_in[8];
  const float* b1 = (const float*)d_in[9];
  const float* W2 = (const float*)d_in[10];
  const float* b2 = (const float*)d_in[11];
  float* out = (float*)d_out;
  char* ws = (char*)d_ws;

  // W1T/W2T bf16 scratch lives in d_out (134 MB): dead before kdec2 fully
  // overwrites out. W1T = 4096x1024 bf16 (8.39MB), W2T = 1024x4096 bf16.
  u16*   W1T = (u16*)d_out;
  u16*   W2T = (u16*)d_out + 4194304;

  // Overlapped ws layout (stream-ordered liveness):
  u16*   C   = (u16*)(ws);                      // [0, 4.19MB)        live kC->kdec2
  u16*   CT  = (u16*)(ws + 4194304);            // CT region 4.19MB:  CT live kC->kHp2
  u16*   ZbB = (u16*)(ws + 4194304 + 1638400);  //   reuses CT space  (kapply2->kmlp1)
  u16*   HfT = (u16*)(ws + 4194304 + 2686976);  //   (kredT->kdec2)
  u16*   Hh  = (u16*)(ws + 8388608);            // Hh region 4.19MB:  Hh live kmlp1->kmlp2p
  u16*   Hb  = (u16*)(ws + 8388608);            //   reuses Hh space  (kredH->kgram)
  float* H   = (float*)(ws + 8388608 + 1048576);//   (kredH->kapply2)
  float* HP  = (float*)(ws + 12582912);         // partials 6.55MB: kHp2->kredH, kmlp2p->kredT
  u16*   PT  = (u16*)(ws + 19136512);           // 131,072 B
  float* G   = (float*)(ws + 19267584);         // 80,000 B
  float* WM  = (float*)(ws + 19347584);         // 80,000 B

  hipLaunchKernelGGL(kprepAll, dim3(2112), dim3(256), 0, stream, pn, PT, W1, W1T, W2, W2T);
  hipLaunchKernelGGL(kC,       dim3(512),  dim3(256), 0, stream, x, PT, C, CT);
  hipLaunchKernelGGL(kHp2,     dim3(512),  dim3(256), 0, stream, x, CT, HP);
  hipLaunchKernelGGL(kredH,    dim3(2048), dim3(256), 0, stream, HP, H, Hb);
  hipLaunchKernelGGL(kgram,    dim3(8),    dim3(256), 0, stream, Hb, G);
  hipLaunchKernelGGL(kns3,     dim3(8),    dim3(256), 0, stream, G, WM);
  hipLaunchKernelGGL(kapply2,  dim3(128),  dim3(256), 0, stream, H, WM, ZbB);
  hipLaunchKernelGGL(kmlp1,    dim3(512),  dim3(256), 0, stream, ZbB, W1T, b1, Hh);
  hipLaunchKernelGGL(kmlp2p,   dim3(512),  dim3(256), 0, stream, Hh, W2T, HP);
  hipLaunchKernelGGL(kredT,    dim3(2048), dim3(256), 0, stream, HP, b2, HfT);
  hipLaunchKernelGGL(kdec2,    dim3(2048), dim3(256), 0, stream, x, C, HfT, out);
}

// Round 11
// 247.271 us; speedup vs baseline: 1.0454x; 1.0454x over previous
//
#include <hip/hip_runtime.h>
#include <stdint.h>
#include <math.h>

#define NS_ITERS 26
#define PIT 72   // LDS row pitch in shorts (144B: 16B-aligned, bank-spread)
#define P2  72   // pitch for kns3 matrices

typedef unsigned short u16;
typedef __attribute__((ext_vector_type(8))) short short8;
typedef __attribute__((ext_vector_type(4))) float f32x4;

__device__ __forceinline__ u16 f2b(float f){
  unsigned u = __float_as_uint(f);
  unsigned r = (u + 0x7FFFu + ((u>>16)&1u)) >> 16;
  return (u16)r;
}
__device__ __forceinline__ float b2f(u16 h){ return __uint_as_float(((unsigned)h)<<16); }
__device__ __forceinline__ unsigned pk2(float lo, float hi){
  return (unsigned)f2b(lo) | ((unsigned)f2b(hi) << 16);
}

// ---------------- threefry2x32 (JAX-compatible) ----------------
__host__ __device__ constexpr uint32_t rotl32(uint32_t v, int n){ return (v<<n)|(v>>(32-n)); }
struct TFOut { uint32_t a, b; };
__host__ __device__ constexpr TFOut tf2x32(uint32_t k0, uint32_t k1, uint32_t x0, uint32_t x1){
  uint32_t ks2 = k0 ^ k1 ^ 0x1BD11BDAu;
  x0 += k0; x1 += k1;
#define TFR(R) x0 += x1; x1 = rotl32(x1,(R)) ^ x0;
  TFR(13) TFR(15) TFR(26) TFR(6)
  x0 += k1; x1 += ks2 + 1u;
  TFR(17) TFR(29) TFR(16) TFR(24)
  x0 += ks2; x1 += k0 + 2u;
  TFR(13) TFR(15) TFR(26) TFR(6)
  x0 += k0; x1 += k1 + 3u;
  TFR(17) TFR(29) TFR(16) TFR(24)
  x0 += k1; x1 += ks2 + 4u;
  TFR(13) TFR(15) TFR(26) TFR(6)
  x0 += ks2; x1 += k0 + 5u;
#undef TFR
  return TFOut{x0, x1};
}

__device__ __forceinline__ float erfinv_f32(float x){
  float w = -log1pf(-x*x);
  float p;
  if (w < 5.0f) {
    w -= 2.5f;
    p = 2.81022636e-08f;
    p = fmaf(p, w, 3.43273939e-07f);
    p = fmaf(p, w, -3.5233877e-06f);
    p = fmaf(p, w, -4.39150654e-06f);
    p = fmaf(p, w, 0.00021858087f);
    p = fmaf(p, w, -0.00125372503f);
    p = fmaf(p, w, -0.00417768164f);
    p = fmaf(p, w, 0.246640727f);
    p = fmaf(p, w, 1.50140941f);
  } else {
    w = sqrtf(w) - 3.0f;
    p = -0.000200214257f;
    p = fmaf(p, w, 0.000100950558f);
    p = fmaf(p, w, 0.00134934322f);
    p = fmaf(p, w, -0.00367342844f);
    p = fmaf(p, w, 0.00573950773f);
    p = fmaf(p, w, -0.0076224613f);
    p = fmaf(p, w, 0.00943887047f);
    p = fmaf(p, w, 1.00167406f);
    p = fmaf(p, w, 2.83297682f);
  }
  return p * x;
}

// ---------------- K1: fused prep ----------------
// blk 0..63     : primes -> PT bf16 [64][1024], unit-norm, rows>=50 zero
// blk 64..1087  : W1 [1024][4096] -> W1T bf16 [4096][1024] (64x64 tiles)
// blk 1088..2111: W2 [4096][1024] -> W2T bf16 [1024][4096]
__global__ __launch_bounds__(256) void kprepAll(const float* __restrict__ prime, u16* __restrict__ PT,
                                                const float* __restrict__ W1, u16* __restrict__ W1T,
                                                const float* __restrict__ W2, u16* __restrict__ W2T){
  int blk = blockIdx.x;
  int tid = threadIdx.x;
  if (blk < 64){
    int m = blk;
    u16* dst = PT + m*1024;
    if (m >= 50){ for (int k = tid; k < 1024; k += 256) dst[k] = 0; return; }
    __shared__ float red[256];
    const float* pr = prime + m*1024;
    float ss = 0.f;
    for (int k = tid; k < 1024; k += 256){ float v = pr[k]; ss = fmaf(v,v,ss); }
    red[tid] = ss; __syncthreads();
    for (int s = 128; s > 0; s >>= 1){ if (tid < s) red[tid] += red[tid+s]; __syncthreads(); }
    float sc = 1.0f / fmaxf(sqrtf(red[0]), 1e-12f);
    for (int k = tid; k < 1024; k += 256) dst[k] = f2b(pr[k]*sc);
    return;
  }
  const float* src; u16* dst; int srcStride, dstStride;
  if (blk < 1088){
    int t = blk - 64;
    int kt2 = t >> 6, nt2 = t & 63;
    src = W1 + (size_t)(kt2*64)*4096 + nt2*64; srcStride = 4096;
    dst = W1T + (size_t)(nt2*64)*1024 + kt2*64; dstStride = 1024;
  } else {
    int t = blk - 1088;
    int kt2 = t >> 4, dt2 = t & 15;
    src = W2 + (size_t)(kt2*64)*1024 + dt2*64; srcStride = 1024;
    dst = W2T + (size_t)(dt2*64)*4096 + kt2*64; dstStride = 4096;
  }
  __shared__ __align__(16) u16 ts[64*PIT];   // [src_row(k)][src_col(n)]
  int r = tid>>2, sseg = tid&3;
  {
    const float* s0 = src + (size_t)r*srcStride + sseg*16;
    unsigned p[8];
#pragma unroll
    for (int i = 0; i < 4; i++){
      float4 v = *reinterpret_cast<const float4*>(s0 + i*4);
      p[2*i]   = pk2(v.x, v.y);
      p[2*i+1] = pk2(v.z, v.w);
    }
    uint4 w0; w0.x=p[0]; w0.y=p[1]; w0.z=p[2]; w0.w=p[3];
    uint4 w1; w1.x=p[4]; w1.y=p[5]; w1.z=p[6]; w1.w=p[7];
    *reinterpret_cast<uint4*>(&ts[r*PIT + sseg*16])     = w0;
    *reinterpret_cast<uint4*>(&ts[r*PIT + sseg*16 + 8]) = w1;
  }
  __syncthreads();
  {
    int n2 = tid>>2, kseg = tid&3;
    unsigned q[8];
#pragma unroll
    for (int j = 0; j < 8; j++){
      u16 lo = ts[(kseg*16 + 2*j)*PIT + n2];
      u16 hi = ts[(kseg*16 + 2*j+1)*PIT + n2];
      q[j] = (unsigned)lo | ((unsigned)hi<<16);
    }
    u16* d2 = dst + (size_t)n2*dstStride + kseg*16;
    uint4 w0; w0.x=q[0]; w0.y=q[1]; w0.z=q[2]; w0.w=q[3];
    uint4 w1; w1.x=q[4]; w1.y=q[5]; w1.z=q[6]; w1.w=q[7];
    *reinterpret_cast<uint4*>(d2)   = w0;
    *reinterpret_cast<uint4*>(d2+8) = w1;
  }
}

// ---------------- K2: MFMA logits + softmax -> C[n][64] bf16 and CT[m][4096n] bf16 ----
__global__ __launch_bounds__(256) void kC(const float* __restrict__ x, const u16* __restrict__ PT,
                                          u16* __restrict__ C, u16* __restrict__ CT){
  int blk = blockIdx.x; int b = blk>>6, n0 = (blk&63)<<6;
  int tid = threadIdx.x, lane = tid&63, w = tid>>6;
  __shared__ __align__(16) u16 xs[64*PIT];
  __shared__ __align__(16) u16 ps[64*PIT];
  __shared__ float sq[64][5];
  f32x4 acc[4] = {{0,0,0,0},{0,0,0,0},{0,0,0,0},{0,0,0,0}};
  float sqa = 0.f;
  int stok = tid>>2, sseg = tid&3;                 // staging map
  int qtok = tid&63, qg = tid>>6;                  // sumsq map
  const float* xb = x + ((size_t)(b*4096 + n0))*1024;
  for (int kc = 0; kc < 16; kc++){
    int k0 = kc*64;
    __syncthreads();
    { // stage x (cvt bf16, packed uint4 writes)
      const float* src = xb + (size_t)stok*1024 + k0 + sseg*16;
      unsigned p[8];
#pragma unroll
      for (int i = 0; i < 4; i++){
        float4 v = *reinterpret_cast<const float4*>(src + i*4);
        p[2*i]   = pk2(v.x, v.y);
        p[2*i+1] = pk2(v.z, v.w);
      }
      uint4 w0; w0.x=p[0]; w0.y=p[1]; w0.z=p[2]; w0.w=p[3];
      uint4 w1; w1.x=p[4]; w1.y=p[5]; w1.z=p[6]; w1.w=p[7];
      *reinterpret_cast<uint4*>(&xs[stok*PIT + sseg*16])     = w0;
      *reinterpret_cast<uint4*>(&xs[stok*PIT + sseg*16 + 8]) = w1;
    }
    { // stage P rows
      const u16* src = PT + (size_t)stok*1024 + k0 + sseg*16;
      *reinterpret_cast<uint4*>(&ps[stok*PIT + sseg*16])   = *reinterpret_cast<const uint4*>(src);
      *reinterpret_cast<uint4*>(&ps[stok*PIT + sseg*16+8]) = *reinterpret_cast<const uint4*>(src+8);
    }
    __syncthreads();
    { // sumsq of this token's 16 values
      const u16* xr = &xs[qtok*PIT + qg*16];
#pragma unroll
      for (int j = 0; j < 16; j++){ float v = b2f(xr[j]); sqa = fmaf(v,v,sqa); }
    }
#pragma unroll
    for (int s = 0; s < 2; s++){
      short8 a = *reinterpret_cast<const short8*>(&xs[(16*w + (lane&15))*PIT + s*32 + (lane>>4)*8]);
#pragma unroll
      for (int t = 0; t < 4; t++){
        short8 bb = *reinterpret_cast<const short8*>(&ps[(t*16 + (lane&15))*PIT + s*32 + (lane>>4)*8]);
        acc[t] = __builtin_amdgcn_mfma_f32_16x16x32_bf16(a, bb, acc[t], 0, 0, 0);
      }
    }
  }
  sq[qtok][qg] = sqa;
  __syncthreads();
  if (tid < 64){
    float ss = sq[tid][0]+sq[tid][1]+sq[tid][2]+sq[tid][3];
    sq[tid][4] = 10.0f / fmaxf(sqrtf(ss), 1e-12f);
  }
  __syncthreads();
  // softmax per token (rows spread over lane>>4 groups; primes = lane&15 + 16*t)
  u16* cl = xs;  // reuse
#pragma unroll
  for (int r = 0; r < 4; r++){
    int gt = 16*w + (lane>>4)*4 + r;
    float scale = sq[gt][4];
    float v[4];
#pragma unroll
    for (int t = 0; t < 4; t++) v[t] = acc[t][r] * scale;
    if ((lane&15) >= 2) v[3] = -1e30f;
    float mx = fmaxf(fmaxf(v[0],v[1]), fmaxf(v[2],v[3]));
#pragma unroll
    for (int off = 1; off < 16; off <<= 1) mx = fmaxf(mx, __shfl_xor(mx, off, 64));
    float e[4], sum = 0.f;
#pragma unroll
    for (int t = 0; t < 4; t++){ e[t] = __expf(v[t]-mx); sum += e[t]; }
#pragma unroll
    for (int off = 1; off < 16; off <<= 1) sum += __shfl_xor(sum, off, 64);
    float inv = 1.0f / sum;
#pragma unroll
    for (int t = 0; t < 4; t++) cl[gt*PIT + t*16 + (lane&15)] = f2b(e[t]*inv);
  }
  __syncthreads();
  { // C write (row-major) b128
    u16* dst = C + ((size_t)(b*4096 + n0 + stok))*64 + sseg*16;
    *reinterpret_cast<uint4*>(dst)   = *reinterpret_cast<const uint4*>(&cl[stok*PIT + sseg*16]);
    *reinterpret_cast<uint4*>(dst+8) = *reinterpret_cast<const uint4*>(&cl[stok*PIT + sseg*16+8]);
  }
  { // CT write (transposed)
    int m = tid>>2, nseg = tid&3;
    unsigned vs[8];
#pragma unroll
    for (int j = 0; j < 8; j++){
      u16 lo = cl[(nseg*16 + 2*j)*PIT + m];
      u16 hi = cl[(nseg*16 + 2*j+1)*PIT + m];
      vs[j] = (unsigned)lo | ((unsigned)hi<<16);
    }
    u16* dst = CT + ((size_t)(b*64 + m))*4096 + n0 + nseg*16;
    uint4 w0; w0.x=vs[0]; w0.y=vs[1]; w0.z=vs[2]; w0.w=vs[3];
    uint4 w1; w1.x=vs[4]; w1.y=vs[5]; w1.z=vs[6]; w1.w=vs[7];
    *reinterpret_cast<uint4*>(dst)   = w0;
    *reinterpret_cast<uint4*>(dst+8) = w1;
  }
}

// ---------------- K3: H_prime partials = CT @ x over n-quarter (MFMA, K-split x4) ----
__global__ __launch_bounds__(256) void kHp2(const float* __restrict__ x, const u16* __restrict__ CT,
                                            float* __restrict__ Hpart){
  int blk = blockIdx.x;            // 512 = b(8) * dt(16) * kt(4)
  int kt = blk & 3, dt = (blk >> 2) & 15, b = blk >> 6;
  int d0 = dt*64;
  int tid = threadIdx.x, lane = tid&63, w = tid>>6;
  __shared__ __align__(16) u16 cs[64*PIT];    // [m][n]
  __shared__ __align__(16) u16 xt[64*PIT];    // [d][n]
  f32x4 acc[4] = {{0,0,0,0},{0,0,0,0},{0,0,0,0},{0,0,0,0}};
  int nn = tid>>2, seg = tid&3;
  int np = tid & 31, dsg = tid >> 5;          // n-pair staging map
  for (int nc = 0; nc < 16; nc++){
    int n0 = kt*1024 + nc*64;
    __syncthreads();
    { // stage CT rows [m][n-chunk]
      const u16* src = CT + ((size_t)(b*64 + nn))*4096 + n0 + seg*16;  // nn = m here
      *reinterpret_cast<uint4*>(&cs[nn*PIT + seg*16])   = *reinterpret_cast<const uint4*>(src);
      *reinterpret_cast<uint4*>(&cs[nn*PIT + seg*16+8]) = *reinterpret_cast<const uint4*>(src+8);
    }
    { // stage x transposed: n-paired packed u32 writes (conflict-free)
      const float* s0 = x + ((size_t)(b*4096 + n0 + 2*np))*1024 + d0 + dsg*8;
      const float* s1 = s0 + 1024;
      float4 a0 = *reinterpret_cast<const float4*>(s0);
      float4 a1 = *reinterpret_cast<const float4*>(s0+4);
      float4 c0v = *reinterpret_cast<const float4*>(s1);
      float4 c1v = *reinterpret_cast<const float4*>(s1+4);
      float av[8] = {a0.x,a0.y,a0.z,a0.w,a1.x,a1.y,a1.z,a1.w};
      float cv[8] = {c0v.x,c0v.y,c0v.z,c0v.w,c1v.x,c1v.y,c1v.z,c1v.w};
#pragma unroll
      for (int j2 = 0; j2 < 8; j2++){
        int dd = dsg*8 + j2;
        *reinterpret_cast<unsigned*>(&xt[dd*PIT + 2*np]) = pk2(av[j2], cv[j2]);
      }
    }
    __syncthreads();
#pragma unroll
    for (int s = 0; s < 2; s++){
      short8 a = *reinterpret_cast<const short8*>(&cs[(16*w + (lane&15))*PIT + s*32 + (lane>>4)*8]);
#pragma unroll
      for (int t = 0; t < 4; t++){
        short8 bb = *reinterpret_cast<const short8*>(&xt[(t*16 + (lane&15))*PIT + s*32 + (lane>>4)*8]);
        acc[t] = __builtin_amdgcn_mfma_f32_16x16x32_bf16(a, bb, acc[t], 0, 0, 0);
      }
    }
  }
#pragma unroll
  for (int t = 0; t < 4; t++)
#pragma unroll
    for (int r = 0; r < 4; r++){
      int m = 16*w + (lane>>4)*4 + r;
      int d = d0 + t*16 + (lane&15);
      if (m < 50) Hpart[(((size_t)(b*4) + kt)*50 + m)*1024 + d] = acc[t][r];
    }
}

// ---------------- K3b: reduce partials -> H f32 + Hb bf16, pad rows zeroed (grid 2048) ----
__global__ void kredH(const float* __restrict__ Hpart, float* __restrict__ H, u16* __restrict__ Hb){
  int e = blockIdx.x*256 + threadIdx.x;    // grid 2048 -> 524288 over [b][m(64)][d]
  int b = e >> 16, rem = e & 65535;
  int m = rem >> 10, d = rem & 1023;
  size_t o = ((size_t)(b*64 + m))*1024 + d;
  if (m < 50){
    const float* p = Hpart + (size_t)b*204800 + m*1024 + d;
    float s = p[0] + p[51200] + p[102400] + p[153600];
    H[o] = s;
    Hb[o] = f2b(s);
  } else {
    Hb[o] = 0;
  }
}

// ---------------- K4a: Gram via MFMA: G = Hb Hb^T ----------------
__global__ __launch_bounds__(256) void kgram(const u16* __restrict__ Hb, float* __restrict__ G){
  int b = blockIdx.x;
  int tid = threadIdx.x, lane = tid&63, w = tid>>6;
  __shared__ __align__(16) u16 hs[64*PIT];
  f32x4 acc[4] = {{0,0,0,0},{0,0,0,0},{0,0,0,0},{0,0,0,0}};
  int m = tid>>2, seg = tid&3;
  for (int kc = 0; kc < 16; kc++){
    int k0 = kc*64;
    __syncthreads();
    const u16* src = Hb + ((size_t)(b*64 + m))*1024 + k0 + seg*16;
    *reinterpret_cast<uint4*>(&hs[m*PIT + seg*16])   = *reinterpret_cast<const uint4*>(src);
    *reinterpret_cast<uint4*>(&hs[m*PIT + seg*16+8]) = *reinterpret_cast<const uint4*>(src+8);
    __syncthreads();
#pragma unroll
    for (int s = 0; s < 2; s++){
      short8 a = *reinterpret_cast<const short8*>(&hs[(16*w + (lane&15))*PIT + s*32 + (lane>>4)*8]);
#pragma unroll
      for (int t = 0; t < 4; t++){
        short8 bb = *reinterpret_cast<const short8*>(&hs[(t*16 + (lane&15))*PIT + s*32 + (lane>>4)*8]);
        acc[t] = __builtin_amdgcn_mfma_f32_16x16x32_bf16(a, bb, acc[t], 0, 0, 0);
      }
    }
  }
#pragma unroll
  for (int t = 0; t < 4; t++)
#pragma unroll
    for (int r = 0; r < 4; r++){
      int i = 16*w + (lane>>4)*4 + r;
      int j = t*16 + (lane&15);
      if (i < 50 && j < 50) G[(size_t)b*2500 + i*50 + j] = acc[t][r];
    }
}

// ---------------- K4b: Newton-Schulz invsqrt via MFMA (bf16 fragments, 64x64 padded) ----
__global__ __launch_bounds__(256) void kns3(const float* __restrict__ G, float* __restrict__ Wm){
  int b = blockIdx.x;
  __shared__ __align__(16) u16 Yr[2][64*P2], Yc[2][64*P2], Zr[2][64*P2], Zc[2][64*P2];
  __shared__ __align__(16) u16 Tr[64*P2], Tc[64*P2];
  __shared__ float sv[2];
  int tid = threadIdx.x, lane = tid&63, w = tid>>6;
  int lr = lane>>4, lc = lane&15;
  int row0 = 16*w;
  const float* Gb = G + (size_t)b*2500;
  if (tid < 64){
    float v = (tid < 50) ? Gb[tid*50+tid] : 0.f;
    for (int off = 1; off < 64; off <<= 1) v += __shfl_xor(v, off, 64);
    if (tid == 0){ sv[0] = 1.0f / v; sv[1] = rsqrtf(v); }
  }
  __syncthreads();
  float rs = sv[0];
  for (int idx = tid; idx < 4096; idx += 256){
    int r = idx>>6, c = idx&63;
    float yv = (r<50 && c<50) ? Gb[r*50+c]*rs : ((r==c) ? 1.f : 0.f);
    float zv = (r==c) ? 1.f : 0.f;
    u16 yb = f2b(yv), zb = f2b(zv);
    Yr[0][r*P2+c] = yb; Yc[0][c*P2+r] = yb;
    Zr[0][r*P2+c] = zb; Zc[0][c*P2+r] = zb;
  }
  __syncthreads();
  for (int it = 0; it < NS_ITERS; it++){
    int cur = it & 1, nxt = cur ^ 1;
    { // phase 1: T = 1.5I - 0.5 * Z@Y
      short8 a0 = *reinterpret_cast<const short8*>(&Zr[cur][(row0+lc)*P2 + lr*8]);
      short8 a1 = *reinterpret_cast<const short8*>(&Zr[cur][(row0+lc)*P2 + 32 + lr*8]);
      f32x4 acc[4] = {{0,0,0,0},{0,0,0,0},{0,0,0,0},{0,0,0,0}};
#pragma unroll
      for (int t = 0; t < 4; t++){
        short8 b0 = *reinterpret_cast<const short8*>(&Yc[cur][(t*16+lc)*P2 + lr*8]);
        short8 b1 = *reinterpret_cast<const short8*>(&Yc[cur][(t*16+lc)*P2 + 32 + lr*8]);
        acc[t] = __builtin_amdgcn_mfma_f32_16x16x32_bf16(a0, b0, acc[t], 0, 0, 0);
        acc[t] = __builtin_amdgcn_mfma_f32_16x16x32_bf16(a1, b1, acc[t], 0, 0, 0);
      }
#pragma unroll
      for (int t = 0; t < 4; t++)
#pragma unroll
        for (int r = 0; r < 4; r++){
          int row = row0 + lr*4 + r, col = t*16 + lc;
          float v = ((row==col) ? 1.5f : 0.f) - 0.5f*acc[t][r];
          u16 h = f2b(v);
          Tr[row*P2+col] = h; Tc[col*P2+row] = h;
        }
    }
    __syncthreads();
    { // phase 2: Y' = Y@T ; Z' = T@Z
      short8 ya0 = *reinterpret_cast<const short8*>(&Yr[cur][(row0+lc)*P2 + lr*8]);
      short8 ya1 = *reinterpret_cast<const short8*>(&Yr[cur][(row0+lc)*P2 + 32 + lr*8]);
      short8 ta0 = *reinterpret_cast<const short8*>(&Tr[(row0+lc)*P2 + lr*8]);
      short8 ta1 = *reinterpret_cast<const short8*>(&Tr[(row0+lc)*P2 + 32 + lr*8]);
      f32x4 accY[4] = {{0,0,0,0},{0,0,0,0},{0,0,0,0},{0,0,0,0}};
      f32x4 accZ[4] = {{0,0,0,0},{0,0,0,0},{0,0,0,0},{0,0,0,0}};
#pragma unroll
      for (int t = 0; t < 4; t++){
        short8 tb0 = *reinterpret_cast<const short8*>(&Tc[(t*16+lc)*P2 + lr*8]);
        short8 tb1 = *reinterpret_cast<const short8*>(&Tc[(t*16+lc)*P2 + 32 + lr*8]);
        accY[t] = __builtin_amdgcn_mfma_f32_16x16x32_bf16(ya0, tb0, accY[t], 0, 0, 0);
        accY[t] = __builtin_amdgcn_mfma_f32_16x16x32_bf16(ya1, tb1, accY[t], 0, 0, 0);
        short8 zb0 = *reinterpret_cast<const short8*>(&Zc[cur][(t*16+lc)*P2 + lr*8]);
        short8 zb1 = *reinterpret_cast<const short8*>(&Zc[cur][(t*16+lc)*P2 + 32 + lr*8]);
        accZ[t] = __builtin_amdgcn_mfma_f32_16x16x32_bf16(ta0, zb0, accZ[t], 0, 0, 0);
        accZ[t] = __builtin_amdgcn_mfma_f32_16x16x32_bf16(ta1, zb1, accZ[t], 0, 0, 0);
      }
#pragma unroll
      for (int t = 0; t < 4; t++)
#pragma unroll
        for (int r = 0; r < 4; r++){
          int row = row0 + lr*4 + r, col = t*16 + lc;
          u16 hy = f2b(accY[t][r]);
          u16 hz = f2b(accZ[t][r]);
          Yr[nxt][row*P2+col] = hy; Yc[nxt][col*P2+row] = hy;
          Zr[nxt][row*P2+col] = hz; Zc[nxt][col*P2+row] = hz;
        }
    }
    __syncthreads();
  }
  float rss = sv[1];
  int fin = NS_ITERS & 1;
  for (int idx = tid; idx < 2500; idx += 256){
    int r = idx/50, c = idx - r*50;
    Wm[(size_t)b*2500 + idx] = b2f(Zr[fin][r*P2+c]) * rss;
  }
}

// ---------------- K4c: H_logic = Wm @ H + threefry noise -> ZbB bf16 (fused) ----------------
__global__ __launch_bounds__(256) void kapply2(const float* __restrict__ H, const float* __restrict__ Wm,
                                               u16* __restrict__ zb){
  TFOut K1 = tf2x32(0u, 42u, 0u, 0u);
  TFOut K2 = tf2x32(0u, 42u, 0u, 1u);
  int blk = blockIdx.x;          // 128 = b(8) * dt(16)
  int dt = blk & 15, b = blk >> 4;
  int d0 = dt*64;
  int tid = threadIdx.x;
  int d = tid & 63, mg = tid >> 6;
  __shared__ __align__(16) float WsT[50*64];
  __shared__ float Hs[50*65];
  for (int idx = tid; idx < 3200; idx += 256){
    int j = idx >> 6, c = idx & 63;
    WsT[idx] = (c < 50) ? Wm[(size_t)b*2500 + c*50 + j] : 0.f;
  }
  for (int idx = tid; idx < 3200; idx += 256){
    int j = idx >> 6, c = idx & 63;
    Hs[j*65 + c] = H[((size_t)(b*64) + j)*1024 + d0 + c];
  }
  __syncthreads();
  float acc[16];
#pragma unroll
  for (int i = 0; i < 16; i++) acc[i] = 0.f;
  for (int j = 0; j < 50; j++){
    float hv = Hs[j*65 + d];
    const float* wb = WsT + j*64 + (mg << 4);
#pragma unroll
    for (int q = 0; q < 4; q++){
      float4 wv = *reinterpret_cast<const float4*>(wb + q*4);
      acc[q*4+0] = fmaf(wv.x, hv, acc[q*4+0]);
      acc[q*4+1] = fmaf(wv.y, hv, acc[q*4+1]);
      acc[q*4+2] = fmaf(wv.z, hv, acc[q*4+2]);
      acc[q*4+3] = fmaf(wv.w, hv, acc[q*4+3]);
    }
  }
#pragma unroll
  for (int i = 0; i < 16; i++){
    int m = (mg << 4) + i;
    size_t zo = ((size_t)(b*64 + m))*1024 + d0 + d;
    u16 ov = 0;
    if (m < 50){
      float val = acc[i];
      uint32_t j = (uint32_t)(((b*50 + m) << 10) + d0 + d);
      TFOut r1 = tf2x32(K1.a, K1.b, 0u, j);
      uint32_t bits = r1.a ^ r1.b;
      float u = __uint_as_float(0x3F800000u | (bits >> 9)) - 1.0f;
      if (u < 0.0464f){
        TFOut r2 = tf2x32(K2.a, K2.b, 0u, j);
        uint32_t nb = r2.a ^ r2.b;
        float ww = __uint_as_float(0x3F800000u | (nb >> 9)) - 1.0f;
        const float lo = -0.99999994f;
        float un = fmaxf(lo, fmaf(ww, 2.0f, lo));
        val += 0.1f * (1.4142135f * erfinv_f32(un));
      }
      ov = f2b(val);
    }
    zb[zo] = ov;
  }
}

// ---------------- K5: Hh = gelu(ZbB @ W1T + b1) (MFMA; bf16 W1T direct staging) ----------------
__global__ __launch_bounds__(256) void kmlp1(const u16* __restrict__ ZbB, const u16* __restrict__ W1T,
                                             const float* __restrict__ b1, u16* __restrict__ Hh){
  int blk = blockIdx.x; int b = blk>>6, c0 = (blk&63)<<6;
  int tid = threadIdx.x, lane = tid&63, w = tid>>6;
  __shared__ __align__(16) u16 az[64*PIT];   // [m][k]
  __shared__ __align__(16) u16 wt[64*PIT];   // [n][k]
  f32x4 acc[4] = {{0,0,0,0},{0,0,0,0},{0,0,0,0},{0,0,0,0}};
  int rr = tid>>2, seg = tid&3;
  for (int kc = 0; kc < 16; kc++){
    int k0 = kc*64;
    __syncthreads();
    { // stage A (ZbB rows)
      const u16* src = ZbB + ((size_t)(b*64 + rr))*1024 + k0 + seg*16;
      *reinterpret_cast<uint4*>(&az[rr*PIT + seg*16])   = *reinterpret_cast<const uint4*>(src);
      *reinterpret_cast<uint4*>(&az[rr*PIT + seg*16+8]) = *reinterpret_cast<const uint4*>(src+8);
    }
    { // stage B (W1T rows, direct bf16 copy)
      const u16* src = W1T + ((size_t)(c0 + rr))*1024 + k0 + seg*16;
      *reinterpret_cast<uint4*>(&wt[rr*PIT + seg*16])   = *reinterpret_cast<const uint4*>(src);
      *reinterpret_cast<uint4*>(&wt[rr*PIT + seg*16+8]) = *reinterpret_cast<const uint4*>(src+8);
    }
    __syncthreads();
#pragma unroll
    for (int s = 0; s < 2; s++){
      short8 a = *reinterpret_cast<const short8*>(&az[(16*w + (lane&15))*PIT + s*32 + (lane>>4)*8]);
#pragma unroll
      for (int t = 0; t < 4; t++){
        short8 bb = *reinterpret_cast<const short8*>(&wt[(t*16 + (lane&15))*PIT + s*32 + (lane>>4)*8]);
        acc[t] = __builtin_amdgcn_mfma_f32_16x16x32_bf16(a, bb, acc[t], 0, 0, 0);
      }
    }
  }
#pragma unroll
  for (int t = 0; t < 4; t++)
#pragma unroll
    for (int r = 0; r < 4; r++){
      int m = 16*w + (lane>>4)*4 + r;
      int n = c0 + t*16 + (lane&15);
      float val = acc[t][r] + b1[n];
      float g = 0.5f * val * (1.0f + erff(val * 0.70710678f));
      Hh[((size_t)(b*64 + m))*4096 + n] = (m < 50) ? f2b(g) : (u16)0;
    }
}

// ---------------- K6: partials of Hh @ W2T (MFMA, K-split x4, bf16 direct staging) ----------------
__global__ __launch_bounds__(256) void kmlp2p(const u16* __restrict__ Hh, const u16* __restrict__ W2T,
                                              float* __restrict__ Mpart){
  int blk = blockIdx.x;            // 512 = b(8) * dt(16) * kt(4)
  int kt = blk & 3, dt = (blk >> 2) & 15, b = blk >> 6;
  int d0 = dt*64;
  int tid = threadIdx.x, lane = tid&63, w = tid>>6;
  __shared__ __align__(16) u16 az[64*PIT];
  __shared__ __align__(16) u16 wt[64*PIT];
  f32x4 acc[4] = {{0,0,0,0},{0,0,0,0},{0,0,0,0},{0,0,0,0}};
  int rr = tid>>2, seg = tid&3;
  for (int kc = 0; kc < 16; kc++){
    int k0 = kt*1024 + kc*64;
    __syncthreads();
    {
      const u16* src = Hh + ((size_t)(b*64 + rr))*4096 + k0 + seg*16;
      *reinterpret_cast<uint4*>(&az[rr*PIT + seg*16])   = *reinterpret_cast<const uint4*>(src);
      *reinterpret_cast<uint4*>(&az[rr*PIT + seg*16+8]) = *reinterpret_cast<const uint4*>(src+8);
    }
    { // stage B (W2T rows, direct bf16 copy)
      const u16* src = W2T + ((size_t)(d0 + rr))*4096 + k0 + seg*16;
      *reinterpret_cast<uint4*>(&wt[rr*PIT + seg*16])   = *reinterpret_cast<const uint4*>(src);
      *reinterpret_cast<uint4*>(&wt[rr*PIT + seg*16+8]) = *reinterpret_cast<const uint4*>(src+8);
    }
    __syncthreads();
#pragma unroll
    for (int s = 0; s < 2; s++){
      short8 a = *reinterpret_cast<const short8*>(&az[(16*w + (lane&15))*PIT + s*32 + (lane>>4)*8]);
#pragma unroll
      for (int t = 0; t < 4; t++){
        short8 bb = *reinterpret_cast<const short8*>(&wt[(t*16 + (lane&15))*PIT + s*32 + (lane>>4)*8]);
        acc[t] = __builtin_amdgcn_mfma_f32_16x16x32_bf16(a, bb, acc[t], 0, 0, 0);
      }
    }
  }
#pragma unroll
  for (int t = 0; t < 4; t++)
#pragma unroll
    for (int r = 0; r < 4; r++){
      int m = 16*w + (lane>>4)*4 + r;
      int d = d0 + t*16 + (lane&15);
      if (m < 50) Mpart[(((size_t)(b*4) + kt)*50 + m)*1024 + d] = acc[t][r];
    }
}

// ---------------- K6b: HfT = tanh(sum partials + b2)^T, bf16, m>=50 zero ----------------
__global__ void kredT(const float* __restrict__ Mpart, const float* __restrict__ b2, u16* __restrict__ HfT){
  int e = blockIdx.x*256 + threadIdx.x;    // grid 2048 -> 524288 over [b][m(64)][d]
  int b = e >> 16, rem = e & 65535;
  int m = rem >> 10, d = rem & 1023;
  u16 outv = 0;
  if (m < 50){
    const float* p = Mpart + (size_t)b*204800 + m*1024 + d;
    float s = p[0] + p[51200] + p[102400] + p[153600] + b2[d];
    outv = f2b(tanhf(s));
  }
  HfT[((size_t)(b*1024) + d)*64 + m] = outv;
}

// ---------------- K7: out = x + C @ Hf (MFMA + LDS-bounced coalesced epilogue) ----------
__global__ __launch_bounds__(256) void kdec2(const float* __restrict__ x, const u16* __restrict__ C,
                                             const u16* __restrict__ HfT, float* __restrict__ out){
  int blk = blockIdx.x;              // 2048 = b(8) * nt(64) * dq(4)
  int dq = blk & 3, nt = (blk >> 2) & 63, b = blk >> 8;
  int n0 = nt << 6;
  int tid = threadIdx.x, lane = tid&63, w = tid>>6;
  __shared__ __align__(16) u16 ctile[64*PIT];   // [tok][m]
  __shared__ __align__(16) u16 htile[64*PIT];   // [d][m]
  __shared__ __align__(16) float obuf[64*68];   // [n][d] f32, pitch 68
  int rr = tid>>2, seg = tid&3;
  {
    const u16* src = C + ((size_t)(b*4096 + n0 + rr))*64 + seg*16;
    *reinterpret_cast<uint4*>(&ctile[rr*PIT + seg*16])   = *reinterpret_cast<const uint4*>(src);
    *reinterpret_cast<uint4*>(&ctile[rr*PIT + seg*16+8]) = *reinterpret_cast<const uint4*>(src+8);
  }
  __syncthreads();
  short8 afrag[2];
#pragma unroll
  for (int s = 0; s < 2; s++)
    afrag[s] = *reinterpret_cast<const short8*>(&ctile[(16*w + (lane&15))*PIT + s*32 + (lane>>4)*8]);
  for (int dt2 = 0; dt2 < 4; dt2++){
    int d0 = (dq*4 + dt2) * 64;
    __syncthreads();
    {
      const u16* src = HfT + ((size_t)(b*1024 + d0 + rr))*64 + seg*16;
      *reinterpret_cast<uint4*>(&htile[rr*PIT + seg*16])   = *reinterpret_cast<const uint4*>(src);
      *reinterpret_cast<uint4*>(&htile[rr*PIT + seg*16+8]) = *reinterpret_cast<const uint4*>(src+8);
    }
    __syncthreads();
    f32x4 acc[4] = {{0,0,0,0},{0,0,0,0},{0,0,0,0},{0,0,0,0}};
#pragma unroll
    for (int s = 0; s < 2; s++){
#pragma unroll
      for (int t = 0; t < 4; t++){
        short8 bb = *reinterpret_cast<const short8*>(&htile[(t*16 + (lane&15))*PIT + s*32 + (lane>>4)*8]);
        acc[t] = __builtin_amdgcn_mfma_f32_16x16x32_bf16(afrag[s], bb, acc[t], 0, 0, 0);
      }
    }
    // scatter acc into LDS [n][d] f32
#pragma unroll
    for (int t = 0; t < 4; t++)
#pragma unroll
      for (int r = 0; r < 4; r++){
        int nl = 16*w + (lane>>4)*4 + r;
        int dl = t*16 + (lane&15);
        obuf[nl*68 + dl] = acc[t][r];
      }
    __syncthreads();
    // coalesced epilogue: 1024 float4-slots (64 rows x 16 slots), 4 per thread
#pragma unroll
    for (int pass = 0; pass < 4; pass++){
      int s2 = tid + pass*256;
      int nl = s2 >> 4, sg = s2 & 15;
      size_t o = ((size_t)(b*4096 + n0 + nl))*1024 + d0 + sg*4;
      float4 xv = *reinterpret_cast<const float4*>(x + o);
      const float* ob = &obuf[nl*68 + sg*4];
      float4 ov;
      ov.x = xv.x + ob[0];
      ov.y = xv.y + ob[1];
      ov.z = xv.z + ob[2];
      ov.w = xv.w + ob[3];
      *reinterpret_cast<float4*>(out + o) = ov;
    }
  }
}

// ---------------- launch ----------------
extern "C" void kernel_launch(void* const* d_in, const int* in_sizes, int n_in,
                              void* d_out, int out_size, void* d_ws, size_t ws_size,
                              hipStream_t stream) {
  (void)in_sizes; (void)n_in; (void)out_size;
  if (ws_size < (size_t)19755264) return;
  const float* x  = (const float*)d_in[0];
  const float* pn = (const float*)d_in[1];
  const float* W1 = (const float*)d_in[8];
  const float* b1 = (const float*)d_in[9];
  const float* W2 = (const float*)d_in[10];
  const float* b2 = (const float*)d_in[11];
  float* out = (float*)d_out;
  char* ws = (char*)d_ws;

  // W1T/W2T bf16 scratch lives in d_out (134 MB): dead before kdec2 fully
  // overwrites out. W1T = 4096x1024 bf16 (8.39MB), W2T = 1024x4096 bf16.
  u16*   W1T = (u16*)d_out;
  u16*   W2T = (u16*)d_out + 4194304;

  // Overlapped ws layout (stream-ordered liveness):
  u16*   C   = (u16*)(ws);                      // [0, 4.19MB)        live kC->kdec2
  u16*   CT  = (u16*)(ws + 4194304);            // CT region 4.19MB:  CT live kC->kHp2
  u16*   ZbB = (u16*)(ws + 4194304 + 1638400);  //   reuses CT space  (kapply2->kmlp1)
  u16*   HfT = (u16*)(ws + 4194304 + 2686976);  //   (kredT->kdec2)
  u16*   Hh  = (u16*)(ws + 8388608);            // Hh region 4.19MB:  Hh live kmlp1->kmlp2p
  u16*   Hb  = (u16*)(ws + 8388608);            //   reuses Hh space  (kredH->kgram)
  float* H   = (float*)(ws + 8388608 + 1048576);//   (kredH->kapply2)
  float* HP  = (float*)(ws + 12582912);         // partials 6.55MB: kHp2->kredH, kmlp2p->kredT
  u16*   PT  = (u16*)(ws + 19136512);           // 131,072 B
  float* G   = (float*)(ws + 19267584);         // 80,000 B
  float* WM  = (float*)(ws + 19347584);         // 80,000 B

  hipLaunchKernelGGL(kprepAll, dim3(2112), dim3(256), 0, stream, pn, PT, W1, W1T, W2, W2T);
  hipLaunchKernelGGL(kC,       dim3(512),  dim3(256), 0, stream, x, PT, C, CT);
  hipLaunchKernelGGL(kHp2,     dim3(512),  dim3(256), 0, stream, x, CT, HP);
  hipLaunchKernelGGL(kredH,    dim3(2048), dim3(256), 0, stream, HP, H, Hb);
  hipLaunchKernelGGL(kgram,    dim3(8),    dim3(256), 0, stream, Hb, G);
  hipLaunchKernelGGL(kns3,     dim3(8),    dim3(256), 0, stream, G, WM);
  hipLaunchKernelGGL(kapply2,  dim3(128),  dim3(256), 0, stream, H, WM, ZbB);
  hipLaunchKernelGGL(kmlp1,    dim3(512),  dim3(256), 0, stream, ZbB, W1T, b1, Hh);
  hipLaunchKernelGGL(kmlp2p,   dim3(512),  dim3(256), 0, stream, Hh, W2T, HP);
  hipLaunchKernelGGL(kredT,    dim3(2048), dim3(256), 0, stream, HP, b2, HfT);
  hipLaunchKernelGGL(kdec2,    dim3(2048), dim3(256), 0, stream, x, C, HfT, out);
}

// Round 12
// 231.665 us; speedup vs baseline: 1.1159x; 1.0674x over previous
//
#include <hip/hip_runtime.h>
#include <stdint.h>
#include <math.h>

#define NS_ITERS 26
#define PIT 72   // LDS row pitch in shorts (144B: 16B-aligned, bank-spread)
#define P2  72   // pitch for kns3 matrices

typedef unsigned short u16;
typedef __attribute__((ext_vector_type(8))) short short8;
typedef __attribute__((ext_vector_type(4))) float f32x4;

__device__ __forceinline__ u16 f2b(float f){
  unsigned u = __float_as_uint(f);
  unsigned r = (u + 0x7FFFu + ((u>>16)&1u)) >> 16;
  return (u16)r;
}
__device__ __forceinline__ float b2f(u16 h){ return __uint_as_float(((unsigned)h)<<16); }
__device__ __forceinline__ unsigned pk2(float lo, float hi){
  return (unsigned)f2b(lo) | ((unsigned)f2b(hi) << 16);
}

// ---------------- threefry2x32 (JAX-compatible) ----------------
__host__ __device__ constexpr uint32_t rotl32(uint32_t v, int n){ return (v<<n)|(v>>(32-n)); }
struct TFOut { uint32_t a, b; };
__host__ __device__ constexpr TFOut tf2x32(uint32_t k0, uint32_t k1, uint32_t x0, uint32_t x1){
  uint32_t ks2 = k0 ^ k1 ^ 0x1BD11BDAu;
  x0 += k0; x1 += k1;
#define TFR(R) x0 += x1; x1 = rotl32(x1,(R)) ^ x0;
  TFR(13) TFR(15) TFR(26) TFR(6)
  x0 += k1; x1 += ks2 + 1u;
  TFR(17) TFR(29) TFR(16) TFR(24)
  x0 += ks2; x1 += k0 + 2u;
  TFR(13) TFR(15) TFR(26) TFR(6)
  x0 += k0; x1 += k1 + 3u;
  TFR(17) TFR(29) TFR(16) TFR(24)
  x0 += k1; x1 += ks2 + 4u;
  TFR(13) TFR(15) TFR(26) TFR(6)
  x0 += ks2; x1 += k0 + 5u;
#undef TFR
  return TFOut{x0, x1};
}

__device__ __forceinline__ float erfinv_f32(float x){
  float w = -log1pf(-x*x);
  float p;
  if (w < 5.0f) {
    w -= 2.5f;
    p = 2.81022636e-08f;
    p = fmaf(p, w, 3.43273939e-07f);
    p = fmaf(p, w, -3.5233877e-06f);
    p = fmaf(p, w, -4.39150654e-06f);
    p = fmaf(p, w, 0.00021858087f);
    p = fmaf(p, w, -0.00125372503f);
    p = fmaf(p, w, -0.00417768164f);
    p = fmaf(p, w, 0.246640727f);
    p = fmaf(p, w, 1.50140941f);
  } else {
    w = sqrtf(w) - 3.0f;
    p = -0.000200214257f;
    p = fmaf(p, w, 0.000100950558f);
    p = fmaf(p, w, 0.00134934322f);
    p = fmaf(p, w, -0.00367342844f);
    p = fmaf(p, w, 0.00573950773f);
    p = fmaf(p, w, -0.0076224613f);
    p = fmaf(p, w, 0.00943887047f);
    p = fmaf(p, w, 1.00167406f);
    p = fmaf(p, w, 2.83297682f);
  }
  return p * x;
}

// ---------------- K1: fused prep ----------------
__global__ __launch_bounds__(256) void kprepAll(const float* __restrict__ prime, u16* __restrict__ PT,
                                                const float* __restrict__ W1, u16* __restrict__ W1T,
                                                const float* __restrict__ W2, u16* __restrict__ W2T){
  int blk = blockIdx.x;
  int tid = threadIdx.x;
  if (blk < 64){
    int m = blk;
    u16* dst = PT + m*1024;
    if (m >= 50){ for (int k = tid; k < 1024; k += 256) dst[k] = 0; return; }
    __shared__ float red[256];
    const float* pr = prime + m*1024;
    float ss = 0.f;
    for (int k = tid; k < 1024; k += 256){ float v = pr[k]; ss = fmaf(v,v,ss); }
    red[tid] = ss; __syncthreads();
    for (int s = 128; s > 0; s >>= 1){ if (tid < s) red[tid] += red[tid+s]; __syncthreads(); }
    float sc = 1.0f / fmaxf(sqrtf(red[0]), 1e-12f);
    for (int k = tid; k < 1024; k += 256) dst[k] = f2b(pr[k]*sc);
    return;
  }
  const float* src; u16* dst; int srcStride, dstStride;
  if (blk < 1088){
    int t = blk - 64;
    int kt2 = t >> 6, nt2 = t & 63;
    src = W1 + (size_t)(kt2*64)*4096 + nt2*64; srcStride = 4096;
    dst = W1T + (size_t)(nt2*64)*1024 + kt2*64; dstStride = 1024;
  } else {
    int t = blk - 1088;
    int kt2 = t >> 4, dt2 = t & 15;
    src = W2 + (size_t)(kt2*64)*1024 + dt2*64; srcStride = 1024;
    dst = W2T + (size_t)(dt2*64)*4096 + kt2*64; dstStride = 4096;
  }
  __shared__ __align__(16) u16 ts[64*PIT];   // [src_row(k)][src_col(n)]
  int r = tid>>2, sseg = tid&3;
  {
    const float* s0 = src + (size_t)r*srcStride + sseg*16;
    unsigned p[8];
#pragma unroll
    for (int i = 0; i < 4; i++){
      float4 v = *reinterpret_cast<const float4*>(s0 + i*4);
      p[2*i]   = pk2(v.x, v.y);
      p[2*i+1] = pk2(v.z, v.w);
    }
    uint4 w0; w0.x=p[0]; w0.y=p[1]; w0.z=p[2]; w0.w=p[3];
    uint4 w1; w1.x=p[4]; w1.y=p[5]; w1.z=p[6]; w1.w=p[7];
    *reinterpret_cast<uint4*>(&ts[r*PIT + sseg*16])     = w0;
    *reinterpret_cast<uint4*>(&ts[r*PIT + sseg*16 + 8]) = w1;
  }
  __syncthreads();
  {
    int n2 = tid>>2, kseg = tid&3;
    unsigned q[8];
#pragma unroll
    for (int j = 0; j < 8; j++){
      u16 lo = ts[(kseg*16 + 2*j)*PIT + n2];
      u16 hi = ts[(kseg*16 + 2*j+1)*PIT + n2];
      q[j] = (unsigned)lo | ((unsigned)hi<<16);
    }
    u16* d2 = dst + (size_t)n2*dstStride + kseg*16;
    uint4 w0; w0.x=q[0]; w0.y=q[1]; w0.z=q[2]; w0.w=q[3];
    uint4 w1; w1.x=q[4]; w1.y=q[5]; w1.z=q[6]; w1.w=q[7];
    *reinterpret_cast<uint4*>(d2)   = w0;
    *reinterpret_cast<uint4*>(d2+8) = w1;
  }
}

// ---------------- K2: MFMA logits + softmax; dbuf LDS, 1 barrier/chunk, in-reg sumsq ----
__global__ __launch_bounds__(256) void kC(const float* __restrict__ x, const u16* __restrict__ PT,
                                          u16* __restrict__ C, u16* __restrict__ CT){
  int blk = blockIdx.x; int b = blk>>6, n0 = (blk&63)<<6;
  int tid = threadIdx.x, lane = tid&63, w = tid>>6;
  __shared__ __align__(16) u16 xs[2][64*PIT];
  __shared__ __align__(16) u16 ps[2][64*PIT];
  __shared__ float sqn[64];
  f32x4 acc[4] = {{0,0,0,0},{0,0,0,0},{0,0,0,0},{0,0,0,0}};
  float sqa = 0.f;
  int stok = tid>>2, sseg = tid&3;                 // staging map
  const float* xb = x + ((size_t)(b*4096 + n0))*1024;
  for (int kc = 0; kc < 16; kc++){
    int k0 = kc*64, cb = kc & 1;
    { // stage x (cvt bf16) + in-register sumsq (these 16 values belong to token stok)
      const float* src = xb + (size_t)stok*1024 + k0 + sseg*16;
      unsigned p[8];
#pragma unroll
      for (int i = 0; i < 4; i++){
        float4 v = *reinterpret_cast<const float4*>(src + i*4);
        sqa = fmaf(v.x,v.x,sqa); sqa = fmaf(v.y,v.y,sqa);
        sqa = fmaf(v.z,v.z,sqa); sqa = fmaf(v.w,v.w,sqa);
        p[2*i]   = pk2(v.x, v.y);
        p[2*i+1] = pk2(v.z, v.w);
      }
      uint4 w0; w0.x=p[0]; w0.y=p[1]; w0.z=p[2]; w0.w=p[3];
      uint4 w1; w1.x=p[4]; w1.y=p[5]; w1.z=p[6]; w1.w=p[7];
      *reinterpret_cast<uint4*>(&xs[cb][stok*PIT + sseg*16])     = w0;
      *reinterpret_cast<uint4*>(&xs[cb][stok*PIT + sseg*16 + 8]) = w1;
    }
    { // stage P rows
      const u16* src = PT + (size_t)stok*1024 + k0 + sseg*16;
      *reinterpret_cast<uint4*>(&ps[cb][stok*PIT + sseg*16])   = *reinterpret_cast<const uint4*>(src);
      *reinterpret_cast<uint4*>(&ps[cb][stok*PIT + sseg*16+8]) = *reinterpret_cast<const uint4*>(src+8);
    }
    __syncthreads();
#pragma unroll
    for (int s = 0; s < 2; s++){
      short8 a = *reinterpret_cast<const short8*>(&xs[cb][(16*w + (lane&15))*PIT + s*32 + (lane>>4)*8]);
#pragma unroll
      for (int t = 0; t < 4; t++){
        short8 bb = *reinterpret_cast<const short8*>(&ps[cb][(t*16 + (lane&15))*PIT + s*32 + (lane>>4)*8]);
        acc[t] = __builtin_amdgcn_mfma_f32_16x16x32_bf16(a, bb, acc[t], 0, 0, 0);
      }
    }
  }
  // reduce sumsq across the 4 threads sharing stok (adjacent lanes)
  sqa += __shfl_xor(sqa, 1, 64);
  sqa += __shfl_xor(sqa, 2, 64);
  if ((tid & 3) == 0) sqn[stok] = 10.0f / fmaxf(sqrtf(sqa), 1e-12f);
  __syncthreads();
  // softmax per token (rows spread over lane>>4 groups; primes = lane&15 + 16*t)
  u16* cl = xs[0];  // reuse (MFMA phase over; only xs[1]/ps[1] were last read targets per-wave,
                    // and all waves passed the final barrier before any cl write lands pre-next-barrier read)
#pragma unroll
  for (int r = 0; r < 4; r++){
    int gt = 16*w + (lane>>4)*4 + r;
    float scale = sqn[gt];
    float v[4];
#pragma unroll
    for (int t = 0; t < 4; t++) v[t] = acc[t][r] * scale;
    if ((lane&15) >= 2) v[3] = -1e30f;
    float mx = fmaxf(fmaxf(v[0],v[1]), fmaxf(v[2],v[3]));
#pragma unroll
    for (int off = 1; off < 16; off <<= 1) mx = fmaxf(mx, __shfl_xor(mx, off, 64));
    float e[4], sum = 0.f;
#pragma unroll
    for (int t = 0; t < 4; t++){ e[t] = __expf(v[t]-mx); sum += e[t]; }
#pragma unroll
    for (int off = 1; off < 16; off <<= 1) sum += __shfl_xor(sum, off, 64);
    float inv = 1.0f / sum;
#pragma unroll
    for (int t = 0; t < 4; t++) cl[gt*PIT + t*16 + (lane&15)] = f2b(e[t]*inv);
  }
  __syncthreads();
  { // C write (row-major) b128
    u16* dst = C + ((size_t)(b*4096 + n0 + stok))*64 + sseg*16;
    *reinterpret_cast<uint4*>(dst)   = *reinterpret_cast<const uint4*>(&cl[stok*PIT + sseg*16]);
    *reinterpret_cast<uint4*>(dst+8) = *reinterpret_cast<const uint4*>(&cl[stok*PIT + sseg*16+8]);
  }
  { // CT write (transposed)
    int m = tid>>2, nseg = tid&3;
    unsigned vs[8];
#pragma unroll
    for (int j = 0; j < 8; j++){
      u16 lo = cl[(nseg*16 + 2*j)*PIT + m];
      u16 hi = cl[(nseg*16 + 2*j+1)*PIT + m];
      vs[j] = (unsigned)lo | ((unsigned)hi<<16);
    }
    u16* dst = CT + ((size_t)(b*64 + m))*4096 + n0 + nseg*16;
    uint4 w0; w0.x=vs[0]; w0.y=vs[1]; w0.z=vs[2]; w0.w=vs[3];
    uint4 w1; w1.x=vs[4]; w1.y=vs[5]; w1.z=vs[6]; w1.w=vs[7];
    *reinterpret_cast<uint4*>(dst)   = w0;
    *reinterpret_cast<uint4*>(dst+8) = w1;
  }
}

// ---------------- K3: H_prime partials (MFMA, K-split x4; dbuf LDS, 1 barrier/chunk) ----
__global__ __launch_bounds__(256) void kHp2(const float* __restrict__ x, const u16* __restrict__ CT,
                                            float* __restrict__ Hpart){
  int blk = blockIdx.x;            // 512 = b(8) * dt(16) * kt(4)
  int kt = blk & 3, dt = (blk >> 2) & 15, b = blk >> 6;
  int d0 = dt*64;
  int tid = threadIdx.x, lane = tid&63, w = tid>>6;
  __shared__ __align__(16) u16 cs[2][64*PIT];    // [m][n]
  __shared__ __align__(16) u16 xt[2][64*PIT];    // [d][n]
  f32x4 acc[4] = {{0,0,0,0},{0,0,0,0},{0,0,0,0},{0,0,0,0}};
  int nn = tid>>2, seg = tid&3;
  int np = tid & 31, dsg = tid >> 5;          // n-pair staging map
  for (int nc = 0; nc < 16; nc++){
    int n0 = kt*1024 + nc*64, cb = nc & 1;
    { // stage CT rows [m][n-chunk]
      const u16* src = CT + ((size_t)(b*64 + nn))*4096 + n0 + seg*16;  // nn = m here
      *reinterpret_cast<uint4*>(&cs[cb][nn*PIT + seg*16])   = *reinterpret_cast<const uint4*>(src);
      *reinterpret_cast<uint4*>(&cs[cb][nn*PIT + seg*16+8]) = *reinterpret_cast<const uint4*>(src+8);
    }
    { // stage x transposed: n-paired packed u32 writes (conflict-free)
      const float* s0 = x + ((size_t)(b*4096 + n0 + 2*np))*1024 + d0 + dsg*8;
      const float* s1 = s0 + 1024;
      float4 a0 = *reinterpret_cast<const float4*>(s0);
      float4 a1 = *reinterpret_cast<const float4*>(s0+4);
      float4 c0v = *reinterpret_cast<const float4*>(s1);
      float4 c1v = *reinterpret_cast<const float4*>(s1+4);
      float av[8] = {a0.x,a0.y,a0.z,a0.w,a1.x,a1.y,a1.z,a1.w};
      float cv[8] = {c0v.x,c0v.y,c0v.z,c0v.w,c1v.x,c1v.y,c1v.z,c1v.w};
#pragma unroll
      for (int j2 = 0; j2 < 8; j2++){
        int dd = dsg*8 + j2;
        *reinterpret_cast<unsigned*>(&xt[cb][dd*PIT + 2*np]) = pk2(av[j2], cv[j2]);
      }
    }
    __syncthreads();
#pragma unroll
    for (int s = 0; s < 2; s++){
      short8 a = *reinterpret_cast<const short8*>(&cs[cb][(16*w + (lane&15))*PIT + s*32 + (lane>>4)*8]);
#pragma unroll
      for (int t = 0; t < 4; t++){
        short8 bb = *reinterpret_cast<const short8*>(&xt[cb][(t*16 + (lane&15))*PIT + s*32 + (lane>>4)*8]);
        acc[t] = __builtin_amdgcn_mfma_f32_16x16x32_bf16(a, bb, acc[t], 0, 0, 0);
      }
    }
  }
#pragma unroll
  for (int t = 0; t < 4; t++)
#pragma unroll
    for (int r = 0; r < 4; r++){
      int m = 16*w + (lane>>4)*4 + r;
      int d = d0 + t*16 + (lane&15);
      if (m < 50) Hpart[(((size_t)(b*4) + kt)*50 + m)*1024 + d] = acc[t][r];
    }
}

// ---------------- K3b: reduce partials -> H f32 + Hb bf16, pad rows zeroed (grid 2048) ----
__global__ void kredH(const float* __restrict__ Hpart, float* __restrict__ H, u16* __restrict__ Hb){
  int e = blockIdx.x*256 + threadIdx.x;    // grid 2048 -> 524288 over [b][m(64)][d]
  int b = e >> 16, rem = e & 65535;
  int m = rem >> 10, d = rem & 1023;
  size_t o = ((size_t)(b*64 + m))*1024 + d;
  if (m < 50){
    const float* p = Hpart + (size_t)b*204800 + m*1024 + d;
    float s = p[0] + p[51200] + p[102400] + p[153600];
    H[o] = s;
    Hb[o] = f2b(s);
  } else {
    Hb[o] = 0;
  }
}

// ---------------- K4a: Gram via MFMA: G = Hb Hb^T ----------------
__global__ __launch_bounds__(256) void kgram(const u16* __restrict__ Hb, float* __restrict__ G){
  int b = blockIdx.x;
  int tid = threadIdx.x, lane = tid&63, w = tid>>6;
  __shared__ __align__(16) u16 hs[64*PIT];
  f32x4 acc[4] = {{0,0,0,0},{0,0,0,0},{0,0,0,0},{0,0,0,0}};
  int m = tid>>2, seg = tid&3;
  for (int kc = 0; kc < 16; kc++){
    int k0 = kc*64;
    __syncthreads();
    const u16* src = Hb + ((size_t)(b*64 + m))*1024 + k0 + seg*16;
    *reinterpret_cast<uint4*>(&hs[m*PIT + seg*16])   = *reinterpret_cast<const uint4*>(src);
    *reinterpret_cast<uint4*>(&hs[m*PIT + seg*16+8]) = *reinterpret_cast<const uint4*>(src+8);
    __syncthreads();
#pragma unroll
    for (int s = 0; s < 2; s++){
      short8 a = *reinterpret_cast<const short8*>(&hs[(16*w + (lane&15))*PIT + s*32 + (lane>>4)*8]);
#pragma unroll
      for (int t = 0; t < 4; t++){
        short8 bb = *reinterpret_cast<const short8*>(&hs[(t*16 + (lane&15))*PIT + s*32 + (lane>>4)*8]);
        acc[t] = __builtin_amdgcn_mfma_f32_16x16x32_bf16(a, bb, acc[t], 0, 0, 0);
      }
    }
  }
#pragma unroll
  for (int t = 0; t < 4; t++)
#pragma unroll
    for (int r = 0; r < 4; r++){
      int i = 16*w + (lane>>4)*4 + r;
      int j = t*16 + (lane&15);
      if (i < 50 && j < 50) G[(size_t)b*2500 + i*50 + j] = acc[t][r];
    }
}

// ---------------- K4b: Newton-Schulz invsqrt via MFMA (bf16 fragments, 64x64 padded) ----
__global__ __launch_bounds__(256) void kns3(const float* __restrict__ G, float* __restrict__ Wm){
  int b = blockIdx.x;
  __shared__ __align__(16) u16 Yr[2][64*P2], Yc[2][64*P2], Zr[2][64*P2], Zc[2][64*P2];
  __shared__ __align__(16) u16 Tr[64*P2], Tc[64*P2];
  __shared__ float sv[2];
  int tid = threadIdx.x, lane = tid&63, w = tid>>6;
  int lr = lane>>4, lc = lane&15;
  int row0 = 16*w;
  const float* Gb = G + (size_t)b*2500;
  if (tid < 64){
    float v = (tid < 50) ? Gb[tid*50+tid] : 0.f;
    for (int off = 1; off < 64; off <<= 1) v += __shfl_xor(v, off, 64);
    if (tid == 0){ sv[0] = 1.0f / v; sv[1] = rsqrtf(v); }
  }
  __syncthreads();
  float rs = sv[0];
  for (int idx = tid; idx < 4096; idx += 256){
    int r = idx>>6, c = idx&63;
    float yv = (r<50 && c<50) ? Gb[r*50+c]*rs : ((r==c) ? 1.f : 0.f);
    float zv = (r==c) ? 1.f : 0.f;
    u16 yb = f2b(yv), zb = f2b(zv);
    Yr[0][r*P2+c] = yb; Yc[0][c*P2+r] = yb;
    Zr[0][r*P2+c] = zb; Zc[0][c*P2+r] = zb;
  }
  __syncthreads();
  for (int it = 0; it < NS_ITERS; it++){
    int cur = it & 1, nxt = cur ^ 1;
    { // phase 1: T = 1.5I - 0.5 * Z@Y
      short8 a0 = *reinterpret_cast<const short8*>(&Zr[cur][(row0+lc)*P2 + lr*8]);
      short8 a1 = *reinterpret_cast<const short8*>(&Zr[cur][(row0+lc)*P2 + 32 + lr*8]);
      f32x4 acc[4] = {{0,0,0,0},{0,0,0,0},{0,0,0,0},{0,0,0,0}};
#pragma unroll
      for (int t = 0; t < 4; t++){
        short8 b0 = *reinterpret_cast<const short8*>(&Yc[cur][(t*16+lc)*P2 + lr*8]);
        short8 b1 = *reinterpret_cast<const short8*>(&Yc[cur][(t*16+lc)*P2 + 32 + lr*8]);
        acc[t] = __builtin_amdgcn_mfma_f32_16x16x32_bf16(a0, b0, acc[t], 0, 0, 0);
        acc[t] = __builtin_amdgcn_mfma_f32_16x16x32_bf16(a1, b1, acc[t], 0, 0, 0);
      }
#pragma unroll
      for (int t = 0; t < 4; t++)
#pragma unroll
        for (int r = 0; r < 4; r++){
          int row = row0 + lr*4 + r, col = t*16 + lc;
          float v = ((row==col) ? 1.5f : 0.f) - 0.5f*acc[t][r];
          u16 h = f2b(v);
          Tr[row*P2+col] = h; Tc[col*P2+row] = h;
        }
    }
    __syncthreads();
    { // phase 2: Y' = Y@T ; Z' = T@Z
      short8 ya0 = *reinterpret_cast<const short8*>(&Yr[cur][(row0+lc)*P2 + lr*8]);
      short8 ya1 = *reinterpret_cast<const short8*>(&Yr[cur][(row0+lc)*P2 + 32 + lr*8]);
      short8 ta0 = *reinterpret_cast<const short8*>(&Tr[(row0+lc)*P2 + lr*8]);
      short8 ta1 = *reinterpret_cast<const short8*>(&Tr[(row0+lc)*P2 + 32 + lr*8]);
      f32x4 accY[4] = {{0,0,0,0},{0,0,0,0},{0,0,0,0},{0,0,0,0}};
      f32x4 accZ[4] = {{0,0,0,0},{0,0,0,0},{0,0,0,0},{0,0,0,0}};
#pragma unroll
      for (int t = 0; t < 4; t++){
        short8 tb0 = *reinterpret_cast<const short8*>(&Tc[(t*16+lc)*P2 + lr*8]);
        short8 tb1 = *reinterpret_cast<const short8*>(&Tc[(t*16+lc)*P2 + 32 + lr*8]);
        accY[t] = __builtin_amdgcn_mfma_f32_16x16x32_bf16(ya0, tb0, accY[t], 0, 0, 0);
        accY[t] = __builtin_amdgcn_mfma_f32_16x16x32_bf16(ya1, tb1, accY[t], 0, 0, 0);
        short8 zb0 = *reinterpret_cast<const short8*>(&Zc[cur][(t*16+lc)*P2 + lr*8]);
        short8 zb1 = *reinterpret_cast<const short8*>(&Zc[cur][(t*16+lc)*P2 + 32 + lr*8]);
        accZ[t] = __builtin_amdgcn_mfma_f32_16x16x32_bf16(ta0, zb0, accZ[t], 0, 0, 0);
        accZ[t] = __builtin_amdgcn_mfma_f32_16x16x32_bf16(ta1, zb1, accZ[t], 0, 0, 0);
      }
#pragma unroll
      for (int t = 0; t < 4; t++)
#pragma unroll
        for (int r = 0; r < 4; r++){
          int row = row0 + lr*4 + r, col = t*16 + lc;
          u16 hy = f2b(accY[t][r]);
          u16 hz = f2b(accZ[t][r]);
          Yr[nxt][row*P2+col] = hy; Yc[nxt][col*P2+row] = hy;
          Zr[nxt][row*P2+col] = hz; Zc[nxt][col*P2+row] = hz;
        }
    }
    __syncthreads();
  }
  float rss = sv[1];
  int fin = NS_ITERS & 1;
  for (int idx = tid; idx < 2500; idx += 256){
    int r = idx/50, c = idx - r*50;
    Wm[(size_t)b*2500 + idx] = b2f(Zr[fin][r*P2+c]) * rss;
  }
}

// ---------------- K4c: H_logic = Wm @ H + threefry noise -> ZbB bf16 (fused) ----------------
__global__ __launch_bounds__(256) void kapply2(const float* __restrict__ H, const float* __restrict__ Wm,
                                               u16* __restrict__ zb){
  TFOut K1 = tf2x32(0u, 42u, 0u, 0u);
  TFOut K2 = tf2x32(0u, 42u, 0u, 1u);
  int blk = blockIdx.x;          // 128 = b(8) * dt(16)
  int dt = blk & 15, b = blk >> 4;
  int d0 = dt*64;
  int tid = threadIdx.x;
  int d = tid & 63, mg = tid >> 6;
  __shared__ __align__(16) float WsT[50*64];
  __shared__ float Hs[50*65];
  for (int idx = tid; idx < 3200; idx += 256){
    int j = idx >> 6, c = idx & 63;
    WsT[idx] = (c < 50) ? Wm[(size_t)b*2500 + c*50 + j] : 0.f;
  }
  for (int idx = tid; idx < 3200; idx += 256){
    int j = idx >> 6, c = idx & 63;
    Hs[j*65 + c] = H[((size_t)(b*64) + j)*1024 + d0 + c];
  }
  __syncthreads();
  float acc[16];
#pragma unroll
  for (int i = 0; i < 16; i++) acc[i] = 0.f;
  for (int j = 0; j < 50; j++){
    float hv = Hs[j*65 + d];
    const float* wb = WsT + j*64 + (mg << 4);
#pragma unroll
    for (int q = 0; q < 4; q++){
      float4 wv = *reinterpret_cast<const float4*>(wb + q*4);
      acc[q*4+0] = fmaf(wv.x, hv, acc[q*4+0]);
      acc[q*4+1] = fmaf(wv.y, hv, acc[q*4+1]);
      acc[q*4+2] = fmaf(wv.z, hv, acc[q*4+2]);
      acc[q*4+3] = fmaf(wv.w, hv, acc[q*4+3]);
    }
  }
#pragma unroll
  for (int i = 0; i < 16; i++){
    int m = (mg << 4) + i;
    size_t zo = ((size_t)(b*64 + m))*1024 + d0 + d;
    u16 ov = 0;
    if (m < 50){
      float val = acc[i];
      uint32_t j = (uint32_t)(((b*50 + m) << 10) + d0 + d);
      TFOut r1 = tf2x32(K1.a, K1.b, 0u, j);
      uint32_t bits = r1.a ^ r1.b;
      float u = __uint_as_float(0x3F800000u | (bits >> 9)) - 1.0f;
      if (u < 0.0464f){
        TFOut r2 = tf2x32(K2.a, K2.b, 0u, j);
        uint32_t nb = r2.a ^ r2.b;
        float ww = __uint_as_float(0x3F800000u | (nb >> 9)) - 1.0f;
        const float lo = -0.99999994f;
        float un = fmaxf(lo, fmaf(ww, 2.0f, lo));
        val += 0.1f * (1.4142135f * erfinv_f32(un));
      }
      ov = f2b(val);
    }
    zb[zo] = ov;
  }
}

// ---------------- K5: Hh = gelu(ZbB @ W1T + b1) (MFMA; dbuf LDS, 1 barrier/chunk) ----------------
__global__ __launch_bounds__(256) void kmlp1(const u16* __restrict__ ZbB, const u16* __restrict__ W1T,
                                             const float* __restrict__ b1, u16* __restrict__ Hh){
  int blk = blockIdx.x; int b = blk>>6, c0 = (blk&63)<<6;
  int tid = threadIdx.x, lane = tid&63, w = tid>>6;
  __shared__ __align__(16) u16 az[2][64*PIT];   // [m][k]
  __shared__ __align__(16) u16 wt[2][64*PIT];   // [n][k]
  f32x4 acc[4] = {{0,0,0,0},{0,0,0,0},{0,0,0,0},{0,0,0,0}};
  int rr = tid>>2, seg = tid&3;
  for (int kc = 0; kc < 16; kc++){
    int k0 = kc*64, cb = kc & 1;
    { // stage A (ZbB rows)
      const u16* src = ZbB + ((size_t)(b*64 + rr))*1024 + k0 + seg*16;
      *reinterpret_cast<uint4*>(&az[cb][rr*PIT + seg*16])   = *reinterpret_cast<const uint4*>(src);
      *reinterpret_cast<uint4*>(&az[cb][rr*PIT + seg*16+8]) = *reinterpret_cast<const uint4*>(src+8);
    }
    { // stage B (W1T rows, direct bf16 copy)
      const u16* src = W1T + ((size_t)(c0 + rr))*1024 + k0 + seg*16;
      *reinterpret_cast<uint4*>(&wt[cb][rr*PIT + seg*16])   = *reinterpret_cast<const uint4*>(src);
      *reinterpret_cast<uint4*>(&wt[cb][rr*PIT + seg*16+8]) = *reinterpret_cast<const uint4*>(src+8);
    }
    __syncthreads();
#pragma unroll
    for (int s = 0; s < 2; s++){
      short8 a = *reinterpret_cast<const short8*>(&az[cb][(16*w + (lane&15))*PIT + s*32 + (lane>>4)*8]);
#pragma unroll
      for (int t = 0; t < 4; t++){
        short8 bb = *reinterpret_cast<const short8*>(&wt[cb][(t*16 + (lane&15))*PIT + s*32 + (lane>>4)*8]);
        acc[t] = __builtin_amdgcn_mfma_f32_16x16x32_bf16(a, bb, acc[t], 0, 0, 0);
      }
    }
  }
#pragma unroll
  for (int t = 0; t < 4; t++)
#pragma unroll
    for (int r = 0; r < 4; r++){
      int m = 16*w + (lane>>4)*4 + r;
      int n = c0 + t*16 + (lane&15);
      float val = acc[t][r] + b1[n];
      float g = 0.5f * val * (1.0f + erff(val * 0.70710678f));
      Hh[((size_t)(b*64 + m))*4096 + n] = (m < 50) ? f2b(g) : (u16)0;
    }
}

// ---------------- K6: partials of Hh @ W2T (MFMA, K-split x4; dbuf LDS, 1 barrier/chunk) ----
__global__ __launch_bounds__(256) void kmlp2p(const u16* __restrict__ Hh, const u16* __restrict__ W2T,
                                              float* __restrict__ Mpart){
  int blk = blockIdx.x;            // 512 = b(8) * dt(16) * kt(4)
  int kt = blk & 3, dt = (blk >> 2) & 15, b = blk >> 6;
  int d0 = dt*64;
  int tid = threadIdx.x, lane = tid&63, w = tid>>6;
  __shared__ __align__(16) u16 az[2][64*PIT];
  __shared__ __align__(16) u16 wt[2][64*PIT];
  f32x4 acc[4] = {{0,0,0,0},{0,0,0,0},{0,0,0,0},{0,0,0,0}};
  int rr = tid>>2, seg = tid&3;
  for (int kc = 0; kc < 16; kc++){
    int k0 = kt*1024 + kc*64, cb = kc & 1;
    {
      const u16* src = Hh + ((size_t)(b*64 + rr))*4096 + k0 + seg*16;
      *reinterpret_cast<uint4*>(&az[cb][rr*PIT + seg*16])   = *reinterpret_cast<const uint4*>(src);
      *reinterpret_cast<uint4*>(&az[cb][rr*PIT + seg*16+8]) = *reinterpret_cast<const uint4*>(src+8);
    }
    { // stage B (W2T rows, direct bf16 copy)
      const u16* src = W2T + ((size_t)(d0 + rr))*4096 + k0 + seg*16;
      *reinterpret_cast<uint4*>(&wt[cb][rr*PIT + seg*16])   = *reinterpret_cast<const uint4*>(src);
      *reinterpret_cast<uint4*>(&wt[cb][rr*PIT + seg*16+8]) = *reinterpret_cast<const uint4*>(src+8);
    }
    __syncthreads();
#pragma unroll
    for (int s = 0; s < 2; s++){
      short8 a = *reinterpret_cast<const short8*>(&az[cb][(16*w + (lane&15))*PIT + s*32 + (lane>>4)*8]);
#pragma unroll
      for (int t = 0; t < 4; t++){
        short8 bb = *reinterpret_cast<const short8*>(&wt[cb][(t*16 + (lane&15))*PIT + s*32 + (lane>>4)*8]);
        acc[t] = __builtin_amdgcn_mfma_f32_16x16x32_bf16(a, bb, acc[t], 0, 0, 0);
      }
    }
  }
#pragma unroll
  for (int t = 0; t < 4; t++)
#pragma unroll
    for (int r = 0; r < 4; r++){
      int m = 16*w + (lane>>4)*4 + r;
      int d = d0 + t*16 + (lane&15);
      if (m < 50) Mpart[(((size_t)(b*4) + kt)*50 + m)*1024 + d] = acc[t][r];
    }
}

// ---------------- K6b: HfT = tanh(sum partials + b2)^T, bf16, m>=50 zero ----------------
__global__ void kredT(const float* __restrict__ Mpart, const float* __restrict__ b2, u16* __restrict__ HfT){
  int e = blockIdx.x*256 + threadIdx.x;    // grid 2048 -> 524288 over [b][m(64)][d]
  int b = e >> 16, rem = e & 65535;
  int m = rem >> 10, d = rem & 1023;
  u16 outv = 0;
  if (m < 50){
    const float* p = Mpart + (size_t)b*204800 + m*1024 + d;
    float s = p[0] + p[51200] + p[102400] + p[153600] + b2[d];
    outv = f2b(tanhf(s));
  }
  HfT[((size_t)(b*1024) + d)*64 + m] = outv;
}

// ---------------- K7: out = x + C @ Hf (MFMA + LDS-bounced coalesced epilogue) ----------
__global__ __launch_bounds__(256) void kdec2(const float* __restrict__ x, const u16* __restrict__ C,
                                             const u16* __restrict__ HfT, float* __restrict__ out){
  int blk = blockIdx.x;              // 2048 = b(8) * nt(64) * dq(4)
  int dq = blk & 3, nt = (blk >> 2) & 63, b = blk >> 8;
  int n0 = nt << 6;
  int tid = threadIdx.x, lane = tid&63, w = tid>>6;
  __shared__ __align__(16) u16 ctile[64*PIT];   // [tok][m]
  __shared__ __align__(16) u16 htile[64*PIT];   // [d][m]
  __shared__ __align__(16) float obuf[64*68];   // [n][d] f32, pitch 68
  int rr = tid>>2, seg = tid&3;
  {
    const u16* src = C + ((size_t)(b*4096 + n0 + rr))*64 + seg*16;
    *reinterpret_cast<uint4*>(&ctile[rr*PIT + seg*16])   = *reinterpret_cast<const uint4*>(src);
    *reinterpret_cast<uint4*>(&ctile[rr*PIT + seg*16+8]) = *reinterpret_cast<const uint4*>(src+8);
  }
  __syncthreads();
  short8 afrag[2];
#pragma unroll
  for (int s = 0; s < 2; s++)
    afrag[s] = *reinterpret_cast<const short8*>(&ctile[(16*w + (lane&15))*PIT + s*32 + (lane>>4)*8]);
  for (int dt2 = 0; dt2 < 4; dt2++){
    int d0 = (dq*4 + dt2) * 64;
    __syncthreads();
    {
      const u16* src = HfT + ((size_t)(b*1024 + d0 + rr))*64 + seg*16;
      *reinterpret_cast<uint4*>(&htile[rr*PIT + seg*16])   = *reinterpret_cast<const uint4*>(src);
      *reinterpret_cast<uint4*>(&htile[rr*PIT + seg*16+8]) = *reinterpret_cast<const uint4*>(src+8);
    }
    __syncthreads();
    f32x4 acc[4] = {{0,0,0,0},{0,0,0,0},{0,0,0,0},{0,0,0,0}};
#pragma unroll
    for (int s = 0; s < 2; s++){
#pragma unroll
      for (int t = 0; t < 4; t++){
        short8 bb = *reinterpret_cast<const short8*>(&htile[(t*16 + (lane&15))*PIT + s*32 + (lane>>4)*8]);
        acc[t] = __builtin_amdgcn_mfma_f32_16x16x32_bf16(afrag[s], bb, acc[t], 0, 0, 0);
      }
    }
    // scatter acc into LDS [n][d] f32
#pragma unroll
    for (int t = 0; t < 4; t++)
#pragma unroll
      for (int r = 0; r < 4; r++){
        int nl = 16*w + (lane>>4)*4 + r;
        int dl = t*16 + (lane&15);
        obuf[nl*68 + dl] = acc[t][r];
      }
    __syncthreads();
    // coalesced epilogue: 1024 float4-slots (64 rows x 16 slots), 4 per thread
#pragma unroll
    for (int pass = 0; pass < 4; pass++){
      int s2 = tid + pass*256;
      int nl = s2 >> 4, sg = s2 & 15;
      size_t o = ((size_t)(b*4096 + n0 + nl))*1024 + d0 + sg*4;
      float4 xv = *reinterpret_cast<const float4*>(x + o);
      const float* ob = &obuf[nl*68 + sg*4];
      float4 ov;
      ov.x = xv.x + ob[0];
      ov.y = xv.y + ob[1];
      ov.z = xv.z + ob[2];
      ov.w = xv.w + ob[3];
      *reinterpret_cast<float4*>(out + o) = ov;
    }
  }
}

// ---------------- launch ----------------
extern "C" void kernel_launch(void* const* d_in, const int* in_sizes, int n_in,
                              void* d_out, int out_size, void* d_ws, size_t ws_size,
                              hipStream_t stream) {
  (void)in_sizes; (void)n_in; (void)out_size;
  if (ws_size < (size_t)19755264) return;
  const float* x  = (const float*)d_in[0];
  const float* pn = (const float*)d_in[1];
  const float* W1 = (const float*)d_in[8];
  const float* b1 = (const float*)d_in[9];
  const float* W2 = (const float*)d_in[10];
  const float* b2 = (const float*)d_in[11];
  float* out = (float*)d_out;
  char* ws = (char*)d_ws;

  // W1T/W2T bf16 scratch lives in d_out (134 MB): dead before kdec2 fully
  // overwrites out. W1T = 4096x1024 bf16 (8.39MB), W2T = 1024x4096 bf16.
  u16*   W1T = (u16*)d_out;
  u16*   W2T = (u16*)d_out + 4194304;

  // Overlapped ws layout (stream-ordered liveness):
  u16*   C   = (u16*)(ws);                      // [0, 4.19MB)        live kC->kdec2
  u16*   CT  = (u16*)(ws + 4194304);            // CT region 4.19MB:  CT live kC->kHp2
  u16*   ZbB = (u16*)(ws + 4194304 + 1638400);  //   reuses CT space  (kapply2->kmlp1)
  u16*   HfT = (u16*)(ws + 4194304 + 2686976);  //   (kredT->kdec2)
  u16*   Hh  = (u16*)(ws + 8388608);            // Hh region 4.19MB:  Hh live kmlp1->kmlp2p
  u16*   Hb  = (u16*)(ws + 8388608);            //   reuses Hh space  (kredH->kgram)
  float* H   = (float*)(ws + 8388608 + 1048576);//   (kredH->kapply2)
  float* HP  = (float*)(ws + 12582912);         // partials 6.55MB: kHp2->kredH, kmlp2p->kredT
  u16*   PT  = (u16*)(ws + 19136512);           // 131,072 B
  float* G   = (float*)(ws + 19267584);         // 80,000 B
  float* WM  = (float*)(ws + 19347584);         // 80,000 B

  hipLaunchKernelGGL(kprepAll, dim3(2112), dim3(256), 0, stream, pn, PT, W1, W1T, W2, W2T);
  hipLaunchKernelGGL(kC,       dim3(512),  dim3(256), 0, stream, x, PT, C, CT);
  hipLaunchKernelGGL(kHp2,     dim3(512),  dim3(256), 0, stream, x, CT, HP);
  hipLaunchKernelGGL(kredH,    dim3(2048), dim3(256), 0, stream, HP, H, Hb);
  hipLaunchKernelGGL(kgram,    dim3(8),    dim3(256), 0, stream, Hb, G);
  hipLaunchKernelGGL(kns3,     dim3(8),    dim3(256), 0, stream, G, WM);
  hipLaunchKernelGGL(kapply2,  dim3(128),  dim3(256), 0, stream, H, WM, ZbB);
  hipLaunchKernelGGL(kmlp1,    dim3(512),  dim3(256), 0, stream, ZbB, W1T, b1, Hh);
  hipLaunchKernelGGL(kmlp2p,   dim3(512),  dim3(256), 0, stream, Hh, W2T, HP);
  hipLaunchKernelGGL(kredT,    dim3(2048), dim3(256), 0, stream, HP, b2, HfT);
  hipLaunchKernelGGL(kdec2,    dim3(2048), dim3(256), 0, stream, x, C, HfT, out);
}

// Round 13
// 220.773 us; speedup vs baseline: 1.1709x; 1.0493x over previous
//
#include <hip/hip_runtime.h>
#include <stdint.h>
#include <math.h>

#define NS_ITERS 26
#define PIT 72   // LDS row pitch in shorts (144B: 16B-aligned, bank-spread)
#define P2  72   // pitch for NS matrices

typedef unsigned short u16;
typedef __attribute__((ext_vector_type(8))) short short8;
typedef __attribute__((ext_vector_type(4))) float f32x4;

__device__ __forceinline__ u16 f2b(float f){
  unsigned u = __float_as_uint(f);
  unsigned r = (u + 0x7FFFu + ((u>>16)&1u)) >> 16;
  return (u16)r;
}
__device__ __forceinline__ float b2f(u16 h){ return __uint_as_float(((unsigned)h)<<16); }
__device__ __forceinline__ unsigned pk2(float lo, float hi){
  return (unsigned)f2b(lo) | ((unsigned)f2b(hi) << 16);
}

// ---------------- threefry2x32 (JAX-compatible) ----------------
__host__ __device__ constexpr uint32_t rotl32(uint32_t v, int n){ return (v<<n)|(v>>(32-n)); }
struct TFOut { uint32_t a, b; };
__host__ __device__ constexpr TFOut tf2x32(uint32_t k0, uint32_t k1, uint32_t x0, uint32_t x1){
  uint32_t ks2 = k0 ^ k1 ^ 0x1BD11BDAu;
  x0 += k0; x1 += k1;
#define TFR(R) x0 += x1; x1 = rotl32(x1,(R)) ^ x0;
  TFR(13) TFR(15) TFR(26) TFR(6)
  x0 += k1; x1 += ks2 + 1u;
  TFR(17) TFR(29) TFR(16) TFR(24)
  x0 += ks2; x1 += k0 + 2u;
  TFR(13) TFR(15) TFR(26) TFR(6)
  x0 += k0; x1 += k1 + 3u;
  TFR(17) TFR(29) TFR(16) TFR(24)
  x0 += k1; x1 += ks2 + 4u;
  TFR(13) TFR(15) TFR(26) TFR(6)
  x0 += ks2; x1 += k0 + 5u;
#undef TFR
  return TFOut{x0, x1};
}

__device__ __forceinline__ float erfinv_f32(float x){
  float w = -log1pf(-x*x);
  float p;
  if (w < 5.0f) {
    w -= 2.5f;
    p = 2.81022636e-08f;
    p = fmaf(p, w, 3.43273939e-07f);
    p = fmaf(p, w, -3.5233877e-06f);
    p = fmaf(p, w, -4.39150654e-06f);
    p = fmaf(p, w, 0.00021858087f);
    p = fmaf(p, w, -0.00125372503f);
    p = fmaf(p, w, -0.00417768164f);
    p = fmaf(p, w, 0.246640727f);
    p = fmaf(p, w, 1.50140941f);
  } else {
    w = sqrtf(w) - 3.0f;
    p = -0.000200214257f;
    p = fmaf(p, w, 0.000100950558f);
    p = fmaf(p, w, 0.00134934322f);
    p = fmaf(p, w, -0.00367342844f);
    p = fmaf(p, w, 0.00573950773f);
    p = fmaf(p, w, -0.0076224613f);
    p = fmaf(p, w, 0.00943887047f);
    p = fmaf(p, w, 1.00167406f);
    p = fmaf(p, w, 2.83297682f);
  }
  return p * x;
}

// ---------------- K1: primes -> PT bf16 [64][1024], unit-norm, rows>=50 zero ----------
__global__ __launch_bounds__(256) void kprep(const float* __restrict__ prime, u16* __restrict__ PT){
  int m = blockIdx.x;
  int tid = threadIdx.x;
  u16* dst = PT + m*1024;
  if (m >= 50){ for (int k = tid; k < 1024; k += 256) dst[k] = 0; return; }
  __shared__ float red[256];
  const float* pr = prime + m*1024;
  float ss = 0.f;
  for (int k = tid; k < 1024; k += 256){ float v = pr[k]; ss = fmaf(v,v,ss); }
  red[tid] = ss; __syncthreads();
  for (int s = 128; s > 0; s >>= 1){ if (tid < s) red[tid] += red[tid+s]; __syncthreads(); }
  float sc = 1.0f / fmaxf(sqrtf(red[0]), 1e-12f);
  for (int k = tid; k < 1024; k += 256) dst[k] = f2b(pr[k]*sc);
}

// ---------------- K2: MFMA logits + softmax; dbuf LDS, 1 barrier/chunk, in-reg sumsq ----
__global__ __launch_bounds__(256) void kC(const float* __restrict__ x, const u16* __restrict__ PT,
                                          u16* __restrict__ C, u16* __restrict__ CT){
  int blk = blockIdx.x; int b = blk>>6, n0 = (blk&63)<<6;
  int tid = threadIdx.x, lane = tid&63, w = tid>>6;
  __shared__ __align__(16) u16 xs[2][64*PIT];
  __shared__ __align__(16) u16 ps[2][64*PIT];
  __shared__ float sqn[64];
  f32x4 acc[4] = {{0,0,0,0},{0,0,0,0},{0,0,0,0},{0,0,0,0}};
  float sqa = 0.f;
  int stok = tid>>2, sseg = tid&3;                 // staging map
  const float* xb = x + ((size_t)(b*4096 + n0))*1024;
  for (int kc = 0; kc < 16; kc++){
    int k0 = kc*64, cb = kc & 1;
    { // stage x (cvt bf16) + in-register sumsq (these 16 values belong to token stok)
      const float* src = xb + (size_t)stok*1024 + k0 + sseg*16;
      unsigned p[8];
#pragma unroll
      for (int i = 0; i < 4; i++){
        float4 v = *reinterpret_cast<const float4*>(src + i*4);
        sqa = fmaf(v.x,v.x,sqa); sqa = fmaf(v.y,v.y,sqa);
        sqa = fmaf(v.z,v.z,sqa); sqa = fmaf(v.w,v.w,sqa);
        p[2*i]   = pk2(v.x, v.y);
        p[2*i+1] = pk2(v.z, v.w);
      }
      uint4 w0; w0.x=p[0]; w0.y=p[1]; w0.z=p[2]; w0.w=p[3];
      uint4 w1; w1.x=p[4]; w1.y=p[5]; w1.z=p[6]; w1.w=p[7];
      *reinterpret_cast<uint4*>(&xs[cb][stok*PIT + sseg*16])     = w0;
      *reinterpret_cast<uint4*>(&xs[cb][stok*PIT + sseg*16 + 8]) = w1;
    }
    { // stage P rows
      const u16* src = PT + (size_t)stok*1024 + k0 + sseg*16;
      *reinterpret_cast<uint4*>(&ps[cb][stok*PIT + sseg*16])   = *reinterpret_cast<const uint4*>(src);
      *reinterpret_cast<uint4*>(&ps[cb][stok*PIT + sseg*16+8]) = *reinterpret_cast<const uint4*>(src+8);
    }
    __syncthreads();
#pragma unroll
    for (int s = 0; s < 2; s++){
      short8 a = *reinterpret_cast<const short8*>(&xs[cb][(16*w + (lane&15))*PIT + s*32 + (lane>>4)*8]);
#pragma unroll
      for (int t = 0; t < 4; t++){
        short8 bb = *reinterpret_cast<const short8*>(&ps[cb][(t*16 + (lane&15))*PIT + s*32 + (lane>>4)*8]);
        acc[t] = __builtin_amdgcn_mfma_f32_16x16x32_bf16(a, bb, acc[t], 0, 0, 0);
      }
    }
  }
  // reduce sumsq across the 4 threads sharing stok (adjacent lanes)
  sqa += __shfl_xor(sqa, 1, 64);
  sqa += __shfl_xor(sqa, 2, 64);
  if ((tid & 3) == 0) sqn[stok] = 10.0f / fmaxf(sqrtf(sqa), 1e-12f);
  __syncthreads();
  // softmax per token (rows spread over lane>>4 groups; primes = lane&15 + 16*t)
  u16* cl = xs[0];  // reuse
#pragma unroll
  for (int r = 0; r < 4; r++){
    int gt = 16*w + (lane>>4)*4 + r;
    float scale = sqn[gt];
    float v[4];
#pragma unroll
    for (int t = 0; t < 4; t++) v[t] = acc[t][r] * scale;
    if ((lane&15) >= 2) v[3] = -1e30f;
    float mx = fmaxf(fmaxf(v[0],v[1]), fmaxf(v[2],v[3]));
#pragma unroll
    for (int off = 1; off < 16; off <<= 1) mx = fmaxf(mx, __shfl_xor(mx, off, 64));
    float e[4], sum = 0.f;
#pragma unroll
    for (int t = 0; t < 4; t++){ e[t] = __expf(v[t]-mx); sum += e[t]; }
#pragma unroll
    for (int off = 1; off < 16; off <<= 1) sum += __shfl_xor(sum, off, 64);
    float inv = 1.0f / sum;
#pragma unroll
    for (int t = 0; t < 4; t++) cl[gt*PIT + t*16 + (lane&15)] = f2b(e[t]*inv);
  }
  __syncthreads();
  { // C write (row-major) b128
    u16* dst = C + ((size_t)(b*4096 + n0 + stok))*64 + sseg*16;
    *reinterpret_cast<uint4*>(dst)   = *reinterpret_cast<const uint4*>(&cl[stok*PIT + sseg*16]);
    *reinterpret_cast<uint4*>(dst+8) = *reinterpret_cast<const uint4*>(&cl[stok*PIT + sseg*16+8]);
  }
  { // CT write (transposed)
    int m = tid>>2, nseg = tid&3;
    unsigned vs[8];
#pragma unroll
    for (int j = 0; j < 8; j++){
      u16 lo = cl[(nseg*16 + 2*j)*PIT + m];
      u16 hi = cl[(nseg*16 + 2*j+1)*PIT + m];
      vs[j] = (unsigned)lo | ((unsigned)hi<<16);
    }
    u16* dst = CT + ((size_t)(b*64 + m))*4096 + n0 + nseg*16;
    uint4 w0; w0.x=vs[0]; w0.y=vs[1]; w0.z=vs[2]; w0.w=vs[3];
    uint4 w1; w1.x=vs[4]; w1.y=vs[5]; w1.z=vs[6]; w1.w=vs[7];
    *reinterpret_cast<uint4*>(dst)   = w0;
    *reinterpret_cast<uint4*>(dst+8) = w1;
  }
}

// ---------------- K3: H_prime partials (MFMA, K-split x4; dbuf LDS, 1 barrier/chunk) ----
__global__ __launch_bounds__(256) void kHp2(const float* __restrict__ x, const u16* __restrict__ CT,
                                            float* __restrict__ Hpart){
  int blk = blockIdx.x;            // 512 = b(8) * dt(16) * kt(4)
  int kt = blk & 3, dt = (blk >> 2) & 15, b = blk >> 6;
  int d0 = dt*64;
  int tid = threadIdx.x, lane = tid&63, w = tid>>6;
  __shared__ __align__(16) u16 cs[2][64*PIT];    // [m][n]
  __shared__ __align__(16) u16 xt[2][64*PIT];    // [d][n]
  f32x4 acc[4] = {{0,0,0,0},{0,0,0,0},{0,0,0,0},{0,0,0,0}};
  int nn = tid>>2, seg = tid&3;
  int np = tid & 31, dsg = tid >> 5;          // n-pair staging map
  for (int nc = 0; nc < 16; nc++){
    int n0 = kt*1024 + nc*64, cb = nc & 1;
    { // stage CT rows [m][n-chunk]
      const u16* src = CT + ((size_t)(b*64 + nn))*4096 + n0 + seg*16;  // nn = m here
      *reinterpret_cast<uint4*>(&cs[cb][nn*PIT + seg*16])   = *reinterpret_cast<const uint4*>(src);
      *reinterpret_cast<uint4*>(&cs[cb][nn*PIT + seg*16+8]) = *reinterpret_cast<const uint4*>(src+8);
    }
    { // stage x transposed: n-paired packed u32 writes (conflict-free)
      const float* s0 = x + ((size_t)(b*4096 + n0 + 2*np))*1024 + d0 + dsg*8;
      const float* s1 = s0 + 1024;
      float4 a0 = *reinterpret_cast<const float4*>(s0);
      float4 a1 = *reinterpret_cast<const float4*>(s0+4);
      float4 c0v = *reinterpret_cast<const float4*>(s1);
      float4 c1v = *reinterpret_cast<const float4*>(s1+4);
      float av[8] = {a0.x,a0.y,a0.z,a0.w,a1.x,a1.y,a1.z,a1.w};
      float cv[8] = {c0v.x,c0v.y,c0v.z,c0v.w,c1v.x,c1v.y,c1v.z,c1v.w};
#pragma unroll
      for (int j2 = 0; j2 < 8; j2++){
        int dd = dsg*8 + j2;
        *reinterpret_cast<unsigned*>(&xt[cb][dd*PIT + 2*np]) = pk2(av[j2], cv[j2]);
      }
    }
    __syncthreads();
#pragma unroll
    for (int s = 0; s < 2; s++){
      short8 a = *reinterpret_cast<const short8*>(&cs[cb][(16*w + (lane&15))*PIT + s*32 + (lane>>4)*8]);
#pragma unroll
      for (int t = 0; t < 4; t++){
        short8 bb = *reinterpret_cast<const short8*>(&xt[cb][(t*16 + (lane&15))*PIT + s*32 + (lane>>4)*8]);
        acc[t] = __builtin_amdgcn_mfma_f32_16x16x32_bf16(a, bb, acc[t], 0, 0, 0);
      }
    }
  }
#pragma unroll
  for (int t = 0; t < 4; t++)
#pragma unroll
    for (int r = 0; r < 4; r++){
      int m = 16*w + (lane>>4)*4 + r;
      int d = d0 + t*16 + (lane&15);
      if (m < 50) Hpart[(((size_t)(b*4) + kt)*50 + m)*1024 + d] = acc[t][r];
    }
}

// ---------------- K3b: reduce partials -> H f32 + Hb bf16, pad rows zeroed (grid 2048) ----
__global__ void kredH(const float* __restrict__ Hpart, float* __restrict__ H, u16* __restrict__ Hb){
  int e = blockIdx.x*256 + threadIdx.x;    // grid 2048 -> 524288 over [b][m(64)][d]
  int b = e >> 16, rem = e & 65535;
  int m = rem >> 10, d = rem & 1023;
  size_t o = ((size_t)(b*64 + m))*1024 + d;
  if (m < 50){
    const float* p = Hpart + (size_t)b*204800 + m*1024 + d;
    float s = p[0] + p[51200] + p[102400] + p[153600];
    H[o] = s;
    Hb[o] = f2b(s);
  } else {
    Hb[o] = 0;
  }
}

// ---------------- K4: fused Gram (LDS) + Newton-Schulz; blocks 8..519 transpose W1/W2 ----
// blk 0..7  : b = blk; G = Hb[b] Hb[b]^T computed into LDS f32; trace-scale; 26 coupled-NS
//             iters in bf16 MFMA; Wm written.
// blk 8..519: 4 weight tiles each (g = (blk-8)*4+i; g<1024 -> W1 64x64 tile, else W2).
__global__ __launch_bounds__(256) void kgramNS(const u16* __restrict__ Hb, float* __restrict__ Wm,
                                               const float* __restrict__ W1, u16* __restrict__ W1T,
                                               const float* __restrict__ W2, u16* __restrict__ W2T){
  __shared__ __align__(16) u16 Yr[2][64*P2], Yc[2][64*P2], Zr[2][64*P2], Zc[2][64*P2];
  __shared__ __align__(16) u16 TrTc[2][64*P2];      // Tr=TrTc[0], Tc=TrTc[1]; init overlay: Gf32
  __shared__ __align__(16) u16 ts[64*PIT];          // gram staging / transpose staging
  __shared__ float sv[2];
  int blk = blockIdx.x;
  int tid = threadIdx.x, lane = tid&63, w = tid>>6;

  if (blk >= 8){
    // ---- weight transpose path (4 tiles per block) ----
    int tblk = blk - 8;
    for (int i = 0; i < 4; i++){
      int g = tblk*4 + i;
      const float* src; u16* dst; int ss, ds;
      if (g < 1024){
        int kt2 = g >> 6, nt2 = g & 63;
        src = W1 + (size_t)(kt2*64)*4096 + nt2*64; ss = 4096;
        dst = W1T + (size_t)(nt2*64)*1024 + kt2*64; ds = 1024;
      } else {
        int t = g - 1024;
        int kt2 = t >> 4, dt2 = t & 15;
        src = W2 + (size_t)(kt2*64)*1024 + dt2*64; ss = 1024;
        dst = W2T + (size_t)(dt2*64)*4096 + kt2*64; ds = 4096;
      }
      int r = tid>>2, sseg = tid&3;
      __syncthreads();   // protect ts reuse across tiles
      {
        const float* s0 = src + (size_t)r*ss + sseg*16;
        unsigned p[8];
#pragma unroll
        for (int q = 0; q < 4; q++){
          float4 v = *reinterpret_cast<const float4*>(s0 + q*4);
          p[2*q]   = pk2(v.x, v.y);
          p[2*q+1] = pk2(v.z, v.w);
        }
        uint4 w0; w0.x=p[0]; w0.y=p[1]; w0.z=p[2]; w0.w=p[3];
        uint4 w1; w1.x=p[4]; w1.y=p[5]; w1.z=p[6]; w1.w=p[7];
        *reinterpret_cast<uint4*>(&ts[r*PIT + sseg*16])     = w0;
        *reinterpret_cast<uint4*>(&ts[r*PIT + sseg*16 + 8]) = w1;
      }
      __syncthreads();
      {
        int n2 = tid>>2, kseg = tid&3;
        unsigned q[8];
#pragma unroll
        for (int j = 0; j < 8; j++){
          u16 lo = ts[(kseg*16 + 2*j)*PIT + n2];
          u16 hi = ts[(kseg*16 + 2*j+1)*PIT + n2];
          q[j] = (unsigned)lo | ((unsigned)hi<<16);
        }
        u16* d2 = dst + (size_t)n2*ds + kseg*16;
        uint4 w0; w0.x=q[0]; w0.y=q[1]; w0.z=q[2]; w0.w=q[3];
        uint4 w1; w1.x=q[4]; w1.y=q[5]; w1.z=q[6]; w1.w=q[7];
        *reinterpret_cast<uint4*>(d2)   = w0;
        *reinterpret_cast<uint4*>(d2+8) = w1;
      }
    }
    return;
  }

  // ---- gram + NS path ----
  int b = blk;
  float* Gf = reinterpret_cast<float*>(&TrTc[0][0]);   // 64x64 f32, pitch 65 (16.6KB < 18.4KB)
  { // Gram via MFMA into LDS
    f32x4 acc[4] = {{0,0,0,0},{0,0,0,0},{0,0,0,0},{0,0,0,0}};
    int m = tid>>2, seg = tid&3;
    for (int kc = 0; kc < 16; kc++){
      int k0 = kc*64;
      __syncthreads();
      const u16* src = Hb + ((size_t)(b*64 + m))*1024 + k0 + seg*16;
      *reinterpret_cast<uint4*>(&ts[m*PIT + seg*16])   = *reinterpret_cast<const uint4*>(src);
      *reinterpret_cast<uint4*>(&ts[m*PIT + seg*16+8]) = *reinterpret_cast<const uint4*>(src+8);
      __syncthreads();
#pragma unroll
      for (int s = 0; s < 2; s++){
        short8 a = *reinterpret_cast<const short8*>(&ts[(16*w + (lane&15))*PIT + s*32 + (lane>>4)*8]);
#pragma unroll
        for (int t = 0; t < 4; t++){
          short8 bb = *reinterpret_cast<const short8*>(&ts[(t*16 + (lane&15))*PIT + s*32 + (lane>>4)*8]);
          acc[t] = __builtin_amdgcn_mfma_f32_16x16x32_bf16(a, bb, acc[t], 0, 0, 0);
        }
      }
    }
    __syncthreads();
#pragma unroll
    for (int t = 0; t < 4; t++)
#pragma unroll
      for (int r = 0; r < 4; r++){
        int i = 16*w + (lane>>4)*4 + r;
        int j = t*16 + (lane&15);
        Gf[i*65 + j] = acc[t][r];
      }
  }
  __syncthreads();
  if (tid < 64){
    float v = (tid < 50) ? Gf[tid*65 + tid] : 0.f;
    for (int off = 1; off < 64; off <<= 1) v += __shfl_xor(v, off, 64);
    if (tid == 0){ sv[0] = 1.0f / v; sv[1] = rsqrtf(v); }
  }
  __syncthreads();
  float rs = sv[0];
  for (int idx = tid; idx < 4096; idx += 256){
    int r = idx>>6, c = idx&63;
    float yv = (r<50 && c<50) ? Gf[r*65+c]*rs : ((r==c) ? 1.f : 0.f);
    float zv = (r==c) ? 1.f : 0.f;
    u16 yb = f2b(yv), zb = f2b(zv);
    Yr[0][r*P2+c] = yb; Yc[0][c*P2+r] = yb;
    Zr[0][r*P2+c] = zb; Zc[0][c*P2+r] = zb;
  }
  __syncthreads();
  u16* Tr = TrTc[0];
  u16* Tc = TrTc[1];
  int lr = lane>>4, lc = lane&15;
  int row0 = 16*w;
  for (int it = 0; it < NS_ITERS; it++){
    int cur = it & 1, nxt = cur ^ 1;
    { // phase 1: T = 1.5I - 0.5 * Z@Y
      short8 a0 = *reinterpret_cast<const short8*>(&Zr[cur][(row0+lc)*P2 + lr*8]);
      short8 a1 = *reinterpret_cast<const short8*>(&Zr[cur][(row0+lc)*P2 + 32 + lr*8]);
      f32x4 acc[4] = {{0,0,0,0},{0,0,0,0},{0,0,0,0},{0,0,0,0}};
#pragma unroll
      for (int t = 0; t < 4; t++){
        short8 b0 = *reinterpret_cast<const short8*>(&Yc[cur][(t*16+lc)*P2 + lr*8]);
        short8 b1 = *reinterpret_cast<const short8*>(&Yc[cur][(t*16+lc)*P2 + 32 + lr*8]);
        acc[t] = __builtin_amdgcn_mfma_f32_16x16x32_bf16(a0, b0, acc[t], 0, 0, 0);
        acc[t] = __builtin_amdgcn_mfma_f32_16x16x32_bf16(a1, b1, acc[t], 0, 0, 0);
      }
      __syncthreads();   // Gf overlay dead after init; ensure phase ordering on Tr/Tc
#pragma unroll
      for (int t = 0; t < 4; t++)
#pragma unroll
        for (int r = 0; r < 4; r++){
          int row = row0 + lr*4 + r, col = t*16 + lc;
          float v = ((row==col) ? 1.5f : 0.f) - 0.5f*acc[t][r];
          u16 h = f2b(v);
          Tr[row*P2+col] = h; Tc[col*P2+row] = h;
        }
    }
    __syncthreads();
    { // phase 2: Y' = Y@T ; Z' = T@Z
      short8 ya0 = *reinterpret_cast<const short8*>(&Yr[cur][(row0+lc)*P2 + lr*8]);
      short8 ya1 = *reinterpret_cast<const short8*>(&Yr[cur][(row0+lc)*P2 + 32 + lr*8]);
      short8 ta0 = *reinterpret_cast<const short8*>(&Tr[(row0+lc)*P2 + lr*8]);
      short8 ta1 = *reinterpret_cast<const short8*>(&Tr[(row0+lc)*P2 + 32 + lr*8]);
      f32x4 accY[4] = {{0,0,0,0},{0,0,0,0},{0,0,0,0},{0,0,0,0}};
      f32x4 accZ[4] = {{0,0,0,0},{0,0,0,0},{0,0,0,0},{0,0,0,0}};
#pragma unroll
      for (int t = 0; t < 4; t++){
        short8 tb0 = *reinterpret_cast<const short8*>(&Tc[(t*16+lc)*P2 + lr*8]);
        short8 tb1 = *reinterpret_cast<const short8*>(&Tc[(t*16+lc)*P2 + 32 + lr*8]);
        accY[t] = __builtin_amdgcn_mfma_f32_16x16x32_bf16(ya0, tb0, accY[t], 0, 0, 0);
        accY[t] = __builtin_amdgcn_mfma_f32_16x16x32_bf16(ya1, tb1, accY[t], 0, 0, 0);
        short8 zb0 = *reinterpret_cast<const short8*>(&Zc[cur][(t*16+lc)*P2 + lr*8]);
        short8 zb1 = *reinterpret_cast<const short8*>(&Zc[cur][(t*16+lc)*P2 + 32 + lr*8]);
        accZ[t] = __builtin_amdgcn_mfma_f32_16x16x32_bf16(ta0, zb0, accZ[t], 0, 0, 0);
        accZ[t] = __builtin_amdgcn_mfma_f32_16x16x32_bf16(ta1, zb1, accZ[t], 0, 0, 0);
      }
#pragma unroll
      for (int t = 0; t < 4; t++)
#pragma unroll
        for (int r = 0; r < 4; r++){
          int row = row0 + lr*4 + r, col = t*16 + lc;
          u16 hy = f2b(accY[t][r]);
          u16 hz = f2b(accZ[t][r]);
          Yr[nxt][row*P2+col] = hy; Yc[nxt][col*P2+row] = hy;
          Zr[nxt][row*P2+col] = hz; Zc[nxt][col*P2+row] = hz;
        }
    }
    __syncthreads();
  }
  float rss = sv[1];
  int fin = NS_ITERS & 1;
  for (int idx = tid; idx < 2500; idx += 256){
    int r = idx/50, c = idx - r*50;
    Wm[(size_t)b*2500 + idx] = b2f(Zr[fin][r*P2+c]) * rss;
  }
}

// ---------------- K4c: H_logic = Wm @ H + threefry noise -> ZbB bf16 (fused) ----------------
__global__ __launch_bounds__(256) void kapply2(const float* __restrict__ H, const float* __restrict__ Wm,
                                               u16* __restrict__ zb){
  TFOut K1 = tf2x32(0u, 42u, 0u, 0u);
  TFOut K2 = tf2x32(0u, 42u, 0u, 1u);
  int blk = blockIdx.x;          // 128 = b(8) * dt(16)
  int dt = blk & 15, b = blk >> 4;
  int d0 = dt*64;
  int tid = threadIdx.x;
  int d = tid & 63, mg = tid >> 6;
  __shared__ __align__(16) float WsT[50*64];
  __shared__ float Hs[50*65];
  for (int idx = tid; idx < 3200; idx += 256){
    int j = idx >> 6, c = idx & 63;
    WsT[idx] = (c < 50) ? Wm[(size_t)b*2500 + c*50 + j] : 0.f;
  }
  for (int idx = tid; idx < 3200; idx += 256){
    int j = idx >> 6, c = idx & 63;
    Hs[j*65 + c] = H[((size_t)(b*64) + j)*1024 + d0 + c];
  }
  __syncthreads();
  float acc[16];
#pragma unroll
  for (int i = 0; i < 16; i++) acc[i] = 0.f;
  for (int j = 0; j < 50; j++){
    float hv = Hs[j*65 + d];
    const float* wb = WsT + j*64 + (mg << 4);
#pragma unroll
    for (int q = 0; q < 4; q++){
      float4 wv = *reinterpret_cast<const float4*>(wb + q*4);
      acc[q*4+0] = fmaf(wv.x, hv, acc[q*4+0]);
      acc[q*4+1] = fmaf(wv.y, hv, acc[q*4+1]);
      acc[q*4+2] = fmaf(wv.z, hv, acc[q*4+2]);
      acc[q*4+3] = fmaf(wv.w, hv, acc[q*4+3]);
    }
  }
#pragma unroll
  for (int i = 0; i < 16; i++){
    int m = (mg << 4) + i;
    size_t zo = ((size_t)(b*64 + m))*1024 + d0 + d;
    u16 ov = 0;
    if (m < 50){
      float val = acc[i];
      uint32_t j = (uint32_t)(((b*50 + m) << 10) + d0 + d);
      TFOut r1 = tf2x32(K1.a, K1.b, 0u, j);
      uint32_t bits = r1.a ^ r1.b;
      float u = __uint_as_float(0x3F800000u | (bits >> 9)) - 1.0f;
      if (u < 0.0464f){
        TFOut r2 = tf2x32(K2.a, K2.b, 0u, j);
        uint32_t nb = r2.a ^ r2.b;
        float ww = __uint_as_float(0x3F800000u | (nb >> 9)) - 1.0f;
        const float lo = -0.99999994f;
        float un = fmaxf(lo, fmaf(ww, 2.0f, lo));
        val += 0.1f * (1.4142135f * erfinv_f32(un));
      }
      ov = f2b(val);
    }
    zb[zo] = ov;
  }
}

// ---------------- K5: Hh = gelu(ZbB @ W1T + b1) (MFMA; dbuf LDS, 1 barrier/chunk) ----------------
__global__ __launch_bounds__(256) void kmlp1(const u16* __restrict__ ZbB, const u16* __restrict__ W1T,
                                             const float* __restrict__ b1, u16* __restrict__ Hh){
  int blk = blockIdx.x; int b = blk>>6, c0 = (blk&63)<<6;
  int tid = threadIdx.x, lane = tid&63, w = tid>>6;
  __shared__ __align__(16) u16 az[2][64*PIT];   // [m][k]
  __shared__ __align__(16) u16 wt[2][64*PIT];   // [n][k]
  f32x4 acc[4] = {{0,0,0,0},{0,0,0,0},{0,0,0,0},{0,0,0,0}};
  int rr = tid>>2, seg = tid&3;
  for (int kc = 0; kc < 16; kc++){
    int k0 = kc*64, cb = kc & 1;
    { // stage A (ZbB rows)
      const u16* src = ZbB + ((size_t)(b*64 + rr))*1024 + k0 + seg*16;
      *reinterpret_cast<uint4*>(&az[cb][rr*PIT + seg*16])   = *reinterpret_cast<const uint4*>(src);
      *reinterpret_cast<uint4*>(&az[cb][rr*PIT + seg*16+8]) = *reinterpret_cast<const uint4*>(src+8);
    }
    { // stage B (W1T rows, direct bf16 copy)
      const u16* src = W1T + ((size_t)(c0 + rr))*1024 + k0 + seg*16;
      *reinterpret_cast<uint4*>(&wt[cb][rr*PIT + seg*16])   = *reinterpret_cast<const uint4*>(src);
      *reinterpret_cast<uint4*>(&wt[cb][rr*PIT + seg*16+8]) = *reinterpret_cast<const uint4*>(src+8);
    }
    __syncthreads();
#pragma unroll
    for (int s = 0; s < 2; s++){
      short8 a = *reinterpret_cast<const short8*>(&az[cb][(16*w + (lane&15))*PIT + s*32 + (lane>>4)*8]);
#pragma unroll
      for (int t = 0; t < 4; t++){
        short8 bb = *reinterpret_cast<const short8*>(&wt[cb][(t*16 + (lane&15))*PIT + s*32 + (lane>>4)*8]);
        acc[t] = __builtin_amdgcn_mfma_f32_16x16x32_bf16(a, bb, acc[t], 0, 0, 0);
      }
    }
  }
#pragma unroll
  for (int t = 0; t < 4; t++)
#pragma unroll
    for (int r = 0; r < 4; r++){
      int m = 16*w + (lane>>4)*4 + r;
      int n = c0 + t*16 + (lane&15);
      float val = acc[t][r] + b1[n];
      float g = 0.5f * val * (1.0f + erff(val * 0.70710678f));
      Hh[((size_t)(b*64 + m))*4096 + n] = (m < 50) ? f2b(g) : (u16)0;
    }
}

// ---------------- K6: partials of Hh @ W2T (MFMA, K-split x4; dbuf LDS, 1 barrier/chunk) ----
__global__ __launch_bounds__(256) void kmlp2p(const u16* __restrict__ Hh, const u16* __restrict__ W2T,
                                              float* __restrict__ Mpart){
  int blk = blockIdx.x;            // 512 = b(8) * dt(16) * kt(4)
  int kt = blk & 3, dt = (blk >> 2) & 15, b = blk >> 6;
  int d0 = dt*64;
  int tid = threadIdx.x, lane = tid&63, w = tid>>6;
  __shared__ __align__(16) u16 az[2][64*PIT];
  __shared__ __align__(16) u16 wt[2][64*PIT];
  f32x4 acc[4] = {{0,0,0,0},{0,0,0,0},{0,0,0,0},{0,0,0,0}};
  int rr = tid>>2, seg = tid&3;
  for (int kc = 0; kc < 16; kc++){
    int k0 = kt*1024 + kc*64, cb = kc & 1;
    {
      const u16* src = Hh + ((size_t)(b*64 + rr))*4096 + k0 + seg*16;
      *reinterpret_cast<uint4*>(&az[cb][rr*PIT + seg*16])   = *reinterpret_cast<const uint4*>(src);
      *reinterpret_cast<uint4*>(&az[cb][rr*PIT + seg*16+8]) = *reinterpret_cast<const uint4*>(src+8);
    }
    { // stage B (W2T rows, direct bf16 copy)
      const u16* src = W2T + ((size_t)(d0 + rr))*4096 + k0 + seg*16;
      *reinterpret_cast<uint4*>(&wt[cb][rr*PIT + seg*16])   = *reinterpret_cast<const uint4*>(src);
      *reinterpret_cast<uint4*>(&wt[cb][rr*PIT + seg*16+8]) = *reinterpret_cast<const uint4*>(src+8);
    }
    __syncthreads();
#pragma unroll
    for (int s = 0; s < 2; s++){
      short8 a = *reinterpret_cast<const short8*>(&az[cb][(16*w + (lane&15))*PIT + s*32 + (lane>>4)*8]);
#pragma unroll
      for (int t = 0; t < 4; t++){
        short8 bb = *reinterpret_cast<const short8*>(&wt[cb][(t*16 + (lane&15))*PIT + s*32 + (lane>>4)*8]);
        acc[t] = __builtin_amdgcn_mfma_f32_16x16x32_bf16(a, bb, acc[t], 0, 0, 0);
      }
    }
  }
#pragma unroll
  for (int t = 0; t < 4; t++)
#pragma unroll
    for (int r = 0; r < 4; r++){
      int m = 16*w + (lane>>4)*4 + r;
      int d = d0 + t*16 + (lane&15);
      if (m < 50) Mpart[(((size_t)(b*4) + kt)*50 + m)*1024 + d] = acc[t][r];
    }
}

// ---------------- K6b: HfT = tanh(sum partials + b2)^T, bf16, m>=50 zero ----------------
__global__ void kredT(const float* __restrict__ Mpart, const float* __restrict__ b2, u16* __restrict__ HfT){
  int e = blockIdx.x*256 + threadIdx.x;    // grid 2048 -> 524288 over [b][m(64)][d]
  int b = e >> 16, rem = e & 65535;
  int m = rem >> 10, d = rem & 1023;
  u16 outv = 0;
  if (m < 50){
    const float* p = Mpart + (size_t)b*204800 + m*1024 + d;
    float s = p[0] + p[51200] + p[102400] + p[153600] + b2[d];
    outv = f2b(tanhf(s));
  }
  HfT[((size_t)(b*1024) + d)*64 + m] = outv;
}

// ---------------- K7: out = x + C @ Hf (MFMA + LDS-bounced coalesced epilogue) ----------
__global__ __launch_bounds__(256) void kdec2(const float* __restrict__ x, const u16* __restrict__ C,
                                             const u16* __restrict__ HfT, float* __restrict__ out){
  int blk = blockIdx.x;              // 2048 = b(8) * nt(64) * dq(4)
  int dq = blk & 3, nt = (blk >> 2) & 63, b = blk >> 8;
  int n0 = nt << 6;
  int tid = threadIdx.x, lane = tid&63, w = tid>>6;
  __shared__ __align__(16) u16 ctile[64*PIT];   // [tok][m]
  __shared__ __align__(16) u16 htile[64*PIT];   // [d][m]
  __shared__ __align__(16) float obuf[64*68];   // [n][d] f32, pitch 68
  int rr = tid>>2, seg = tid&3;
  {
    const u16* src = C + ((size_t)(b*4096 + n0 + rr))*64 + seg*16;
    *reinterpret_cast<uint4*>(&ctile[rr*PIT + seg*16])   = *reinterpret_cast<const uint4*>(src);
    *reinterpret_cast<uint4*>(&ctile[rr*PIT + seg*16+8]) = *reinterpret_cast<const uint4*>(src+8);
  }
  __syncthreads();
  short8 afrag[2];
#pragma unroll
  for (int s = 0; s < 2; s++)
    afrag[s] = *reinterpret_cast<const short8*>(&ctile[(16*w + (lane&15))*PIT + s*32 + (lane>>4)*8]);
  for (int dt2 = 0; dt2 < 4; dt2++){
    int d0 = (dq*4 + dt2) * 64;
    __syncthreads();
    {
      const u16* src = HfT + ((size_t)(b*1024 + d0 + rr))*64 + seg*16;
      *reinterpret_cast<uint4*>(&htile[rr*PIT + seg*16])   = *reinterpret_cast<const uint4*>(src);
      *reinterpret_cast<uint4*>(&htile[rr*PIT + seg*16+8]) = *reinterpret_cast<const uint4*>(src+8);
    }
    __syncthreads();
    f32x4 acc[4] = {{0,0,0,0},{0,0,0,0},{0,0,0,0},{0,0,0,0}};
#pragma unroll
    for (int s = 0; s < 2; s++){
#pragma unroll
      for (int t = 0; t < 4; t++){
        short8 bb = *reinterpret_cast<const short8*>(&htile[(t*16 + (lane&15))*PIT + s*32 + (lane>>4)*8]);
        acc[t] = __builtin_amdgcn_mfma_f32_16x16x32_bf16(afrag[s], bb, acc[t], 0, 0, 0);
      }
    }
    // scatter acc into LDS [n][d] f32
#pragma unroll
    for (int t = 0; t < 4; t++)
#pragma unroll
      for (int r = 0; r < 4; r++){
        int nl = 16*w + (lane>>4)*4 + r;
        int dl = t*16 + (lane&15);
        obuf[nl*68 + dl] = acc[t][r];
      }
    __syncthreads();
    // coalesced epilogue: 1024 float4-slots (64 rows x 16 slots), 4 per thread
#pragma unroll
    for (int pass = 0; pass < 4; pass++){
      int s2 = tid + pass*256;
      int nl = s2 >> 4, sg = s2 & 15;
      size_t o = ((size_t)(b*4096 + n0 + nl))*1024 + d0 + sg*4;
      float4 xv = *reinterpret_cast<const float4*>(x + o);
      const float* ob = &obuf[nl*68 + sg*4];
      float4 ov;
      ov.x = xv.x + ob[0];
      ov.y = xv.y + ob[1];
      ov.z = xv.z + ob[2];
      ov.w = xv.w + ob[3];
      *reinterpret_cast<float4*>(out + o) = ov;
    }
  }
}

// ---------------- launch ----------------
extern "C" void kernel_launch(void* const* d_in, const int* in_sizes, int n_in,
                              void* d_out, int out_size, void* d_ws, size_t ws_size,
                              hipStream_t stream) {
  (void)in_sizes; (void)n_in; (void)out_size;
  if (ws_size < (size_t)19755264) return;
  const float* x  = (const float*)d_in[0];
  const float* pn = (const float*)d_in[1];
  const float* W1 = (const float*)d_in[8];
  const float* b1 = (const float*)d_in[9];
  const float* W2 = (const float*)d_in[10];
  const float* b2 = (const float*)d_in[11];
  float* out = (float*)d_out;
  char* ws = (char*)d_ws;

  // W1T/W2T bf16 scratch lives in d_out (134 MB): dead before kdec2 fully
  // overwrites out. W1T = 4096x1024 bf16 (8.39MB), W2T = 1024x4096 bf16.
  u16*   W1T = (u16*)d_out;
  u16*   W2T = (u16*)d_out + 4194304;

  // Overlapped ws layout (stream-ordered liveness):
  u16*   C   = (u16*)(ws);                      // [0, 4.19MB)        live kC->kdec2
  u16*   CT  = (u16*)(ws + 4194304);            // CT region 4.19MB:  CT live kC->kHp2
  u16*   ZbB = (u16*)(ws + 4194304 + 1638400);  //   reuses CT space  (kapply2->kmlp1)
  u16*   HfT = (u16*)(ws + 4194304 + 2686976);  //   (kredT->kdec2)
  u16*   Hh  = (u16*)(ws + 8388608);            // Hh region 4.19MB:  Hh live kmlp1->kmlp2p
  u16*   Hb  = (u16*)(ws + 8388608);            //   reuses Hh space  (kredH->kgramNS)
  float* H   = (float*)(ws + 8388608 + 1048576);//   (kredH->kapply2)
  float* HP  = (float*)(ws + 12582912);         // partials 6.55MB: kHp2->kredH, kmlp2p->kredT
  u16*   PT  = (u16*)(ws + 19136512);           // 131,072 B
  float* WM  = (float*)(ws + 19347584);         // 80,000 B

  hipLaunchKernelGGL(kprep,   dim3(64),   dim3(256), 0, stream, pn, PT);
  hipLaunchKernelGGL(kC,      dim3(512),  dim3(256), 0, stream, x, PT, C, CT);
  hipLaunchKernelGGL(kHp2,    dim3(512),  dim3(256), 0, stream, x, CT, HP);
  hipLaunchKernelGGL(kredH,   dim3(2048), dim3(256), 0, stream, HP, H, Hb);
  hipLaunchKernelGGL(kgramNS, dim3(520),  dim3(256), 0, stream, Hb, WM, W1, W1T, W2, W2T);
  hipLaunchKernelGGL(kapply2, dim3(128),  dim3(256), 0, stream, H, WM, ZbB);
  hipLaunchKernelGGL(kmlp1,   dim3(512),  dim3(256), 0, stream, ZbB, W1T, b1, Hh);
  hipLaunchKernelGGL(kmlp2p,  dim3(512),  dim3(256), 0, stream, Hh, W2T, HP);
  hipLaunchKernelGGL(kredT,   dim3(2048), dim3(256), 0, stream, HP, b2, HfT);
  hipLaunchKernelGGL(kdec2,   dim3(2048), dim3(256), 0, stream, x, C, HfT, out);
}

// Round 14
// 208.093 us; speedup vs baseline: 1.2423x; 1.0609x over previous
//
#include <hip/hip_runtime.h>
#include <stdint.h>
#include <math.h>

#define NS_ITERS 18
#define PIT 72   // LDS row pitch in shorts (144B: 16B-aligned, bank-spread)
#define P2  72   // pitch for NS matrices

typedef unsigned short u16;
typedef __attribute__((ext_vector_type(8))) short short8;
typedef __attribute__((ext_vector_type(4))) float f32x4;

__device__ __forceinline__ u16 f2b(float f){
  unsigned u = __float_as_uint(f);
  unsigned r = (u + 0x7FFFu + ((u>>16)&1u)) >> 16;
  return (u16)r;
}
__device__ __forceinline__ float b2f(u16 h){ return __uint_as_float(((unsigned)h)<<16); }
__device__ __forceinline__ unsigned pk2(float lo, float hi){
  return (unsigned)f2b(lo) | ((unsigned)f2b(hi) << 16);
}

// ---------------- threefry2x32 (JAX-compatible) ----------------
__host__ __device__ constexpr uint32_t rotl32(uint32_t v, int n){ return (v<<n)|(v>>(32-n)); }
struct TFOut { uint32_t a, b; };
__host__ __device__ constexpr TFOut tf2x32(uint32_t k0, uint32_t k1, uint32_t x0, uint32_t x1){
  uint32_t ks2 = k0 ^ k1 ^ 0x1BD11BDAu;
  x0 += k0; x1 += k1;
#define TFR(R) x0 += x1; x1 = rotl32(x1,(R)) ^ x0;
  TFR(13) TFR(15) TFR(26) TFR(6)
  x0 += k1; x1 += ks2 + 1u;
  TFR(17) TFR(29) TFR(16) TFR(24)
  x0 += ks2; x1 += k0 + 2u;
  TFR(13) TFR(15) TFR(26) TFR(6)
  x0 += k0; x1 += k1 + 3u;
  TFR(17) TFR(29) TFR(16) TFR(24)
  x0 += k1; x1 += ks2 + 4u;
  TFR(13) TFR(15) TFR(26) TFR(6)
  x0 += ks2; x1 += k0 + 5u;
#undef TFR
  return TFOut{x0, x1};
}

__device__ __forceinline__ float erfinv_f32(float x){
  float w = -log1pf(-x*x);
  float p;
  if (w < 5.0f) {
    w -= 2.5f;
    p = 2.81022636e-08f;
    p = fmaf(p, w, 3.43273939e-07f);
    p = fmaf(p, w, -3.5233877e-06f);
    p = fmaf(p, w, -4.39150654e-06f);
    p = fmaf(p, w, 0.00021858087f);
    p = fmaf(p, w, -0.00125372503f);
    p = fmaf(p, w, -0.00417768164f);
    p = fmaf(p, w, 0.246640727f);
    p = fmaf(p, w, 1.50140941f);
  } else {
    w = sqrtf(w) - 3.0f;
    p = -0.000200214257f;
    p = fmaf(p, w, 0.000100950558f);
    p = fmaf(p, w, 0.00134934322f);
    p = fmaf(p, w, -0.00367342844f);
    p = fmaf(p, w, 0.00573950773f);
    p = fmaf(p, w, -0.0076224613f);
    p = fmaf(p, w, 0.00943887047f);
    p = fmaf(p, w, 1.00167406f);
    p = fmaf(p, w, 2.83297682f);
  }
  return p * x;
}

// ---------------- K1: primes -> PT bf16 [64][1024], unit-norm, rows>=50 zero ----------
__global__ __launch_bounds__(256) void kprep(const float* __restrict__ prime, u16* __restrict__ PT){
  int m = blockIdx.x;
  int tid = threadIdx.x;
  u16* dst = PT + m*1024;
  if (m >= 50){ for (int k = tid; k < 1024; k += 256) dst[k] = 0; return; }
  __shared__ float red[256];
  const float* pr = prime + m*1024;
  float ss = 0.f;
  for (int k = tid; k < 1024; k += 256){ float v = pr[k]; ss = fmaf(v,v,ss); }
  red[tid] = ss; __syncthreads();
  for (int s = 128; s > 0; s >>= 1){ if (tid < s) red[tid] += red[tid+s]; __syncthreads(); }
  float sc = 1.0f / fmaxf(sqrtf(red[0]), 1e-12f);
  for (int k = tid; k < 1024; k += 256) dst[k] = f2b(pr[k]*sc);
}

// ---------------- K2: MFMA logits + softmax; dbuf LDS, 1 barrier/chunk, in-reg sumsq ----
__global__ __launch_bounds__(256) void kC(const float* __restrict__ x, const u16* __restrict__ PT,
                                          u16* __restrict__ C, u16* __restrict__ CT){
  int blk = blockIdx.x; int b = blk>>6, n0 = (blk&63)<<6;
  int tid = threadIdx.x, lane = tid&63, w = tid>>6;
  __shared__ __align__(16) u16 xs[2][64*PIT];
  __shared__ __align__(16) u16 ps[2][64*PIT];
  __shared__ float sqn[64];
  f32x4 acc[4] = {{0,0,0,0},{0,0,0,0},{0,0,0,0},{0,0,0,0}};
  float sqa = 0.f;
  int stok = tid>>2, sseg = tid&3;                 // staging map
  const float* xb = x + ((size_t)(b*4096 + n0))*1024;
  for (int kc = 0; kc < 16; kc++){
    int k0 = kc*64, cb = kc & 1;
    { // stage x (cvt bf16) + in-register sumsq (these 16 values belong to token stok)
      const float* src = xb + (size_t)stok*1024 + k0 + sseg*16;
      unsigned p[8];
#pragma unroll
      for (int i = 0; i < 4; i++){
        float4 v = *reinterpret_cast<const float4*>(src + i*4);
        sqa = fmaf(v.x,v.x,sqa); sqa = fmaf(v.y,v.y,sqa);
        sqa = fmaf(v.z,v.z,sqa); sqa = fmaf(v.w,v.w,sqa);
        p[2*i]   = pk2(v.x, v.y);
        p[2*i+1] = pk2(v.z, v.w);
      }
      uint4 w0; w0.x=p[0]; w0.y=p[1]; w0.z=p[2]; w0.w=p[3];
      uint4 w1; w1.x=p[4]; w1.y=p[5]; w1.z=p[6]; w1.w=p[7];
      *reinterpret_cast<uint4*>(&xs[cb][stok*PIT + sseg*16])     = w0;
      *reinterpret_cast<uint4*>(&xs[cb][stok*PIT + sseg*16 + 8]) = w1;
    }
    { // stage P rows
      const u16* src = PT + (size_t)stok*1024 + k0 + sseg*16;
      *reinterpret_cast<uint4*>(&ps[cb][stok*PIT + sseg*16])   = *reinterpret_cast<const uint4*>(src);
      *reinterpret_cast<uint4*>(&ps[cb][stok*PIT + sseg*16+8]) = *reinterpret_cast<const uint4*>(src+8);
    }
    __syncthreads();
#pragma unroll
    for (int s = 0; s < 2; s++){
      short8 a = *reinterpret_cast<const short8*>(&xs[cb][(16*w + (lane&15))*PIT + s*32 + (lane>>4)*8]);
#pragma unroll
      for (int t = 0; t < 4; t++){
        short8 bb = *reinterpret_cast<const short8*>(&ps[cb][(t*16 + (lane&15))*PIT + s*32 + (lane>>4)*8]);
        acc[t] = __builtin_amdgcn_mfma_f32_16x16x32_bf16(a, bb, acc[t], 0, 0, 0);
      }
    }
  }
  // reduce sumsq across the 4 threads sharing stok (adjacent lanes)
  sqa += __shfl_xor(sqa, 1, 64);
  sqa += __shfl_xor(sqa, 2, 64);
  if ((tid & 3) == 0) sqn[stok] = 10.0f / fmaxf(sqrtf(sqa), 1e-12f);
  __syncthreads();
  // softmax per token (rows spread over lane>>4 groups; primes = lane&15 + 16*t)
  u16* cl = xs[0];  // reuse
#pragma unroll
  for (int r = 0; r < 4; r++){
    int gt = 16*w + (lane>>4)*4 + r;
    float scale = sqn[gt];
    float v[4];
#pragma unroll
    for (int t = 0; t < 4; t++) v[t] = acc[t][r] * scale;
    if ((lane&15) >= 2) v[3] = -1e30f;
    float mx = fmaxf(fmaxf(v[0],v[1]), fmaxf(v[2],v[3]));
#pragma unroll
    for (int off = 1; off < 16; off <<= 1) mx = fmaxf(mx, __shfl_xor(mx, off, 64));
    float e[4], sum = 0.f;
#pragma unroll
    for (int t = 0; t < 4; t++){ e[t] = __expf(v[t]-mx); sum += e[t]; }
#pragma unroll
    for (int off = 1; off < 16; off <<= 1) sum += __shfl_xor(sum, off, 64);
    float inv = 1.0f / sum;
#pragma unroll
    for (int t = 0; t < 4; t++) cl[gt*PIT + t*16 + (lane&15)] = f2b(e[t]*inv);
  }
  __syncthreads();
  { // C write (row-major) b128
    u16* dst = C + ((size_t)(b*4096 + n0 + stok))*64 + sseg*16;
    *reinterpret_cast<uint4*>(dst)   = *reinterpret_cast<const uint4*>(&cl[stok*PIT + sseg*16]);
    *reinterpret_cast<uint4*>(dst+8) = *reinterpret_cast<const uint4*>(&cl[stok*PIT + sseg*16+8]);
  }
  { // CT write (transposed)
    int m = tid>>2, nseg = tid&3;
    unsigned vs[8];
#pragma unroll
    for (int j = 0; j < 8; j++){
      u16 lo = cl[(nseg*16 + 2*j)*PIT + m];
      u16 hi = cl[(nseg*16 + 2*j+1)*PIT + m];
      vs[j] = (unsigned)lo | ((unsigned)hi<<16);
    }
    u16* dst = CT + ((size_t)(b*64 + m))*4096 + n0 + nseg*16;
    uint4 w0; w0.x=vs[0]; w0.y=vs[1]; w0.z=vs[2]; w0.w=vs[3];
    uint4 w1; w1.x=vs[4]; w1.y=vs[5]; w1.z=vs[6]; w1.w=vs[7];
    *reinterpret_cast<uint4*>(dst)   = w0;
    *reinterpret_cast<uint4*>(dst+8) = w1;
  }
}

// ---------------- K3: H_prime partials -> bf16 (MFMA, K-split x4; dbuf LDS) ----------
__global__ __launch_bounds__(256) void kHp2(const float* __restrict__ x, const u16* __restrict__ CT,
                                            u16* __restrict__ Hpart){
  int blk = blockIdx.x;            // 512 = b(8) * dt(16) * kt(4)
  int kt = blk & 3, dt = (blk >> 2) & 15, b = blk >> 6;
  int d0 = dt*64;
  int tid = threadIdx.x, lane = tid&63, w = tid>>6;
  __shared__ __align__(16) u16 cs[2][64*PIT];    // [m][n]
  __shared__ __align__(16) u16 xt[2][64*PIT];    // [d][n]
  f32x4 acc[4] = {{0,0,0,0},{0,0,0,0},{0,0,0,0},{0,0,0,0}};
  int nn = tid>>2, seg = tid&3;
  int np = tid & 31, dsg = tid >> 5;          // n-pair staging map
  for (int nc = 0; nc < 16; nc++){
    int n0 = kt*1024 + nc*64, cb = nc & 1;
    { // stage CT rows [m][n-chunk]
      const u16* src = CT + ((size_t)(b*64 + nn))*4096 + n0 + seg*16;  // nn = m here
      *reinterpret_cast<uint4*>(&cs[cb][nn*PIT + seg*16])   = *reinterpret_cast<const uint4*>(src);
      *reinterpret_cast<uint4*>(&cs[cb][nn*PIT + seg*16+8]) = *reinterpret_cast<const uint4*>(src+8);
    }
    { // stage x transposed: n-paired packed u32 writes (conflict-free)
      const float* s0 = x + ((size_t)(b*4096 + n0 + 2*np))*1024 + d0 + dsg*8;
      const float* s1 = s0 + 1024;
      float4 a0 = *reinterpret_cast<const float4*>(s0);
      float4 a1 = *reinterpret_cast<const float4*>(s0+4);
      float4 c0v = *reinterpret_cast<const float4*>(s1);
      float4 c1v = *reinterpret_cast<const float4*>(s1+4);
      float av[8] = {a0.x,a0.y,a0.z,a0.w,a1.x,a1.y,a1.z,a1.w};
      float cv[8] = {c0v.x,c0v.y,c0v.z,c0v.w,c1v.x,c1v.y,c1v.z,c1v.w};
#pragma unroll
      for (int j2 = 0; j2 < 8; j2++){
        int dd = dsg*8 + j2;
        *reinterpret_cast<unsigned*>(&xt[cb][dd*PIT + 2*np]) = pk2(av[j2], cv[j2]);
      }
    }
    __syncthreads();
#pragma unroll
    for (int s = 0; s < 2; s++){
      short8 a = *reinterpret_cast<const short8*>(&cs[cb][(16*w + (lane&15))*PIT + s*32 + (lane>>4)*8]);
#pragma unroll
      for (int t = 0; t < 4; t++){
        short8 bb = *reinterpret_cast<const short8*>(&xt[cb][(t*16 + (lane&15))*PIT + s*32 + (lane>>4)*8]);
        acc[t] = __builtin_amdgcn_mfma_f32_16x16x32_bf16(a, bb, acc[t], 0, 0, 0);
      }
    }
  }
#pragma unroll
  for (int t = 0; t < 4; t++)
#pragma unroll
    for (int r = 0; r < 4; r++){
      int m = 16*w + (lane>>4)*4 + r;
      int d = d0 + t*16 + (lane&15);
      if (m < 50) Hpart[(((size_t)(b*4) + kt)*50 + m)*1024 + d] = f2b(acc[t][r]);
    }
}

// ---------------- K3b: reduce bf16 partials -> H f32 + Hb bf16, pad rows zeroed ----------
__global__ void kredH(const u16* __restrict__ Hpart, float* __restrict__ H, u16* __restrict__ Hb){
  int e = blockIdx.x*256 + threadIdx.x;    // grid 2048 -> 524288 over [b][m(64)][d]
  int b = e >> 16, rem = e & 65535;
  int m = rem >> 10, d = rem & 1023;
  size_t o = ((size_t)(b*64 + m))*1024 + d;
  if (m < 50){
    const u16* p = Hpart + (size_t)b*204800 + m*1024 + d;
    float s = b2f(p[0]) + b2f(p[51200]) + b2f(p[102400]) + b2f(p[153600]);
    H[o] = s;
    Hb[o] = f2b(s);
  } else {
    Hb[o] = 0;
  }
}

// ---------------- K4: fused Gram (LDS) + Newton-Schulz; blocks 8..519 transpose W1/W2 ----
__global__ __launch_bounds__(256) void kgramNS(const u16* __restrict__ Hb, float* __restrict__ Wm,
                                               const float* __restrict__ W1, u16* __restrict__ W1T,
                                               const float* __restrict__ W2, u16* __restrict__ W2T){
  __shared__ __align__(16) u16 Yr[2][64*P2], Yc[2][64*P2], Zr[2][64*P2], Zc[2][64*P2];
  __shared__ __align__(16) u16 TrTc[2][64*P2];      // Tr=TrTc[0], Tc=TrTc[1]; init overlay: Gf32
  __shared__ __align__(16) u16 ts[64*PIT];          // gram staging / transpose staging
  __shared__ float sv[2];
  int blk = blockIdx.x;
  int tid = threadIdx.x, lane = tid&63, w = tid>>6;

  if (blk >= 8){
    // ---- weight transpose path (4 tiles per block) ----
    int tblk = blk - 8;
    for (int i = 0; i < 4; i++){
      int g = tblk*4 + i;
      const float* src; u16* dst; int ss, ds;
      if (g < 1024){
        int kt2 = g >> 6, nt2 = g & 63;
        src = W1 + (size_t)(kt2*64)*4096 + nt2*64; ss = 4096;
        dst = W1T + (size_t)(nt2*64)*1024 + kt2*64; ds = 1024;
      } else {
        int t = g - 1024;
        int kt2 = t >> 4, dt2 = t & 15;
        src = W2 + (size_t)(kt2*64)*1024 + dt2*64; ss = 1024;
        dst = W2T + (size_t)(dt2*64)*4096 + kt2*64; ds = 4096;
      }
      int r = tid>>2, sseg = tid&3;
      __syncthreads();   // protect ts reuse across tiles
      {
        const float* s0 = src + (size_t)r*ss + sseg*16;
        unsigned p[8];
#pragma unroll
        for (int q = 0; q < 4; q++){
          float4 v = *reinterpret_cast<const float4*>(s0 + q*4);
          p[2*q]   = pk2(v.x, v.y);
          p[2*q+1] = pk2(v.z, v.w);
        }
        uint4 w0; w0.x=p[0]; w0.y=p[1]; w0.z=p[2]; w0.w=p[3];
        uint4 w1; w1.x=p[4]; w1.y=p[5]; w1.z=p[6]; w1.w=p[7];
        *reinterpret_cast<uint4*>(&ts[r*PIT + sseg*16])     = w0;
        *reinterpret_cast<uint4*>(&ts[r*PIT + sseg*16 + 8]) = w1;
      }
      __syncthreads();
      {
        int n2 = tid>>2, kseg = tid&3;
        unsigned q[8];
#pragma unroll
        for (int j = 0; j < 8; j++){
          u16 lo = ts[(kseg*16 + 2*j)*PIT + n2];
          u16 hi = ts[(kseg*16 + 2*j+1)*PIT + n2];
          q[j] = (unsigned)lo | ((unsigned)hi<<16);
        }
        u16* d2 = dst + (size_t)n2*ds + kseg*16;
        uint4 w0; w0.x=q[0]; w0.y=q[1]; w0.z=q[2]; w0.w=q[3];
        uint4 w1; w1.x=q[4]; w1.y=q[5]; w1.z=q[6]; w1.w=q[7];
        *reinterpret_cast<uint4*>(d2)   = w0;
        *reinterpret_cast<uint4*>(d2+8) = w1;
      }
    }
    return;
  }

  // ---- gram + NS path ----
  int b = blk;
  float* Gf = reinterpret_cast<float*>(&TrTc[0][0]);   // 64x64 f32, pitch 65
  { // Gram via MFMA into LDS
    f32x4 acc[4] = {{0,0,0,0},{0,0,0,0},{0,0,0,0},{0,0,0,0}};
    int m = tid>>2, seg = tid&3;
    for (int kc = 0; kc < 16; kc++){
      int k0 = kc*64;
      __syncthreads();
      const u16* src = Hb + ((size_t)(b*64 + m))*1024 + k0 + seg*16;
      *reinterpret_cast<uint4*>(&ts[m*PIT + seg*16])   = *reinterpret_cast<const uint4*>(src);
      *reinterpret_cast<uint4*>(&ts[m*PIT + seg*16+8]) = *reinterpret_cast<const uint4*>(src+8);
      __syncthreads();
#pragma unroll
      for (int s = 0; s < 2; s++){
        short8 a = *reinterpret_cast<const short8*>(&ts[(16*w + (lane&15))*PIT + s*32 + (lane>>4)*8]);
#pragma unroll
        for (int t = 0; t < 4; t++){
          short8 bb = *reinterpret_cast<const short8*>(&ts[(t*16 + (lane&15))*PIT + s*32 + (lane>>4)*8]);
          acc[t] = __builtin_amdgcn_mfma_f32_16x16x32_bf16(a, bb, acc[t], 0, 0, 0);
        }
      }
    }
    __syncthreads();
#pragma unroll
    for (int t = 0; t < 4; t++)
#pragma unroll
      for (int r = 0; r < 4; r++){
        int i = 16*w + (lane>>4)*4 + r;
        int j = t*16 + (lane&15);
        Gf[i*65 + j] = acc[t][r];
      }
  }
  __syncthreads();
  if (tid < 64){
    float v = (tid < 50) ? Gf[tid*65 + tid] : 0.f;
    for (int off = 1; off < 64; off <<= 1) v += __shfl_xor(v, off, 64);
    if (tid == 0){ sv[0] = 1.0f / v; sv[1] = rsqrtf(v); }
  }
  __syncthreads();
  float rs = sv[0];
  for (int idx = tid; idx < 4096; idx += 256){
    int r = idx>>6, c = idx&63;
    float yv = (r<50 && c<50) ? Gf[r*65+c]*rs : ((r==c) ? 1.f : 0.f);
    float zv = (r==c) ? 1.f : 0.f;
    u16 yb = f2b(yv), zb = f2b(zv);
    Yr[0][r*P2+c] = yb; Yc[0][c*P2+r] = yb;
    Zr[0][r*P2+c] = zb; Zc[0][c*P2+r] = zb;
  }
  __syncthreads();
  u16* Tr = TrTc[0];
  u16* Tc = TrTc[1];
  int lr = lane>>4, lc = lane&15;
  int row0 = 16*w;
  for (int it = 0; it < NS_ITERS; it++){
    int cur = it & 1, nxt = cur ^ 1;
    { // phase 1: T = 1.5I - 0.5 * Z@Y
      short8 a0 = *reinterpret_cast<const short8*>(&Zr[cur][(row0+lc)*P2 + lr*8]);
      short8 a1 = *reinterpret_cast<const short8*>(&Zr[cur][(row0+lc)*P2 + 32 + lr*8]);
      f32x4 acc[4] = {{0,0,0,0},{0,0,0,0},{0,0,0,0},{0,0,0,0}};
#pragma unroll
      for (int t = 0; t < 4; t++){
        short8 b0 = *reinterpret_cast<const short8*>(&Yc[cur][(t*16+lc)*P2 + lr*8]);
        short8 b1 = *reinterpret_cast<const short8*>(&Yc[cur][(t*16+lc)*P2 + 32 + lr*8]);
        acc[t] = __builtin_amdgcn_mfma_f32_16x16x32_bf16(a0, b0, acc[t], 0, 0, 0);
        acc[t] = __builtin_amdgcn_mfma_f32_16x16x32_bf16(a1, b1, acc[t], 0, 0, 0);
      }
      __syncthreads();
#pragma unroll
      for (int t = 0; t < 4; t++)
#pragma unroll
        for (int r = 0; r < 4; r++){
          int row = row0 + lr*4 + r, col = t*16 + lc;
          float v = ((row==col) ? 1.5f : 0.f) - 0.5f*acc[t][r];
          u16 h = f2b(v);
          Tr[row*P2+col] = h; Tc[col*P2+row] = h;
        }
    }
    __syncthreads();
    { // phase 2: Y' = Y@T ; Z' = T@Z
      short8 ya0 = *reinterpret_cast<const short8*>(&Yr[cur][(row0+lc)*P2 + lr*8]);
      short8 ya1 = *reinterpret_cast<const short8*>(&Yr[cur][(row0+lc)*P2 + 32 + lr*8]);
      short8 ta0 = *reinterpret_cast<const short8*>(&Tr[(row0+lc)*P2 + lr*8]);
      short8 ta1 = *reinterpret_cast<const short8*>(&Tr[(row0+lc)*P2 + 32 + lr*8]);
      f32x4 accY[4] = {{0,0,0,0},{0,0,0,0},{0,0,0,0},{0,0,0,0}};
      f32x4 accZ[4] = {{0,0,0,0},{0,0,0,0},{0,0,0,0},{0,0,0,0}};
#pragma unroll
      for (int t = 0; t < 4; t++){
        short8 tb0 = *reinterpret_cast<const short8*>(&Tc[(t*16+lc)*P2 + lr*8]);
        short8 tb1 = *reinterpret_cast<const short8*>(&Tc[(t*16+lc)*P2 + 32 + lr*8]);
        accY[t] = __builtin_amdgcn_mfma_f32_16x16x32_bf16(ya0, tb0, accY[t], 0, 0, 0);
        accY[t] = __builtin_amdgcn_mfma_f32_16x16x32_bf16(ya1, tb1, accY[t], 0, 0, 0);
        short8 zb0 = *reinterpret_cast<const short8*>(&Zc[cur][(t*16+lc)*P2 + lr*8]);
        short8 zb1 = *reinterpret_cast<const short8*>(&Zc[cur][(t*16+lc)*P2 + 32 + lr*8]);
        accZ[t] = __builtin_amdgcn_mfma_f32_16x16x32_bf16(ta0, zb0, accZ[t], 0, 0, 0);
        accZ[t] = __builtin_amdgcn_mfma_f32_16x16x32_bf16(ta1, zb1, accZ[t], 0, 0, 0);
      }
#pragma unroll
      for (int t = 0; t < 4; t++)
#pragma unroll
        for (int r = 0; r < 4; r++){
          int row = row0 + lr*4 + r, col = t*16 + lc;
          u16 hy = f2b(accY[t][r]);
          u16 hz = f2b(accZ[t][r]);
          Yr[nxt][row*P2+col] = hy; Yc[nxt][col*P2+row] = hy;
          Zr[nxt][row*P2+col] = hz; Zc[nxt][col*P2+row] = hz;
        }
    }
    __syncthreads();
  }
  float rss = sv[1];
  int fin = NS_ITERS & 1;
  for (int idx = tid; idx < 2500; idx += 256){
    int r = idx/50, c = idx - r*50;
    Wm[(size_t)b*2500 + idx] = b2f(Zr[fin][r*P2+c]) * rss;
  }
}

// ---------------- K4c: H_logic = Wm @ H + threefry noise -> ZbB bf16 (fused) ----------------
__global__ __launch_bounds__(256) void kapply2(const float* __restrict__ H, const float* __restrict__ Wm,
                                               u16* __restrict__ zb){
  TFOut K1 = tf2x32(0u, 42u, 0u, 0u);
  TFOut K2 = tf2x32(0u, 42u, 0u, 1u);
  int blk = blockIdx.x;          // 128 = b(8) * dt(16)
  int dt = blk & 15, b = blk >> 4;
  int d0 = dt*64;
  int tid = threadIdx.x;
  int d = tid & 63, mg = tid >> 6;
  __shared__ __align__(16) float WsT[50*64];
  __shared__ float Hs[50*65];
  for (int idx = tid; idx < 3200; idx += 256){
    int j = idx >> 6, c = idx & 63;
    WsT[idx] = (c < 50) ? Wm[(size_t)b*2500 + c*50 + j] : 0.f;
  }
  for (int idx = tid; idx < 3200; idx += 256){
    int j = idx >> 6, c = idx & 63;
    Hs[j*65 + c] = H[((size_t)(b*64) + j)*1024 + d0 + c];
  }
  __syncthreads();
  float acc[16];
#pragma unroll
  for (int i = 0; i < 16; i++) acc[i] = 0.f;
  for (int j = 0; j < 50; j++){
    float hv = Hs[j*65 + d];
    const float* wb = WsT + j*64 + (mg << 4);
#pragma unroll
    for (int q = 0; q < 4; q++){
      float4 wv = *reinterpret_cast<const float4*>(wb + q*4);
      acc[q*4+0] = fmaf(wv.x, hv, acc[q*4+0]);
      acc[q*4+1] = fmaf(wv.y, hv, acc[q*4+1]);
      acc[q*4+2] = fmaf(wv.z, hv, acc[q*4+2]);
      acc[q*4+3] = fmaf(wv.w, hv, acc[q*4+3]);
    }
  }
#pragma unroll
  for (int i = 0; i < 16; i++){
    int m = (mg << 4) + i;
    size_t zo = ((size_t)(b*64 + m))*1024 + d0 + d;
    u16 ov = 0;
    if (m < 50){
      float val = acc[i];
      uint32_t j = (uint32_t)(((b*50 + m) << 10) + d0 + d);
      TFOut r1 = tf2x32(K1.a, K1.b, 0u, j);
      uint32_t bits = r1.a ^ r1.b;
      float u = __uint_as_float(0x3F800000u | (bits >> 9)) - 1.0f;
      if (u < 0.0464f){
        TFOut r2 = tf2x32(K2.a, K2.b, 0u, j);
        uint32_t nb = r2.a ^ r2.b;
        float ww = __uint_as_float(0x3F800000u | (nb >> 9)) - 1.0f;
        const float lo = -0.99999994f;
        float un = fmaxf(lo, fmaf(ww, 2.0f, lo));
        val += 0.1f * (1.4142135f * erfinv_f32(un));
      }
      ov = f2b(val);
    }
    zb[zo] = ov;
  }
}

// ---------------- K5: Hh = gelu(ZbB @ W1T + b1) (MFMA; dbuf LDS, 1 barrier/chunk) ----------------
__global__ __launch_bounds__(256) void kmlp1(const u16* __restrict__ ZbB, const u16* __restrict__ W1T,
                                             const float* __restrict__ b1, u16* __restrict__ Hh){
  int blk = blockIdx.x; int b = blk>>6, c0 = (blk&63)<<6;
  int tid = threadIdx.x, lane = tid&63, w = tid>>6;
  __shared__ __align__(16) u16 az[2][64*PIT];   // [m][k]
  __shared__ __align__(16) u16 wt[2][64*PIT];   // [n][k]
  f32x4 acc[4] = {{0,0,0,0},{0,0,0,0},{0,0,0,0},{0,0,0,0}};
  int rr = tid>>2, seg = tid&3;
  for (int kc = 0; kc < 16; kc++){
    int k0 = kc*64, cb = kc & 1;
    { // stage A (ZbB rows)
      const u16* src = ZbB + ((size_t)(b*64 + rr))*1024 + k0 + seg*16;
      *reinterpret_cast<uint4*>(&az[cb][rr*PIT + seg*16])   = *reinterpret_cast<const uint4*>(src);
      *reinterpret_cast<uint4*>(&az[cb][rr*PIT + seg*16+8]) = *reinterpret_cast<const uint4*>(src+8);
    }
    { // stage B (W1T rows, direct bf16 copy)
      const u16* src = W1T + ((size_t)(c0 + rr))*1024 + k0 + seg*16;
      *reinterpret_cast<uint4*>(&wt[cb][rr*PIT + seg*16])   = *reinterpret_cast<const uint4*>(src);
      *reinterpret_cast<uint4*>(&wt[cb][rr*PIT + seg*16+8]) = *reinterpret_cast<const uint4*>(src+8);
    }
    __syncthreads();
#pragma unroll
    for (int s = 0; s < 2; s++){
      short8 a = *reinterpret_cast<const short8*>(&az[cb][(16*w + (lane&15))*PIT + s*32 + (lane>>4)*8]);
#pragma unroll
      for (int t = 0; t < 4; t++){
        short8 bb = *reinterpret_cast<const short8*>(&wt[cb][(t*16 + (lane&15))*PIT + s*32 + (lane>>4)*8]);
        acc[t] = __builtin_amdgcn_mfma_f32_16x16x32_bf16(a, bb, acc[t], 0, 0, 0);
      }
    }
  }
#pragma unroll
  for (int t = 0; t < 4; t++)
#pragma unroll
    for (int r = 0; r < 4; r++){
      int m = 16*w + (lane>>4)*4 + r;
      int n = c0 + t*16 + (lane&15);
      float val = acc[t][r] + b1[n];
      float g = 0.5f * val * (1.0f + erff(val * 0.70710678f));
      Hh[((size_t)(b*64 + m))*4096 + n] = (m < 50) ? f2b(g) : (u16)0;
    }
}

// ---------------- K6: partials of Hh @ W2T -> bf16 (MFMA, K-split x4; dbuf LDS) ----------
__global__ __launch_bounds__(256) void kmlp2p(const u16* __restrict__ Hh, const u16* __restrict__ W2T,
                                              u16* __restrict__ Mpart){
  int blk = blockIdx.x;            // 512 = b(8) * dt(16) * kt(4)
  int kt = blk & 3, dt = (blk >> 2) & 15, b = blk >> 6;
  int d0 = dt*64;
  int tid = threadIdx.x, lane = tid&63, w = tid>>6;
  __shared__ __align__(16) u16 az[2][64*PIT];
  __shared__ __align__(16) u16 wt[2][64*PIT];
  f32x4 acc[4] = {{0,0,0,0},{0,0,0,0},{0,0,0,0},{0,0,0,0}};
  int rr = tid>>2, seg = tid&3;
  for (int kc = 0; kc < 16; kc++){
    int k0 = kt*1024 + kc*64, cb = kc & 1;
    {
      const u16* src = Hh + ((size_t)(b*64 + rr))*4096 + k0 + seg*16;
      *reinterpret_cast<uint4*>(&az[cb][rr*PIT + seg*16])   = *reinterpret_cast<const uint4*>(src);
      *reinterpret_cast<uint4*>(&az[cb][rr*PIT + seg*16+8]) = *reinterpret_cast<const uint4*>(src+8);
    }
    { // stage B (W2T rows, direct bf16 copy)
      const u16* src = W2T + ((size_t)(d0 + rr))*4096 + k0 + seg*16;
      *reinterpret_cast<uint4*>(&wt[cb][rr*PIT + seg*16])   = *reinterpret_cast<const uint4*>(src);
      *reinterpret_cast<uint4*>(&wt[cb][rr*PIT + seg*16+8]) = *reinterpret_cast<const uint4*>(src+8);
    }
    __syncthreads();
#pragma unroll
    for (int s = 0; s < 2; s++){
      short8 a = *reinterpret_cast<const short8*>(&az[cb][(16*w + (lane&15))*PIT + s*32 + (lane>>4)*8]);
#pragma unroll
      for (int t = 0; t < 4; t++){
        short8 bb = *reinterpret_cast<const short8*>(&wt[cb][(t*16 + (lane&15))*PIT + s*32 + (lane>>4)*8]);
        acc[t] = __builtin_amdgcn_mfma_f32_16x16x32_bf16(a, bb, acc[t], 0, 0, 0);
      }
    }
  }
#pragma unroll
  for (int t = 0; t < 4; t++)
#pragma unroll
    for (int r = 0; r < 4; r++){
      int m = 16*w + (lane>>4)*4 + r;
      int d = d0 + t*16 + (lane&15);
      if (m < 50) Mpart[(((size_t)(b*4) + kt)*50 + m)*1024 + d] = f2b(acc[t][r]);
    }
}

// ---------------- K6b: HfT = tanh(sum bf16 partials + b2)^T, bf16, m>=50 zero ----------------
__global__ void kredT(const u16* __restrict__ Mpart, const float* __restrict__ b2, u16* __restrict__ HfT){
  int e = blockIdx.x*256 + threadIdx.x;    // grid 2048 -> 524288 over [b][m(64)][d]
  int b = e >> 16, rem = e & 65535;
  int m = rem >> 10, d = rem & 1023;
  u16 outv = 0;
  if (m < 50){
    const u16* p = Mpart + (size_t)b*204800 + m*1024 + d;
    float s = b2f(p[0]) + b2f(p[51200]) + b2f(p[102400]) + b2f(p[153600]) + b2[d];
    outv = f2b(tanhf(s));
  }
  HfT[((size_t)(b*1024) + d)*64 + m] = outv;
}

// ---------------- K7: out = x + C @ Hf (MFMA + LDS-bounced coalesced epilogue) ----------
__global__ __launch_bounds__(256) void kdec2(const float* __restrict__ x, const u16* __restrict__ C,
                                             const u16* __restrict__ HfT, float* __restrict__ out){
  int blk = blockIdx.x;              // 2048 = b(8) * nt(64) * dq(4)
  int dq = blk & 3, nt = (blk >> 2) & 63, b = blk >> 8;
  int n0 = nt << 6;
  int tid = threadIdx.x, lane = tid&63, w = tid>>6;
  __shared__ __align__(16) u16 ctile[64*PIT];   // [tok][m]
  __shared__ __align__(16) u16 htile[64*PIT];   // [d][m]
  __shared__ __align__(16) float obuf[64*68];   // [n][d] f32, pitch 68
  int rr = tid>>2, seg = tid&3;
  {
    const u16* src = C + ((size_t)(b*4096 + n0 + rr))*64 + seg*16;
    *reinterpret_cast<uint4*>(&ctile[rr*PIT + seg*16])   = *reinterpret_cast<const uint4*>(src);
    *reinterpret_cast<uint4*>(&ctile[rr*PIT + seg*16+8]) = *reinterpret_cast<const uint4*>(src+8);
  }
  __syncthreads();
  short8 afrag[2];
#pragma unroll
  for (int s = 0; s < 2; s++)
    afrag[s] = *reinterpret_cast<const short8*>(&ctile[(16*w + (lane&15))*PIT + s*32 + (lane>>4)*8]);
  for (int dt2 = 0; dt2 < 4; dt2++){
    int d0 = (dq*4 + dt2) * 64;
    __syncthreads();
    {
      const u16* src = HfT + ((size_t)(b*1024 + d0 + rr))*64 + seg*16;
      *reinterpret_cast<uint4*>(&htile[rr*PIT + seg*16])   = *reinterpret_cast<const uint4*>(src);
      *reinterpret_cast<uint4*>(&htile[rr*PIT + seg*16+8]) = *reinterpret_cast<const uint4*>(src+8);
    }
    __syncthreads();
    f32x4 acc[4] = {{0,0,0,0},{0,0,0,0},{0,0,0,0},{0,0,0,0}};
#pragma unroll
    for (int s = 0; s < 2; s++){
#pragma unroll
      for (int t = 0; t < 4; t++){
        short8 bb = *reinterpret_cast<const short8*>(&htile[(t*16 + (lane&15))*PIT + s*32 + (lane>>4)*8]);
        acc[t] = __builtin_amdgcn_mfma_f32_16x16x32_bf16(afrag[s], bb, acc[t], 0, 0, 0);
      }
    }
    // scatter acc into LDS [n][d] f32
#pragma unroll
    for (int t = 0; t < 4; t++)
#pragma unroll
      for (int r = 0; r < 4; r++){
        int nl = 16*w + (lane>>4)*4 + r;
        int dl = t*16 + (lane&15);
        obuf[nl*68 + dl] = acc[t][r];
      }
    __syncthreads();
    // coalesced epilogue: 1024 float4-slots (64 rows x 16 slots), 4 per thread
#pragma unroll
    for (int pass = 0; pass < 4; pass++){
      int s2 = tid + pass*256;
      int nl = s2 >> 4, sg = s2 & 15;
      size_t o = ((size_t)(b*4096 + n0 + nl))*1024 + d0 + sg*4;
      float4 xv = *reinterpret_cast<const float4*>(x + o);
      const float* ob = &obuf[nl*68 + sg*4];
      float4 ov;
      ov.x = xv.x + ob[0];
      ov.y = xv.y + ob[1];
      ov.z = xv.z + ob[2];
      ov.w = xv.w + ob[3];
      *reinterpret_cast<float4*>(out + o) = ov;
    }
  }
}

// ---------------- launch ----------------
extern "C" void kernel_launch(void* const* d_in, const int* in_sizes, int n_in,
                              void* d_out, int out_size, void* d_ws, size_t ws_size,
                              hipStream_t stream) {
  (void)in_sizes; (void)n_in; (void)out_size;
  if (ws_size < (size_t)19755264) return;
  const float* x  = (const float*)d_in[0];
  const float* pn = (const float*)d_in[1];
  const float* W1 = (const float*)d_in[8];
  const float* b1 = (const float*)d_in[9];
  const float* W2 = (const float*)d_in[10];
  const float* b2 = (const float*)d_in[11];
  float* out = (float*)d_out;
  char* ws = (char*)d_ws;

  // W1T/W2T bf16 scratch lives in d_out (134 MB): dead before kdec2 fully
  // overwrites out. W1T = 4096x1024 bf16 (8.39MB), W2T = 1024x4096 bf16.
  u16*   W1T = (u16*)d_out;
  u16*   W2T = (u16*)d_out + 4194304;

  // Overlapped ws layout (stream-ordered liveness):
  u16*   C   = (u16*)(ws);                      // [0, 4.19MB)        live kC->kdec2
  u16*   CT  = (u16*)(ws + 4194304);            // CT region 4.19MB:  CT live kC->kHp2
  u16*   ZbB = (u16*)(ws + 4194304 + 1638400);  //   reuses CT space  (kapply2->kmlp1)
  u16*   HfT = (u16*)(ws + 4194304 + 2686976);  //   (kredT->kdec2)
  u16*   Hh  = (u16*)(ws + 8388608);            // Hh region 4.19MB:  Hh live kmlp1->kmlp2p
  u16*   Hb  = (u16*)(ws + 8388608);            //   reuses Hh space  (kredH->kgramNS)
  float* H   = (float*)(ws + 8388608 + 1048576);//   (kredH->kapply2)
  u16*   HP  = (u16*)(ws + 12582912);           // bf16 partials 3.27MB: kHp2->kredH, kmlp2p->kredT
  u16*   PT  = (u16*)(ws + 19136512);           // 131,072 B
  float* WM  = (float*)(ws + 19347584);         // 80,000 B

  hipLaunchKernelGGL(kprep,   dim3(64),   dim3(256), 0, stream, pn, PT);
  hipLaunchKernelGGL(kC,      dim3(512),  dim3(256), 0, stream, x, PT, C, CT);
  hipLaunchKernelGGL(kHp2,    dim3(512),  dim3(256), 0, stream, x, CT, HP);
  hipLaunchKernelGGL(kredH,   dim3(2048), dim3(256), 0, stream, HP, H, Hb);
  hipLaunchKernelGGL(kgramNS, dim3(520),  dim3(256), 0, stream, Hb, WM, W1, W1T, W2, W2T);
  hipLaunchKernelGGL(kapply2, dim3(128),  dim3(256), 0, stream, H, WM, ZbB);
  hipLaunchKernelGGL(kmlp1,   dim3(512),  dim3(256), 0, stream, ZbB, W1T, b1, Hh);
  hipLaunchKernelGGL(kmlp2p,  dim3(512),  dim3(256), 0, stream, Hh, W2T, HP);
  hipLaunchKernelGGL(kredT,   dim3(2048), dim3(256), 0, stream, HP, b2, HfT);
  hipLaunchKernelGGL(kdec2,   dim3(2048), dim3(256), 0, stream, x, C, HfT, out);
}